// Round 2
// baseline (13876.208 us; speedup 1.0000x reference)
//
#include <hip/hip_runtime.h>
#include <hip/hip_bf16.h>
#include <math.h>

#define NN 20000
#define EE 320000
#define GG 64
#define IN_F 256
#define H1 512
#define H2 256
#define NHEADS 2
#define NC 16
#define NSTEPS 4
#define KT 4
#define NPB 4

__device__ __forceinline__ float sigmoidf_(float x) { return 1.f / (1.f + expf(-x)); }

__device__ __forceinline__ void atomicMaxF(float* addr, float val) {
    int* ai = (int*)addr;
    int old = *ai;
    while (__int_as_float(old) < val) {
        int assumed = old;
        old = atomicCAS(ai, assumed, __float_as_int(val));
        if (old == assumed) break;
    }
}

// ---- pad input (N,256) -> h (N,512) f32 ----
__global__ void pad_kernel(const float* __restrict__ in_feat, float* __restrict__ h) {
    int idx = blockIdx.x * 256 + threadIdx.x;
    if (idx >= NN * H1) return;
    int n = idx >> 9, d = idx & 511;
    h[idx] = (d < IN_F) ? in_feat[n * IN_F + d] : 0.f;
}

// ---- transpose f32 weight (rows,cols) -> (cols,rows) ----
__global__ void transpose_kernel(const float* __restrict__ w, float* __restrict__ wT,
                                 int rows, int cols) {
    int idx = blockIdx.x * 256 + threadIdx.x;
    if (idx >= rows * cols) return;
    int r = idx / cols, c = idx % cols;
    wT[c * rows + r] = w[r * cols + c];
}

// ---- scatter: S[dst,:] += h[src,:] for edges of etype k; cntk[dst] += 1 ----
__global__ void scatter_k(const int* __restrict__ src, const int* __restrict__ dst,
                          const int* __restrict__ etype, const float* __restrict__ h,
                          float* __restrict__ S, float* __restrict__ cntk, int k) {
    int idx = blockIdx.x * 256 + threadIdx.x;
    if (idx >= EE * H1) return;
    int e = idx >> 9, d = idx & 511;
    if (etype[e] != k) return;
    atomicAdd(&S[dst[e] * H1 + d], h[src[e] * H1 + d]);
    if (d == 0) atomicAdd(&cntk[dst[e]], 1.0f);
}

// ---- a += S @ Wmsg[k] + cntk * bmsg[k]  (Wmsg layout [k,d,o]) ----
__global__ void gemm_msg(const float* __restrict__ S, const float* __restrict__ cntk,
                         const float* __restrict__ Wmsg, const float* __restrict__ bmsg,
                         float* __restrict__ a, int k) {
    __shared__ float Sl[NPB][H1];
    int n0 = blockIdx.x * NPB;
    int t = threadIdx.x;
    for (int nb = 0; nb < NPB; nb++)
        for (int d = t; d < H1; d += 256) Sl[nb][d] = S[(n0 + nb) * H1 + d];
    __syncthreads();
    const float* W = Wmsg + (size_t)k * H1 * H1;
    float acc[NPB][2] = {};
    int o0 = t, o1 = t + 256;
    for (int d = 0; d < H1; d++) {
        float w0 = W[d * H1 + o0];
        float w1 = W[d * H1 + o1];
#pragma unroll
        for (int nb = 0; nb < NPB; nb++) {
            acc[nb][0] += Sl[nb][d] * w0;
            acc[nb][1] += Sl[nb][d] * w1;
        }
    }
    float b0 = bmsg[k * H1 + o0];
    float b1 = bmsg[k * H1 + o1];
    for (int nb = 0; nb < NPB; nb++) {
        float c = cntk[n0 + nb];
        a[(n0 + nb) * H1 + o0] += acc[nb][0] + c * b0;
        a[(n0 + nb) * H1 + o1] += acc[nb][1] + c * b1;
    }
}

// ---- fused GRUCell: h = GRU(a, h).  wihT/whhT layout [d][1536] ----
__global__ void gru_kernel(const float* __restrict__ a, float* __restrict__ h,
                           const float* __restrict__ wihT, const float* __restrict__ whhT,
                           const float* __restrict__ b_ih, const float* __restrict__ b_hh) {
    __shared__ float aL[NPB][H1], hL[NPB][H1];
    int n0 = blockIdx.x * NPB, t = threadIdx.x;
    for (int nb = 0; nb < NPB; nb++)
        for (int d = t; d < H1; d += 256) {
            aL[nb][d] = a[(n0 + nb) * H1 + d];
            hL[nb][d] = h[(n0 + nb) * H1 + d];
        }
    __syncthreads();
    for (int half = 0; half < 2; half++) {
        int o = t + half * 256;
        float ir[NPB] = {}, iz[NPB] = {}, inn[NPB] = {};
        float hr[NPB] = {}, hz[NPB] = {}, hn[NPB] = {};
        for (int d = 0; d < H1; d++) {
            float wir = wihT[d * 1536 + o];
            float wiz = wihT[d * 1536 + 512 + o];
            float win = wihT[d * 1536 + 1024 + o];
            float whr = whhT[d * 1536 + o];
            float whz = whhT[d * 1536 + 512 + o];
            float whn = whhT[d * 1536 + 1024 + o];
#pragma unroll
            for (int nb = 0; nb < NPB; nb++) {
                float av = aL[nb][d], hv = hL[nb][d];
                ir[nb] += av * wir; iz[nb] += av * wiz; inn[nb] += av * win;
                hr[nb] += hv * whr; hz[nb] += hv * whz; hn[nb] += hv * whn;
            }
        }
        float bir = b_ih[o],        bhr = b_hh[o];
        float biz = b_ih[512 + o],  bhz = b_hh[512 + o];
        float bin = b_ih[1024 + o], bhn = b_hh[1024 + o];
        for (int nb = 0; nb < NPB; nb++) {
            float r = sigmoidf_(ir[nb] + bir + hr[nb] + bhr);
            float z = sigmoidf_(iz[nb] + biz + hz[nb] + bhz);
            float nv = tanhf(inn[nb] + bin + r * (hn[nb] + bhn));
            h[(n0 + nb) * H1 + o] = (1.f - z) * nv + z * hL[nb][o];
        }
    }
}

// ---- L2-normalize over dim1 then sigmoid, in place ----
__global__ void norm_sigmoid(float* __restrict__ h) {
    __shared__ float red[256];
    int n = blockIdx.x, t = threadIdx.x;
    float v0 = h[n * H1 + t], v1 = h[n * H1 + 256 + t];
    red[t] = v0 * v0 + v1 * v1;
    __syncthreads();
    for (int off = 128; off > 0; off >>= 1) {
        if (t < off) red[t] += red[t + off];
        __syncthreads();
    }
    float inv = 1.f / fmaxf(sqrtf(red[0]), 1e-12f);
    h[n * H1 + t] = sigmoidf_(v0 * inv);
    h[n * H1 + 256 + t] = sigmoidf_(v1 * inv);
}

// ---- feat = h @ fc_w^T (fcT layout [d][512]) ----
__global__ void feat_gemm(const float* __restrict__ h, const float* __restrict__ fcT,
                          float* __restrict__ feat) {
    __shared__ float hl[NPB][H1];
    int n0 = blockIdx.x * NPB, t = threadIdx.x;
    for (int nb = 0; nb < NPB; nb++)
        for (int d = t; d < H1; d += 256) hl[nb][d] = h[(n0 + nb) * H1 + d];
    __syncthreads();
    float acc[NPB][2] = {};
    int o0 = t, o1 = t + 256;
    for (int d = 0; d < H1; d++) {
        float w0 = fcT[d * H1 + o0];
        float w1 = fcT[d * H1 + o1];
#pragma unroll
        for (int nb = 0; nb < NPB; nb++) {
            acc[nb][0] += hl[nb][d] * w0;
            acc[nb][1] += hl[nb][d] * w1;
        }
    }
    for (int nb = 0; nb < NPB; nb++) {
        feat[(n0 + nb) * H1 + o0] = acc[nb][0];
        feat[(n0 + nb) * H1 + o1] = acc[nb][1];
    }
}

// ---- el/er per node per head ----
__global__ void el_er_kernel(const float* __restrict__ feat, const float* __restrict__ attn_l,
                             const float* __restrict__ attn_r, float* __restrict__ el,
                             float* __restrict__ er) {
    __shared__ float red[4 * 256];
    int n = blockIdx.x, t = threadIdx.x;
    float f0 = feat[n * H1 + t], f1 = feat[n * H1 + 256 + t];
    red[t]         = f0 * attn_l[t];
    red[256 + t]   = f1 * attn_l[256 + t];
    red[512 + t]   = f0 * attn_r[t];
    red[768 + t]   = f1 * attn_r[256 + t];
    __syncthreads();
    for (int off = 128; off > 0; off >>= 1) {
        if (t < off) {
#pragma unroll
            for (int j = 0; j < 4; j++) red[j * 256 + t] += red[j * 256 + t + off];
        }
        __syncthreads();
    }
    if (t == 0) {
        el[n * 2 + 0] = red[0];
        el[n * 2 + 1] = red[256];
        er[n * 2 + 0] = red[512];
        er[n * 2 + 1] = red[768];
    }
}

__global__ void init_neg_inf(float* __restrict__ p, int n) {
    int i = blockIdx.x * 256 + threadIdx.x;
    if (i < n) p[i] = -INFINITY;
}

// ---- edge scores + segment max ----
__global__ void edge_score(const int* __restrict__ src, const int* __restrict__ dst,
                           const float* __restrict__ el, const float* __restrict__ er,
                           float* __restrict__ escore, float* __restrict__ emax) {
    int idx = blockIdx.x * 256 + threadIdx.x;
    if (idx >= EE * NHEADS) return;
    int e = idx >> 1, hd = idx & 1;
    float sc = el[src[e] * 2 + hd] + er[dst[e] * 2 + hd];
    sc = sc < 0.f ? 0.2f * sc : sc;
    escore[idx] = sc;
    atomicMaxF(&emax[dst[e] * 2 + hd], sc);
}

// ---- exp(e - emax[dst]) in place + denom ----
__global__ void edge_exp(const int* __restrict__ dst, float* __restrict__ escore,
                         const float* __restrict__ emax, float* __restrict__ denom) {
    int idx = blockIdx.x * 256 + threadIdx.x;
    if (idx >= EE * NHEADS) return;
    int e = idx >> 1, hd = idx & 1;
    float v = expf(escore[idx] - emax[dst[e] * 2 + hd]);
    escore[idx] = v;
    atomicAdd(&denom[dst[e] * 2 + hd], v);
}

// ---- alpha = ee/denom in place ----
__global__ void edge_norm(const int* __restrict__ dst, float* __restrict__ escore,
                          const float* __restrict__ denom) {
    int idx = blockIdx.x * 256 + threadIdx.x;
    if (idx >= EE * NHEADS) return;
    int e = idx >> 1, hd = idx & 1;
    escore[idx] = escore[idx] / denom[dst[e] * 2 + hd];
}

// ---- rst[dst,:] += alpha * feat[src,:] ----
__global__ void edge_agg(const int* __restrict__ src, const int* __restrict__ dst,
                         const float* __restrict__ escore, const float* __restrict__ feat,
                         float* __restrict__ rst) {
    int idx = blockIdx.x * 256 + threadIdx.x;
    if (idx >= EE * H1) return;
    int e = idx >> 9, d = idx & 511, hd = d >> 8;
    float alpha = escore[e * 2 + hd];
    atomicAdd(&rst[dst[e] * H1 + d], alpha * feat[src[e] * H1 + d]);
}

// ---- relu(rst + bias) then per-graph sum ----
__global__ void bias_relu_gsum(const float* __restrict__ rst, const float* __restrict__ gat_bias,
                               const int* __restrict__ graph_ids, float* __restrict__ hg,
                               float* __restrict__ gcnt) {
    int idx = blockIdx.x * 256 + threadIdx.x;
    if (idx >= NN * H1) return;
    int n = idx >> 9, d = idx & 511;
    float v = fmaxf(rst[idx] + gat_bias[d], 0.f);
    int g = graph_ids[n];
    atomicAdd(&hg[g * H1 + d], v);
    if (d == 0) atomicAdd(&gcnt[g], 1.f);
}

// ---- per-graph mean + classifier, f32 out ----
__global__ void classify(const float* __restrict__ hg, const float* __restrict__ gcnt,
                         const float* __restrict__ cw, const float* __restrict__ cb,
                         float* __restrict__ out) {
    __shared__ float hl[H1];
    int g = blockIdx.x, t = threadIdx.x;  // 64 threads
    float inv = 1.f / fmaxf(gcnt[g], 1.f);
    for (int d = t; d < H1; d += 64) hl[d] = hg[g * H1 + d] * inv;
    __syncthreads();
    if (t < 32) {
        int hd = t >> 4, c = t & 15;
        float acc = 0.f;
        for (int d = 0; d < H2; d++) acc += hl[hd * H2 + d] * cw[c * H2 + d];
        acc += cb[c];
        out[(g * NHEADS + hd) * NC + c] = acc;
    }
}

static inline int cdiv(int a, int b) { return (a + b - 1) / b; }

extern "C" void kernel_launch(void* const* d_in, const int* in_sizes, int n_in,
                              void* d_out, int out_size, void* d_ws, size_t ws_size,
                              hipStream_t stream) {
    const float* in_feat   = (const float*)d_in[0];
    const int*   src       = (const int*)d_in[1];
    const int*   dst       = (const int*)d_in[2];
    const int*   etype     = (const int*)d_in[3];
    const int*   graph_ids = (const int*)d_in[4];
    const float* Wmsg      = (const float*)d_in[5];
    const float* bmsg      = (const float*)d_in[6];
    const float* w_ih      = (const float*)d_in[7];
    const float* w_hh      = (const float*)d_in[8];
    const float* b_ih      = (const float*)d_in[9];
    const float* b_hh      = (const float*)d_in[10];
    const float* fc_w      = (const float*)d_in[11];
    const float* attn_l    = (const float*)d_in[12];
    const float* attn_r    = (const float*)d_in[13];
    const float* gat_bias  = (const float*)d_in[14];
    const float* cw        = (const float*)d_in[15];
    const float* cb        = (const float*)d_in[16];
    float* out = (float*)d_out;

    char* p = (char*)d_ws;
    float* h     = (float*)p; p += (size_t)NN * H1 * 4;
    float* a     = (float*)p; p += (size_t)NN * H1 * 4;
    float* S     = (float*)p; p += (size_t)NN * H1 * 4;
    float* cntk  = (float*)p; p += (size_t)NN * 4;
    float* el    = (float*)p; p += (size_t)NN * 2 * 4;
    float* er    = (float*)p; p += (size_t)NN * 2 * 4;
    float* emax  = (float*)p; p += (size_t)NN * 2 * 4;
    float* denom = (float*)p; p += (size_t)NN * 2 * 4;
    float* esc   = (float*)p; p += (size_t)EE * 2 * 4;
    float* hg    = (float*)p; p += (size_t)GG * H1 * 4;
    float* gcnt  = (float*)p; p += (size_t)GG * 4;
    float* wihT  = (float*)p; p += (size_t)1536 * 512 * 4;
    float* whhT  = (float*)p; p += (size_t)1536 * 512 * 4;
    float* fcT   = (float*)p; p += (size_t)512 * 512 * 4;
    float* feat  = S;  // alias: S free after message-passing steps
    float* rst   = a;  // alias: a free after last GRU

    // weight transposes (once per launch)
    transpose_kernel<<<cdiv(1536 * 512, 256), 256, 0, stream>>>(w_ih, wihT, 1536, 512);
    transpose_kernel<<<cdiv(1536 * 512, 256), 256, 0, stream>>>(w_hh, whhT, 1536, 512);
    transpose_kernel<<<cdiv(512 * 512, 256), 256, 0, stream>>>(fc_w, fcT, 512, 512);

    pad_kernel<<<cdiv(NN * H1, 256), 256, 0, stream>>>(in_feat, h);

    for (int step = 0; step < NSTEPS; step++) {
        hipMemsetAsync(a, 0, (size_t)NN * H1 * 4, stream);
        for (int k = 0; k < KT; k++) {
            hipMemsetAsync(S, 0, (size_t)NN * H1 * 4, stream);
            hipMemsetAsync(cntk, 0, (size_t)NN * 4, stream);
            scatter_k<<<cdiv(EE * H1, 256), 256, 0, stream>>>(src, dst, etype, h, S, cntk, k);
            gemm_msg<<<NN / NPB, 256, 0, stream>>>(S, cntk, Wmsg, bmsg, a, k);
        }
        gru_kernel<<<NN / NPB, 256, 0, stream>>>(a, h, wihT, whhT, b_ih, b_hh);
    }

    norm_sigmoid<<<NN, 256, 0, stream>>>(h);
    feat_gemm<<<NN / NPB, 256, 0, stream>>>(h, fcT, feat);
    el_er_kernel<<<NN, 256, 0, stream>>>(feat, attn_l, attn_r, el, er);

    init_neg_inf<<<cdiv(NN * 2, 256), 256, 0, stream>>>(emax, NN * 2);
    hipMemsetAsync(denom, 0, (size_t)NN * 2 * 4, stream);
    edge_score<<<cdiv(EE * 2, 256), 256, 0, stream>>>(src, dst, el, er, esc, emax);
    edge_exp<<<cdiv(EE * 2, 256), 256, 0, stream>>>(dst, esc, emax, denom);
    edge_norm<<<cdiv(EE * 2, 256), 256, 0, stream>>>(dst, esc, denom);

    hipMemsetAsync(rst, 0, (size_t)NN * H1 * 4, stream);
    edge_agg<<<cdiv(EE * H1, 256), 256, 0, stream>>>(src, dst, esc, feat, rst);

    hipMemsetAsync(hg, 0, (size_t)GG * H1 * 4, stream);
    hipMemsetAsync(gcnt, 0, (size_t)GG * 4, stream);
    bias_relu_gsum<<<cdiv(NN * H1, 256), 256, 0, stream>>>(rst, gat_bias, graph_ids, hg, gcnt);
    classify<<<GG, 64, 0, stream>>>(hg, gcnt, cw, cb, out);
}

// Round 3
// 2725.457 us; speedup vs baseline: 5.0913x; 5.0913x over previous
//
#include <hip/hip_runtime.h>
#include <math.h>

#define NN 20000
#define NP 20096           // NN padded to 128
#define EE 320000
#define GG 64
#define IN_F 256
#define H1 512
#define NC 16
#define NSTEPS 4
#define KT 4
#define TOTKV (KT*NP)      // 80384

typedef unsigned int uint;
typedef unsigned short ushort;
typedef __attribute__((ext_vector_type(4))) float f4;
typedef __attribute__((ext_vector_type(4))) ushort u16x4;
typedef __attribute__((ext_vector_type(4))) uint u32x4;
typedef __attribute__((ext_vector_type(8))) short s16x8;

__device__ __forceinline__ ushort f2b(float f) {
    uint u = __float_as_uint(f);
    u = (u + 0x7FFFu + ((u >> 16) & 1u)) >> 16;   // RNE f32->bf16
    return (ushort)u;
}
__device__ __forceinline__ float b2f(ushort s) { return __uint_as_float(((uint)s) << 16); }
__device__ __forceinline__ float sgm(float x) { return 1.f / (1.f + __expf(-x)); }

// ---------- weight prep ----------
__global__ void conv_msgT(const float* __restrict__ Wm, ushort* __restrict__ WT) {
    // WT[k][o][d] <- Wmsg[k][d][o]
    int idx = blockIdx.x * 256 + threadIdx.x;
    if (idx >= KT * 512 * 512) return;
    int k = idx >> 18, rem = idx & 262143;
    int o = rem >> 9, d = rem & 511;
    WT[idx] = f2b(Wm[(k << 18) + (d << 9) + o]);
}
__global__ void conv_copy(const float* __restrict__ x, ushort* __restrict__ y, int n) {
    int i = blockIdx.x * 256 + threadIdx.x;
    if (i < n) y[i] = f2b(x[i]);
}
__global__ void conv_f2b(const float* __restrict__ x, ushort* __restrict__ y, int n4) {
    int i = blockIdx.x * 256 + threadIdx.x;
    if (i >= n4) return;
    f4 v = *(const f4*)(x + (size_t)i * 4);
    u16x4 p = { f2b(v[0]), f2b(v[1]), f2b(v[2]), f2b(v[3]) };
    *(u16x4*)(y + (size_t)i * 4) = p;
}

// ---------- CSR build (etype-major, dst-minor) ----------
__global__ void count_edges(const int* __restrict__ etype, const int* __restrict__ dst,
                            int* __restrict__ cnt) {
    int e = blockIdx.x * 256 + threadIdx.x;
    if (e >= EE) return;
    atomicAdd(&cnt[etype[e] * NP + dst[e]], 1);
}
__global__ __launch_bounds__(1024) void scan_kernel(const int* __restrict__ cnt,
                                                    int* __restrict__ offs,
                                                    float* __restrict__ cntf) {
    __shared__ int part[1024];
    int t = threadIdx.x;
    const int chunk = (TOTKV + 1023) / 1024;
    int b = t * chunk, e = b + chunk; if (e > TOTKV) e = TOTKV; if (b > TOTKV) b = TOTKV;
    int s = 0;
    for (int i = b; i < e; i++) s += cnt[i];
    part[t] = s; __syncthreads();
    for (int off = 1; off < 1024; off <<= 1) {
        int v = part[t];
        int add = (t >= off) ? part[t - off] : 0;
        __syncthreads();
        part[t] = v + add;
        __syncthreads();
    }
    int run = part[t] - s;  // exclusive prefix
    for (int i = b; i < e; i++) { offs[i] = run; cntf[i] = (float)cnt[i]; run += cnt[i]; }
    if (t == 1023) offs[TOTKV] = part[1023];
}
__global__ void fill_edges(const int* __restrict__ etype, const int* __restrict__ dst,
                           const int* __restrict__ src, int* __restrict__ cursor,
                           int* __restrict__ srcs_s) {
    int e = blockIdx.x * 256 + threadIdx.x;
    if (e >= EE) return;
    int pos = atomicAdd(&cursor[etype[e] * NP + dst[e]], 1);
    srcs_s[pos] = src[e];
}

// ---------- pad input ----------
__global__ void pad_kernel(const float* __restrict__ in_feat, float* __restrict__ h) {
    int idx = blockIdx.x * 256 + threadIdx.x;
    if (idx >= NN * H1) return;
    int n = idx >> 9, d = idx & 511;
    h[idx] = (d < IN_F) ? in_feat[n * IN_F + d] : 0.f;
}

// ---------- per-(step,k) gather-sum: S[v] = sum over in-edges of etype k of h[src], bf16 out ----------
__global__ void gather_S(const int* __restrict__ offs, const int* __restrict__ srcs,
                         const float* __restrict__ h, ushort* __restrict__ S, int k) {
    int wave = threadIdx.x >> 6, lane = threadIdx.x & 63;
    int v = blockIdx.x * 4 + wave;
    int beg = offs[k * NP + v], end = offs[k * NP + v + 1];
    f4 a0 = {0,0,0,0}, a1 = {0,0,0,0};
    for (int e = beg; e < end; e++) {
        int s = srcs[e];
        const f4* hp = (const f4*)(h + (size_t)s * 512);
        a0 += hp[lane];
        a1 += hp[64 + lane];
    }
    u16x4 p0 = { f2b(a0[0]), f2b(a0[1]), f2b(a0[2]), f2b(a0[3]) };
    u16x4 p1 = { f2b(a1[0]), f2b(a1[1]), f2b(a1[2]), f2b(a1[3]) };
    *(u16x4*)(S + (size_t)v * 512 + lane * 4) = p0;
    *(u16x4*)(S + (size_t)v * 512 + 256 + lane * 4) = p1;
}

// ---------- MFMA GEMM: C[node][o] (=|+=) X@W^T via D[o][node]; W bf16 [512o][512d], X bf16 [NP][512d] ----------
__global__ __launch_bounds__(256) void gemm_oT(
    const ushort* __restrict__ W, const ushort* __restrict__ X, float* __restrict__ C,
    const float* __restrict__ bias, const float* __restrict__ cntv, int accumulate) {
    __shared__ ushort As[128][72];
    __shared__ ushort Bs[128][72];
    int t = threadIdx.x;
    int n0 = blockIdx.x * 128, o0 = blockIdx.y * 128;
    int wave = t >> 6, lane = t & 63;
    int wm = wave & 1, wn = wave >> 1;
    int l16 = lane & 15, quad = lane >> 4;
    f4 acc[4][4];
#pragma unroll
    for (int i = 0; i < 4; i++)
#pragma unroll
        for (int j = 0; j < 4; j++) acc[i][j] = (f4){0,0,0,0};
    for (int kk = 0; kk < 512; kk += 64) {
        for (int i = t; i < 1024; i += 256) {
            int row = i >> 3, c8 = (i & 7) << 3;
            *(u32x4*)&As[row][c8] = *(const u32x4*)(W + (size_t)(o0 + row) * 512 + kk + c8);
            *(u32x4*)&Bs[row][c8] = *(const u32x4*)(X + (size_t)(n0 + row) * 512 + kk + c8);
        }
        __syncthreads();
#pragma unroll
        for (int ks = 0; ks < 64; ks += 32) {
            s16x8 af[4], bf[4];
#pragma unroll
            for (int mi = 0; mi < 4; mi++) af[mi] = *(const s16x8*)&As[wm*64 + mi*16 + l16][ks + quad*8];
#pragma unroll
            for (int ni = 0; ni < 4; ni++) bf[ni] = *(const s16x8*)&Bs[wn*64 + ni*16 + l16][ks + quad*8];
#pragma unroll
            for (int mi = 0; mi < 4; mi++)
#pragma unroll
                for (int ni = 0; ni < 4; ni++)
                    acc[mi][ni] = __builtin_amdgcn_mfma_f32_16x16x32_bf16(af[mi], bf[ni], acc[mi][ni], 0, 0, 0);
        }
        __syncthreads();
    }
#pragma unroll
    for (int ni = 0; ni < 4; ni++) {
        int node = n0 + wn*64 + ni*16 + l16;
        float cf = cntv ? cntv[node] : 0.f;
#pragma unroll
        for (int mi = 0; mi < 4; mi++) {
            int o = o0 + wm*64 + mi*16 + quad*4;
            f4 v = acc[mi][ni];
            if (bias) { f4 bv = *(const f4*)(bias + o); v += cf * bv; }
            float* cp = C + (size_t)node * 512 + o;
            if (accumulate) { f4 old = *(const f4*)cp; v += old; }
            *(f4*)cp = v;
        }
    }
}

// ---------- fused GRU: h = GRU(a, h), 6 weight stripes, epilogue nonlinearity ----------
__global__ __launch_bounds__(256) void gru_mfma(
    const ushort* __restrict__ wih, const ushort* __restrict__ whh,
    const ushort* __restrict__ abf, const ushort* __restrict__ hbf,
    const float* __restrict__ b_ih, const float* __restrict__ b_hh,
    float* __restrict__ h) {
    __shared__ ushort Ws[6][64][72];
    __shared__ ushort Ab[64][72];
    __shared__ ushort Hb[64][72];
    int t = threadIdx.x;
    int n0 = blockIdx.x * 64, o0 = blockIdx.y * 64;
    int wave = t >> 6, lane = t & 63;
    int l16 = lane & 15, quad = lane >> 4;
    int wo = wave * 16;
    f4 acc[6][4];
#pragma unroll
    for (int s = 0; s < 6; s++)
#pragma unroll
        for (int ni = 0; ni < 4; ni++) acc[s][ni] = (f4){0,0,0,0};
    for (int kk = 0; kk < 512; kk += 64) {
        for (int i = t; i < 3072; i += 256) {
            int s = i >> 9, rem = i & 511;
            int row = rem >> 3, c8 = (rem & 7) << 3;
            const ushort* g = (s < 3)
                ? wih + (size_t)(s * 512 + o0 + row) * 512 + kk + c8
                : whh + (size_t)((s - 3) * 512 + o0 + row) * 512 + kk + c8;
            *(u32x4*)&Ws[s][row][c8] = *(const u32x4*)g;
        }
        for (int i = t; i < 512; i += 256) {
            int row = i >> 3, c8 = (i & 7) << 3;
            *(u32x4*)&Ab[row][c8] = *(const u32x4*)(abf + (size_t)(n0 + row) * 512 + kk + c8);
        }
        for (int i = t; i < 512; i += 256) {
            int row = i >> 3, c8 = (i & 7) << 3;
            *(u32x4*)&Hb[row][c8] = *(const u32x4*)(hbf + (size_t)(n0 + row) * 512 + kk + c8);
        }
        __syncthreads();
#pragma unroll
        for (int ks = 0; ks < 64; ks += 32) {
            s16x8 wf[6], af_[4], hf[4];
#pragma unroll
            for (int s = 0; s < 6; s++) wf[s] = *(const s16x8*)&Ws[s][wo + l16][ks + quad*8];
#pragma unroll
            for (int ni = 0; ni < 4; ni++) {
                af_[ni] = *(const s16x8*)&Ab[ni*16 + l16][ks + quad*8];
                hf[ni]  = *(const s16x8*)&Hb[ni*16 + l16][ks + quad*8];
            }
#pragma unroll
            for (int s = 0; s < 6; s++)
#pragma unroll
                for (int ni = 0; ni < 4; ni++)
                    acc[s][ni] = __builtin_amdgcn_mfma_f32_16x16x32_bf16(
                        wf[s], (s < 3 ? af_[ni] : hf[ni]), acc[s][ni], 0, 0, 0);
        }
        __syncthreads();
    }
    int o = o0 + wo + quad * 4;
    f4 bi0 = *(const f4*)(b_ih + o);
    f4 bi1 = *(const f4*)(b_ih + 512 + o);
    f4 bi2 = *(const f4*)(b_ih + 1024 + o);
    f4 bh0 = *(const f4*)(b_hh + o);
    f4 bh1 = *(const f4*)(b_hh + 512 + o);
    f4 bh2 = *(const f4*)(b_hh + 1024 + o);
#pragma unroll
    for (int ni = 0; ni < 4; ni++) {
        int node = n0 + ni*16 + l16;
        u16x4 hv4 = *(const u16x4*)(hbf + (size_t)node * 512 + o);
        f4 outv;
#pragma unroll
        for (int r = 0; r < 4; r++) {
            float rg = sgm(acc[0][ni][r] + bi0[r] + acc[3][ni][r] + bh0[r]);
            float zg = sgm(acc[1][ni][r] + bi1[r] + acc[4][ni][r] + bh1[r]);
            float ng = tanhf(acc[2][ni][r] + bi2[r] + rg * (acc[5][ni][r] + bh2[r]));
            outv[r] = (1.f - zg) * ng + zg * b2f(hv4[r]);
        }
        *(f4*)(h + (size_t)node * 512 + o) = outv;
    }
}

// ---------- L2 normalize + sigmoid; writes f32 h and bf16 hbf ----------
__global__ void norm_sigmoid(float* __restrict__ h, ushort* __restrict__ hbf) {
    __shared__ float red[256];
    int n = blockIdx.x, t = threadIdx.x;
    float v0 = h[n * 512 + t], v1 = h[n * 512 + 256 + t];
    red[t] = v0 * v0 + v1 * v1;
    __syncthreads();
    for (int off = 128; off > 0; off >>= 1) {
        if (t < off) red[t] += red[t + off];
        __syncthreads();
    }
    float inv = 1.f / fmaxf(sqrtf(red[0]), 1e-12f);
    float s0 = sgm(v0 * inv), s1 = sgm(v1 * inv);
    h[n * 512 + t] = s0;       hbf[n * 512 + t] = f2b(s0);
    h[n * 512 + 256 + t] = s1; hbf[n * 512 + 256 + t] = f2b(s1);
}

// ---------- el/er ----------
__global__ void el_er_kernel(const float* __restrict__ feat, const float* __restrict__ attn_l,
                             const float* __restrict__ attn_r, float* __restrict__ el,
                             float* __restrict__ er) {
    __shared__ float red[4 * 256];
    int n = blockIdx.x, t = threadIdx.x;
    float f0 = feat[n * 512 + t], f1 = feat[n * 512 + 256 + t];
    red[t]       = f0 * attn_l[t];
    red[256 + t] = f1 * attn_l[256 + t];
    red[512 + t] = f0 * attn_r[t];
    red[768 + t] = f1 * attn_r[256 + t];
    __syncthreads();
    for (int off = 128; off > 0; off >>= 1) {
        if (t < off) {
#pragma unroll
            for (int j = 0; j < 4; j++) red[j * 256 + t] += red[j * 256 + t + off];
        }
        __syncthreads();
    }
    if (t == 0) {
        el[n * 2 + 0] = red[0];   el[n * 2 + 1] = red[256];
        er[n * 2 + 0] = red[512]; er[n * 2 + 1] = red[768];
    }
}

// ---------- fused GAT: per-node softmax + aggregation + bias/relu + graph pooling ----------
__global__ void gat_fused(const int* __restrict__ offs, const int* __restrict__ srcs,
                          const float* __restrict__ el, const float* __restrict__ er,
                          const float* __restrict__ feat, const float* __restrict__ gat_bias,
                          const int* __restrict__ graph_ids,
                          float* __restrict__ hg, float* __restrict__ gcnt) {
    int wave = threadIdx.x >> 6, lane = threadIdx.x & 63;
    int v = blockIdx.x * 4 + wave;
    float er0 = er[v * 2], er1 = er[v * 2 + 1];
    float m0 = -1e30f, m1 = -1e30f;
    int deg = 0;
    for (int k = 0; k < KT; k++) {
        int beg = offs[k * NP + v], end = offs[k * NP + v + 1];
        deg += end - beg;
        for (int base = beg; base < end; base += 64) {
            int e = base + lane;
            if (e < end) {
                int s = srcs[e];
                float s0 = el[s * 2] + er0;     s0 = s0 < 0.f ? 0.2f * s0 : s0;
                float s1 = el[s * 2 + 1] + er1; s1 = s1 < 0.f ? 0.2f * s1 : s1;
                m0 = fmaxf(m0, s0); m1 = fmaxf(m1, s1);
            }
        }
    }
    for (int off = 32; off > 0; off >>= 1) {
        m0 = fmaxf(m0, __shfl_xor(m0, off));
        m1 = fmaxf(m1, __shfl_xor(m1, off));
    }
    float d0 = 0.f, d1 = 0.f;
    for (int k = 0; k < KT; k++) {
        int beg = offs[k * NP + v], end = offs[k * NP + v + 1];
        for (int base = beg; base < end; base += 64) {
            int e = base + lane;
            if (e < end) {
                int s = srcs[e];
                float s0 = el[s * 2] + er0;     s0 = s0 < 0.f ? 0.2f * s0 : s0;
                float s1 = el[s * 2 + 1] + er1; s1 = s1 < 0.f ? 0.2f * s1 : s1;
                d0 += __expf(s0 - m0); d1 += __expf(s1 - m1);
            }
        }
    }
    for (int off = 32; off > 0; off >>= 1) { d0 += __shfl_xor(d0, off); d1 += __shfl_xor(d1, off); }
    f4 acc0 = {0,0,0,0}, acc1 = {0,0,0,0};
    if (deg > 0) {
        float i0 = 1.f / d0, i1 = 1.f / d1;
        for (int k = 0; k < KT; k++) {
            int beg = offs[k * NP + v], end = offs[k * NP + v + 1];
            for (int e = beg; e < end; e++) {
                int s = srcs[e];
                float s0 = el[s * 2] + er0;     s0 = s0 < 0.f ? 0.2f * s0 : s0;
                float s1 = el[s * 2 + 1] + er1; s1 = s1 < 0.f ? 0.2f * s1 : s1;
                float al0 = __expf(s0 - m0) * i0, al1 = __expf(s1 - m1) * i1;
                const f4* fp = (const f4*)(feat + (size_t)s * 512);
                acc0 += al0 * fp[lane];
                acc1 += al1 * fp[64 + lane];
            }
        }
    }
    int g = graph_ids[v];
    int di = lane * 4;
    f4 gb0 = *(const f4*)(gat_bias + di);
    f4 gb1 = *(const f4*)(gat_bias + 256 + di);
#pragma unroll
    for (int r = 0; r < 4; r++) {
        atomicAdd(&hg[g * 512 + di + r],       fmaxf(acc0[r] + gb0[r], 0.f));
        atomicAdd(&hg[g * 512 + 256 + di + r], fmaxf(acc1[r] + gb1[r], 0.f));
    }
    if (lane == 0) atomicAdd(&gcnt[g], 1.f);
}

// ---------- classify ----------
__global__ void classify(const float* __restrict__ hg, const float* __restrict__ gcnt,
                         const float* __restrict__ cw, const float* __restrict__ cb,
                         float* __restrict__ out) {
    __shared__ float hl[512];
    int g = blockIdx.x, t = threadIdx.x;  // 64 threads
    float inv = 1.f / fmaxf(gcnt[g], 1.f);
    for (int d = t; d < 512; d += 64) hl[d] = hg[g * 512 + d] * inv;
    __syncthreads();
    if (t < 32) {
        int hd = t >> 4, c = t & 15;
        float acc = 0.f;
        for (int d = 0; d < 256; d++) acc += hl[hd * 256 + d] * cw[c * 256 + d];
        out[(g * 2 + hd) * NC + c] = acc + cb[c];
    }
}

static inline int cdiv(int a, int b) { return (a + b - 1) / b; }
static inline size_t alup(size_t x) { return (x + 255) & ~(size_t)255; }

extern "C" void kernel_launch(void* const* d_in, const int* in_sizes, int n_in,
                              void* d_out, int out_size, void* d_ws, size_t ws_size,
                              hipStream_t stream) {
    const float* in_feat   = (const float*)d_in[0];
    const int*   src       = (const int*)d_in[1];
    const int*   dst       = (const int*)d_in[2];
    const int*   etype     = (const int*)d_in[3];
    const int*   graph_ids = (const int*)d_in[4];
    const float* Wmsg      = (const float*)d_in[5];
    const float* bmsg      = (const float*)d_in[6];
    const float* w_ih      = (const float*)d_in[7];
    const float* w_hh      = (const float*)d_in[8];
    const float* b_ih      = (const float*)d_in[9];
    const float* b_hh      = (const float*)d_in[10];
    const float* fc_w      = (const float*)d_in[11];
    const float* attn_l    = (const float*)d_in[12];
    const float* attn_r    = (const float*)d_in[13];
    const float* gat_bias  = (const float*)d_in[14];
    const float* cw        = (const float*)d_in[15];
    const float* cb        = (const float*)d_in[16];
    float* out = (float*)d_out;

    char* p = (char*)d_ws;
    float*  h     = (float*)p;  p += alup((size_t)NP * 512 * 4);
    float*  a     = (float*)p;  p += alup((size_t)NP * 512 * 4);
    ushort* S     = (ushort*)p; p += alup((size_t)NP * 512 * 2);  // per-k gather out; later abf
    ushort* hbf   = (ushort*)p; p += alup((size_t)NP * 512 * 2);
    ushort* wmsgT = (ushort*)p; p += alup((size_t)KT * 512 * 512 * 2);
    ushort* wihb  = (ushort*)p; p += alup((size_t)1536 * 512 * 2);
    ushort* whhb  = (ushort*)p; p += alup((size_t)1536 * 512 * 2);
    ushort* fcb   = (ushort*)p; p += alup((size_t)512 * 512 * 2);
    int*    cnt   = (int*)p;    p += alup((size_t)TOTKV * 4);
    int*    offs  = (int*)p;    p += alup(((size_t)TOTKV + 1) * 4);
    int*    cursor= (int*)p;    p += alup(((size_t)TOTKV + 1) * 4);
    float*  cntf  = (float*)p;  p += alup((size_t)TOTKV * 4);
    int*    srcs_s= (int*)p;    p += alup((size_t)EE * 4);
    float*  el    = (float*)p;  p += alup((size_t)NN * 2 * 4);
    float*  er    = (float*)p;  p += alup((size_t)NN * 2 * 4);
    float*  hg    = (float*)p;  p += alup((size_t)GG * 512 * 4);
    float*  gcnt  = (float*)p;  p += alup((size_t)GG * 4);
    float*  feat  = a;   // alias: a free after last GRU

    // weight prep
    conv_msgT<<<cdiv(KT * 512 * 512, 256), 256, 0, stream>>>(Wmsg, wmsgT);
    conv_copy<<<cdiv(1536 * 512, 256), 256, 0, stream>>>(w_ih, wihb, 1536 * 512);
    conv_copy<<<cdiv(1536 * 512, 256), 256, 0, stream>>>(w_hh, whhb, 1536 * 512);
    conv_copy<<<cdiv(512 * 512, 256), 256, 0, stream>>>(fc_w, fcb, 512 * 512);

    // CSR build
    hipMemsetAsync(cnt, 0, (size_t)TOTKV * 4, stream);
    count_edges<<<cdiv(EE, 256), 256, 0, stream>>>(etype, dst, cnt);
    scan_kernel<<<1, 1024, 0, stream>>>(cnt, offs, cntf);
    hipMemcpyAsync(cursor, offs, (size_t)TOTKV * 4, hipMemcpyDeviceToDevice, stream);
    fill_edges<<<cdiv(EE, 256), 256, 0, stream>>>(etype, dst, src, cursor, srcs_s);

    pad_kernel<<<cdiv(NN * 512, 256), 256, 0, stream>>>(in_feat, h);

    const int N4 = NP * 512 / 4;
    for (int step = 0; step < NSTEPS; step++) {
        conv_f2b<<<cdiv(N4, 256), 256, 0, stream>>>(h, hbf, N4);
        for (int k = 0; k < KT; k++) {
            gather_S<<<NP / 4, 256, 0, stream>>>(offs, srcs_s, h, S, k);
            gemm_oT<<<dim3(NP / 128, 4), 256, 0, stream>>>(
                wmsgT + (size_t)k * 512 * 512, S, a, bmsg + k * 512, cntf + (size_t)k * NP, k > 0);
        }
        conv_f2b<<<cdiv(N4, 256), 256, 0, stream>>>(a, S /* abf */, N4);
        gru_mfma<<<dim3(NP / 64, 8), 256, 0, stream>>>(wihb, whhb, S, hbf, b_ih, b_hh, h);
    }

    norm_sigmoid<<<NN, 256, 0, stream>>>(h, hbf);
    gemm_oT<<<dim3(NP / 128, 4), 256, 0, stream>>>(fcb, hbf, feat, nullptr, nullptr, 0);
    el_er_kernel<<<NN, 256, 0, stream>>>(feat, attn_l, attn_r, el, er);

    hipMemsetAsync(hg, 0, (size_t)GG * 512 * 4, stream);
    hipMemsetAsync(gcnt, 0, (size_t)GG * 4, stream);
    gat_fused<<<NN / 4, 256, 0, stream>>>(offs, srcs_s, el, er, feat, gat_bias, graph_ids, hg, gcnt);
    classify<<<GG, 64, 0, stream>>>(hg, gcnt, cw, cb, out);
}

// Round 4
// 2413.985 us; speedup vs baseline: 5.7483x; 1.1290x over previous
//
#include <hip/hip_runtime.h>
#include <math.h>

#define NN 20000
#define NP 20096           // NN padded to 128 (157 tiles)
#define EE 320000
#define GG 64
#define IN_F 256
#define NC 16
#define NSTEPS 4
#define KT 4
#define TOTKV (KT*NP)      // 80384

typedef unsigned int uint;
typedef unsigned short ushort;
typedef __attribute__((ext_vector_type(4))) float f4;
typedef __attribute__((ext_vector_type(4))) ushort u16x4;
typedef __attribute__((ext_vector_type(8))) ushort u16x8;
typedef __attribute__((ext_vector_type(4))) uint u32x4;
typedef __attribute__((ext_vector_type(8))) short s16x8;

__device__ __forceinline__ ushort f2b(float f) {
    uint u = __float_as_uint(f);
    u = (u + 0x7FFFu + ((u >> 16) & 1u)) >> 16;   // RNE f32->bf16
    return (ushort)u;
}
__device__ __forceinline__ float b2f(ushort s) { return __uint_as_float(((uint)s) << 16); }
__device__ __forceinline__ float sgm(float x) { return 1.f / (1.f + __expf(-x)); }

// ---------- weight prep ----------
__global__ void conv_msgT(const float* __restrict__ Wm, ushort* __restrict__ WT) {
    // WT[k][o][d] <- Wmsg[k][d][o]
    int idx = blockIdx.x * 256 + threadIdx.x;
    if (idx >= KT * 512 * 512) return;
    int k = idx >> 18, rem = idx & 262143;
    int o = rem >> 9, d = rem & 511;
    WT[idx] = f2b(Wm[(k << 18) + (d << 9) + o]);
}
__global__ void conv_copy(const float* __restrict__ x, ushort* __restrict__ y, int n) {
    int i = blockIdx.x * 256 + threadIdx.x;
    if (i < n) y[i] = f2b(x[i]);
}
// Wrz[o2][k2]: o2<512 -> r-gate rows, o2>=512 -> z-gate; k2<512 from w_ih, else w_hh
__global__ void build_wrz(const float* __restrict__ wih, const float* __restrict__ whh,
                          ushort* __restrict__ W) {
    int idx = blockIdx.x * 256 + threadIdx.x;
    if (idx >= 1024 * 1024) return;
    int o2 = idx >> 10, k2 = idx & 1023;
    int gate = o2 >> 9, o = o2 & 511;
    float v = (k2 < 512) ? wih[(gate * 512 + o) * 512 + k2]
                         : whh[(gate * 512 + o) * 512 + (k2 - 512)];
    W[idx] = f2b(v);
}

// ---------- CSR build (etype-major, dst-minor) ----------
__global__ void count_edges(const int* __restrict__ etype, const int* __restrict__ dst,
                            int* __restrict__ cnt) {
    int e = blockIdx.x * 256 + threadIdx.x;
    if (e >= EE) return;
    atomicAdd(&cnt[etype[e] * NP + dst[e]], 1);
}
__global__ __launch_bounds__(1024) void scan_kernel(const int* __restrict__ cnt,
                                                    int* __restrict__ offs,
                                                    float* __restrict__ cntf) {
    __shared__ int part[1024];
    int t = threadIdx.x;
    const int chunk = (TOTKV + 1023) / 1024;
    int b = t * chunk, e = b + chunk; if (e > TOTKV) e = TOTKV; if (b > TOTKV) b = TOTKV;
    int s = 0;
    for (int i = b; i < e; i++) s += cnt[i];
    part[t] = s; __syncthreads();
    for (int off = 1; off < 1024; off <<= 1) {
        int v = part[t];
        int add = (t >= off) ? part[t - off] : 0;
        __syncthreads();
        part[t] = v + add;
        __syncthreads();
    }
    int run = part[t] - s;  // exclusive prefix
    for (int i = b; i < e; i++) { offs[i] = run; cntf[i] = (float)cnt[i]; run += cnt[i]; }
    if (t == 1023) offs[TOTKV] = part[1023];
}
__global__ void fill_edges(const int* __restrict__ etype, const int* __restrict__ dst,
                           const int* __restrict__ src, int* __restrict__ cursor,
                           int* __restrict__ srcs_s) {
    int e = blockIdx.x * 256 + threadIdx.x;
    if (e >= EE) return;
    int pos = atomicAdd(&cursor[etype[e] * NP + dst[e]], 1);
    srcs_s[pos] = src[e];
}

// ---------- pad input -> bf16 h (zeros for d>=256 and rows>=NN) ----------
__global__ void pad2(const float* __restrict__ in_feat, ushort* __restrict__ h) {
    int idx = blockIdx.x * 256 + threadIdx.x;   // one per 8 elems
    if (idx >= NP * 64) return;
    int n = idx >> 6, o = (idx & 63) * 8;
    u16x8 ov = {0,0,0,0,0,0,0,0};
    if (n < NN && o < IN_F) {
        f4 a = *(const f4*)(in_feat + (size_t)n * IN_F + o);
        f4 b = *(const f4*)(in_feat + (size_t)n * IN_F + o + 4);
        ov = (u16x8){ f2b(a[0]), f2b(a[1]), f2b(a[2]), f2b(a[3]),
                      f2b(b[0]), f2b(b[1]), f2b(b[2]), f2b(b[3]) };
    }
    *(u16x8*)(h + (size_t)n * 512 + o) = ov;
}

// ---------- gather for k-pair: S2[kl][v][:] = sum of hbf[src] over in-edges of etype kp*2+kl ----------
__global__ void gather2(const int* __restrict__ offs, const int* __restrict__ srcs,
                        const ushort* __restrict__ hin, ushort* __restrict__ S2, int kp) {
    int wv = threadIdx.x >> 6, lane = threadIdx.x & 63;
    int r = blockIdx.x * 4 + wv;                 // [0, 2*NP)
    int kl = (r >= NP) ? 1 : 0;
    int v = r - kl * NP;
    int k = kp * 2 + kl;
    int beg = offs[k * NP + v], end = offs[k * NP + v + 1];
    float acc[8] = {0,0,0,0,0,0,0,0};
    for (int e = beg; e < end; e++) {
        int s = srcs[e];
        u16x8 hv = *(const u16x8*)(hin + (size_t)s * 512 + lane * 8);
#pragma unroll
        for (int j = 0; j < 8; j++) acc[j] += b2f(hv[j]);
    }
    u16x8 ov;
#pragma unroll
    for (int j = 0; j < 8; j++) ov[j] = f2b(acc[j]);
    *(u16x8*)(S2 + ((size_t)kl * NP + v) * 512 + lane * 8) = ov;
}

// ---------- generic MFMA GEMM, 128x128 tile, bf16 out ----------
// C[node][o] = sum_k B[node][k] * W[o][k], K split at 512 between (Wa,Ba) and (Wb,Bb).
// flags: 1 = accumulate into existing bf16 C; 2 = add sum_k cntf[k*NP+node]*bmsg[k*512+o]
__global__ __launch_bounds__(256) void gemm2(
    const ushort* __restrict__ Wa, const ushort* __restrict__ Wb, int swA,
    const ushort* __restrict__ Ba, const ushort* __restrict__ Bb, int Kt,
    ushort* __restrict__ C, int ldC, int flags,
    const float* __restrict__ cntf, const float* __restrict__ bmsg) {
    __shared__ ushort As[128][72];
    __shared__ ushort Bs[128][72];
    int t = threadIdx.x;
    int n0 = blockIdx.x * 128, o0 = blockIdx.y * 128;
    int wave = t >> 6, lane = t & 63;
    int wm = wave & 1, wn = wave >> 1;
    int l16 = lane & 15, quad = lane >> 4;
    f4 acc[4][4];
#pragma unroll
    for (int i = 0; i < 4; i++)
#pragma unroll
        for (int j = 0; j < 4; j++) acc[i][j] = (f4){0,0,0,0};
    for (int kk = 0; kk < Kt; kk += 64) {
        const ushort* Wsrc = (kk < 512) ? Wa : Wb;
        const ushort* Bsrc = (kk < 512) ? Ba : Bb;
        int ko = (kk < 512) ? kk : kk - 512;
        for (int i = t; i < 1024; i += 256) {
            int row = i >> 3, c8 = (i & 7) << 3;
            *(u32x4*)&As[row][c8] = *(const u32x4*)(Wsrc + (size_t)(o0 + row) * swA + ko + c8);
            *(u32x4*)&Bs[row][c8] = *(const u32x4*)(Bsrc + (size_t)(n0 + row) * 512 + ko + c8);
        }
        __syncthreads();
#pragma unroll
        for (int ks = 0; ks < 64; ks += 32) {
            s16x8 af[4], bf[4];
#pragma unroll
            for (int mi = 0; mi < 4; mi++) af[mi] = *(const s16x8*)&As[wm*64 + mi*16 + l16][ks + quad*8];
#pragma unroll
            for (int ni = 0; ni < 4; ni++) bf[ni] = *(const s16x8*)&Bs[wn*64 + ni*16 + l16][ks + quad*8];
#pragma unroll
            for (int mi = 0; mi < 4; mi++)
#pragma unroll
                for (int ni = 0; ni < 4; ni++)
                    acc[mi][ni] = __builtin_amdgcn_mfma_f32_16x16x32_bf16(af[mi], bf[ni], acc[mi][ni], 0, 0, 0);
        }
        __syncthreads();
    }
#pragma unroll
    for (int ni = 0; ni < 4; ni++) {
        int node = n0 + wn*64 + ni*16 + l16;
#pragma unroll
        for (int mi = 0; mi < 4; mi++) {
            int o = o0 + wm*64 + mi*16 + quad*4;
            f4 v = acc[mi][ni];
            if (flags & 2) {
#pragma unroll
                for (int k = 0; k < KT; k++) {
                    float ck = cntf[k * NP + node];
                    f4 bm = *(const f4*)(bmsg + k * 512 + o);
                    v += ck * bm;
                }
            }
            ushort* cp = C + (size_t)node * ldC + o;
            if (flags & 1) {
                u16x4 old = *(const u16x4*)cp;
                v += (f4){ b2f(old[0]), b2f(old[1]), b2f(old[2]), b2f(old[3]) };
            }
            u16x4 ov = { f2b(v[0]), f2b(v[1]), f2b(v[2]), f2b(v[3]) };
            *(u16x4*)cp = ov;
        }
    }
}

// ---------- GRU elementwise: h_out = (1-z)*tanh(in + bin + r*(hn + bhn)) + z*h_old ----------
// io holds i_n on entry, receives h_out (same addresses, thread-local)
__global__ void gru_ew(const ushort* __restrict__ rz, const ushort* __restrict__ hnb,
                       const ushort* __restrict__ hin, ushort* __restrict__ io,
                       const float* __restrict__ b_ih, const float* __restrict__ b_hh) {
    int idx = blockIdx.x * 256 + threadIdx.x;   // one per 8 elems
    int n = idx >> 6, o = (idx & 63) * 8;
    u16x8 rz1 = *(const u16x8*)(rz + (size_t)n * 1024 + o);
    u16x8 rz2 = *(const u16x8*)(rz + (size_t)n * 1024 + 512 + o);
    u16x8 inn = *(const u16x8*)(io + (size_t)n * 512 + o);
    u16x8 hnn = *(const u16x8*)(hnb + (size_t)n * 512 + o);
    u16x8 hol = *(const u16x8*)(hin + (size_t)n * 512 + o);
    u16x8 ov;
#pragma unroll
    for (int j = 0; j < 8; j++) {
        float r = sgm(b2f(rz1[j]) + b_ih[o + j] + b_hh[o + j]);
        float z = sgm(b2f(rz2[j]) + b_ih[512 + o + j] + b_hh[512 + o + j]);
        float nv = tanhf(b2f(inn[j]) + b_ih[1024 + o + j] + r * (b2f(hnn[j]) + b_hh[1024 + o + j]));
        ov[j] = f2b((1.f - z) * nv + z * b2f(hol[j]));
    }
    *(u16x8*)(io + (size_t)n * 512 + o) = ov;
}

// ---------- L2 normalize + sigmoid (bf16 in/out), one wave per node ----------
__global__ void norm_sig(ushort* __restrict__ h) {
    int n = blockIdx.x, lane = threadIdx.x;   // 64 threads
    u16x8 v = *(const u16x8*)(h + (size_t)n * 512 + lane * 8);
    float f[8], ss = 0.f;
#pragma unroll
    for (int j = 0; j < 8; j++) { f[j] = b2f(v[j]); ss += f[j] * f[j]; }
    for (int off = 32; off > 0; off >>= 1) ss += __shfl_xor(ss, off);
    float inv = 1.f / fmaxf(sqrtf(ss), 1e-12f);
    u16x8 ov;
#pragma unroll
    for (int j = 0; j < 8; j++) ov[j] = f2b(sgm(f[j] * inv));
    *(u16x8*)(h + (size_t)n * 512 + lane * 8) = ov;
}

// ---------- el/er from bf16 feat, one wave per node ----------
__global__ void el_er2(const ushort* __restrict__ feat, const float* __restrict__ attn_l,
                       const float* __restrict__ attn_r, float* __restrict__ el,
                       float* __restrict__ er) {
    int n = blockIdx.x, lane = threadIdx.x;   // 64
    int head = lane >> 5;
    int ld = (lane * 8) & 255;
    u16x8 v = *(const u16x8*)(feat + (size_t)n * 512 + lane * 8);
    float sl = 0.f, sr = 0.f;
#pragma unroll
    for (int j = 0; j < 8; j++) {
        float f = b2f(v[j]);
        sl += f * attn_l[head * 256 + ld + j];
        sr += f * attn_r[head * 256 + ld + j];
    }
    for (int off = 16; off > 0; off >>= 1) { sl += __shfl_xor(sl, off); sr += __shfl_xor(sr, off); }
    if ((lane & 31) == 0) { el[n * 2 + head] = sl; er[n * 2 + head] = sr; }
}

// ---------- fused GAT: softmax over in-edges + aggregation + bias/relu + graph pooling ----------
__global__ void gat2(const int* __restrict__ offs, const int* __restrict__ srcs,
                     const float* __restrict__ el, const float* __restrict__ er,
                     const ushort* __restrict__ feat, const float* __restrict__ gat_bias,
                     const int* __restrict__ graph_ids,
                     float* __restrict__ hg, float* __restrict__ gcnt) {
    int wave = threadIdx.x >> 6, lane = threadIdx.x & 63;
    int v = blockIdx.x * 4 + wave;
    float er0 = er[v * 2], er1 = er[v * 2 + 1];
    float m0 = -1e30f, m1 = -1e30f;
    int deg = 0;
    for (int k = 0; k < KT; k++) {
        int beg = offs[k * NP + v], end = offs[k * NP + v + 1];
        deg += end - beg;
        for (int base = beg; base < end; base += 64) {
            int e = base + lane;
            if (e < end) {
                int s = srcs[e];
                float s0 = el[s * 2] + er0;     s0 = s0 < 0.f ? 0.2f * s0 : s0;
                float s1 = el[s * 2 + 1] + er1; s1 = s1 < 0.f ? 0.2f * s1 : s1;
                m0 = fmaxf(m0, s0); m1 = fmaxf(m1, s1);
            }
        }
    }
    for (int off = 32; off > 0; off >>= 1) {
        m0 = fmaxf(m0, __shfl_xor(m0, off));
        m1 = fmaxf(m1, __shfl_xor(m1, off));
    }
    float d0 = 0.f, d1 = 0.f;
    for (int k = 0; k < KT; k++) {
        int beg = offs[k * NP + v], end = offs[k * NP + v + 1];
        for (int base = beg; base < end; base += 64) {
            int e = base + lane;
            if (e < end) {
                int s = srcs[e];
                float s0 = el[s * 2] + er0;     s0 = s0 < 0.f ? 0.2f * s0 : s0;
                float s1 = el[s * 2 + 1] + er1; s1 = s1 < 0.f ? 0.2f * s1 : s1;
                d0 += __expf(s0 - m0); d1 += __expf(s1 - m1);
            }
        }
    }
    for (int off = 32; off > 0; off >>= 1) { d0 += __shfl_xor(d0, off); d1 += __shfl_xor(d1, off); }
    float acc[8] = {0,0,0,0,0,0,0,0};
    int head = lane >> 5;
    if (deg > 0) {
        float i0 = 1.f / d0, i1 = 1.f / d1;
        for (int k = 0; k < KT; k++) {
            int beg = offs[k * NP + v], end = offs[k * NP + v + 1];
            for (int e = beg; e < end; e++) {
                int s = srcs[e];
                float sc, iv, mm;
                if (head == 0) { sc = el[s * 2] + er0;     mm = m0; iv = i0; }
                else           { sc = el[s * 2 + 1] + er1; mm = m1; iv = i1; }
                sc = sc < 0.f ? 0.2f * sc : sc;
                float al = __expf(sc - mm) * iv;
                u16x8 fv = *(const u16x8*)(feat + (size_t)s * 512 + lane * 8);
#pragma unroll
                for (int j = 0; j < 8; j++) acc[j] += al * b2f(fv[j]);
            }
        }
    }
    int g = graph_ids[v];
    int di = lane * 8;
#pragma unroll
    for (int j = 0; j < 8; j++)
        atomicAdd(&hg[g * 512 + di + j], fmaxf(acc[j] + gat_bias[di + j], 0.f));
    if (lane == 0) atomicAdd(&gcnt[g], 1.f);
}

// ---------- classify ----------
__global__ void classify(const float* __restrict__ hg, const float* __restrict__ gcnt,
                         const float* __restrict__ cw, const float* __restrict__ cb,
                         float* __restrict__ out) {
    __shared__ float hl[512];
    int g = blockIdx.x, t = threadIdx.x;  // 64 threads
    float inv = 1.f / fmaxf(gcnt[g], 1.f);
    for (int d = t; d < 512; d += 64) hl[d] = hg[g * 512 + d] * inv;
    __syncthreads();
    if (t < 32) {
        int hd = t >> 4, c = t & 15;
        float acc = 0.f;
        for (int d = 0; d < 256; d++) acc += hl[hd * 256 + d] * cw[c * 256 + d];
        out[(g * 2 + hd) * NC + c] = acc + cb[c];
    }
}

static inline int cdiv(int a, int b) { return (a + b - 1) / b; }
static inline size_t alup(size_t x) { return (x + 255) & ~(size_t)255; }

extern "C" void kernel_launch(void* const* d_in, const int* in_sizes, int n_in,
                              void* d_out, int out_size, void* d_ws, size_t ws_size,
                              hipStream_t stream) {
    const float* in_feat   = (const float*)d_in[0];
    const int*   src       = (const int*)d_in[1];
    const int*   dst       = (const int*)d_in[2];
    const int*   etype     = (const int*)d_in[3];
    const int*   graph_ids = (const int*)d_in[4];
    const float* Wmsg      = (const float*)d_in[5];
    const float* bmsg      = (const float*)d_in[6];
    const float* w_ih      = (const float*)d_in[7];
    const float* w_hh      = (const float*)d_in[8];
    const float* b_ih      = (const float*)d_in[9];
    const float* b_hh      = (const float*)d_in[10];
    const float* fc_w      = (const float*)d_in[11];
    const float* attn_l    = (const float*)d_in[12];
    const float* attn_r    = (const float*)d_in[13];
    const float* gat_bias  = (const float*)d_in[14];
    const float* cw        = (const float*)d_in[15];
    const float* cb        = (const float*)d_in[16];
    float* out = (float*)d_out;

    char* p = (char*)d_ws;
    ushort* hbfA  = (ushort*)p; p += alup((size_t)NP * 512 * 2);
    ushort* hbfB  = (ushort*)p; p += alup((size_t)NP * 512 * 2);
    ushort* abf   = (ushort*)p; p += alup((size_t)NP * 512 * 2);
    ushort* S2    = (ushort*)p; p += alup((size_t)2 * NP * 512 * 2);  // also rz (NP x 1024), also featbf
    ushort* wmsgT = (ushort*)p; p += alup((size_t)KT * 512 * 512 * 2);
    ushort* wihb  = (ushort*)p; p += alup((size_t)1536 * 512 * 2);
    ushort* whhb  = (ushort*)p; p += alup((size_t)1536 * 512 * 2);
    ushort* wrz   = (ushort*)p; p += alup((size_t)1024 * 1024 * 2);
    ushort* fcb   = (ushort*)p; p += alup((size_t)512 * 512 * 2);
    int*    cnt   = (int*)p;    p += alup((size_t)TOTKV * 4);
    int*    offs  = (int*)p;    p += alup(((size_t)TOTKV + 1) * 4);
    int*    cursor= (int*)p;    p += alup(((size_t)TOTKV + 1) * 4);
    float*  cntf  = (float*)p;  p += alup((size_t)TOTKV * 4);
    int*    srcs_s= (int*)p;    p += alup((size_t)EE * 4);
    float*  el    = (float*)p;  p += alup((size_t)NN * 2 * 4);
    float*  er    = (float*)p;  p += alup((size_t)NN * 2 * 4);
    float*  hg    = (float*)p;  p += alup((size_t)GG * 512 * 4);
    float*  gcnt  = (float*)p;  p += alup((size_t)GG * 4);
    ushort* featbf = S2;   // alias: S2/rz free after last GRU step

    // ---- weight prep ----
    conv_msgT<<<cdiv(KT * 512 * 512, 256), 256, 0, stream>>>(Wmsg, wmsgT);
    conv_copy<<<cdiv(1536 * 512, 256), 256, 0, stream>>>(w_ih, wihb, 1536 * 512);
    conv_copy<<<cdiv(1536 * 512, 256), 256, 0, stream>>>(w_hh, whhb, 1536 * 512);
    build_wrz<<<cdiv(1024 * 1024, 256), 256, 0, stream>>>(w_ih, w_hh, wrz);
    conv_copy<<<cdiv(512 * 512, 256), 256, 0, stream>>>(fc_w, fcb, 512 * 512);

    // ---- CSR build ----
    hipMemsetAsync(cnt, 0, (size_t)TOTKV * 4, stream);
    count_edges<<<cdiv(EE, 256), 256, 0, stream>>>(etype, dst, cnt);
    scan_kernel<<<1, 1024, 0, stream>>>(cnt, offs, cntf);
    hipMemcpyAsync(cursor, offs, (size_t)TOTKV * 4, hipMemcpyDeviceToDevice, stream);
    fill_edges<<<cdiv(EE, 256), 256, 0, stream>>>(etype, dst, src, cursor, srcs_s);

    pad2<<<cdiv(NP * 64, 256), 256, 0, stream>>>(in_feat, hbfA);

    const ushort* win = wihb + (size_t)1024 * 512;   // n-gate rows of w_ih
    const ushort* whn = whhb + (size_t)1024 * 512;   // n-gate rows of w_hh

    ushort* hin = hbfA;
    ushort* hout = hbfB;
    for (int step = 0; step < NSTEPS; step++) {
        // message passing: abf = sum_k S_k @ Wmsg_k^T + sum_k cnt_k*bmsg_k   (bf16)
        gather2<<<2 * NP / 4, 256, 0, stream>>>(offs, srcs_s, hin, S2, 0);
        gemm2<<<dim3(NP / 128, 4), 256, 0, stream>>>(
            wmsgT, wmsgT + (size_t)1 * 262144, 512, S2, S2 + (size_t)NP * 512, 1024,
            abf, 512, 0, nullptr, nullptr);
        gather2<<<2 * NP / 4, 256, 0, stream>>>(offs, srcs_s, hin, S2, 1);
        gemm2<<<dim3(NP / 128, 4), 256, 0, stream>>>(
            wmsgT + (size_t)2 * 262144, wmsgT + (size_t)3 * 262144, 512, S2, S2 + (size_t)NP * 512, 1024,
            abf, 512, 3, cntf, bmsg);
        // GRU: rz = [abf|hin] @ Wrz^T  (K=1024, M=1024) -> S2 region
        gemm2<<<dim3(NP / 128, 8), 256, 0, stream>>>(
            wrz, wrz + 512, 1024, abf, hin, 1024, S2, 1024, 0, nullptr, nullptr);
        // i_n = abf @ win^T -> hout region
        gemm2<<<dim3(NP / 128, 4), 256, 0, stream>>>(
            win, win, 512, abf, abf, 512, hout, 512, 0, nullptr, nullptr);
        // h_n = hin @ whn^T -> abf region (abf no longer needed)
        gemm2<<<dim3(NP / 128, 4), 256, 0, stream>>>(
            whn, whn, 512, hin, hin, 512, abf, 512, 0, nullptr, nullptr);
        // elementwise GRU combine -> hout (in place over i_n)
        gru_ew<<<NP * 64 / 256, 256, 0, stream>>>(S2, abf, hin, hout, b_ih, b_hh);
        ushort* tmp = hin; hin = hout; hout = tmp;
    }
    // hin now holds final h (hbfA after 4 steps)

    norm_sig<<<NN, 64, 0, stream>>>(hin);
    // feat = h @ fc_w^T  (bf16) -> featbf (S2 region)
    gemm2<<<dim3(NP / 128, 4), 256, 0, stream>>>(
        fcb, fcb, 512, hin, hin, 512, featbf, 512, 0, nullptr, nullptr);
    el_er2<<<NN, 64, 0, stream>>>(featbf, attn_l, attn_r, el, er);

    hipMemsetAsync(hg, 0, (size_t)GG * 512 * 4, stream);
    hipMemsetAsync(gcnt, 0, (size_t)GG * 4, stream);
    gat2<<<NN / 4, 256, 0, stream>>>(offs, srcs_s, el, er, featbf, gat_bias, graph_ids, hg, gcnt);
    classify<<<GG, 64, 0, stream>>>(hg, gcnt, cw, cb, out);
}

// Round 5
// 2168.206 us; speedup vs baseline: 6.3999x; 1.1134x over previous
//
#include <hip/hip_runtime.h>
#include <math.h>

#define NN 20000
#define NP 20096           // NN padded to 128 (157 tiles)
#define EE 320000
#define GG 64
#define IN_F 256
#define NC 16
#define NSTEPS 4
#define KT 4
#define TOTKV (KT*NP)      // 80384

typedef unsigned int uint;
typedef unsigned short ushort;
typedef __attribute__((ext_vector_type(2))) float f2;
typedef __attribute__((ext_vector_type(4))) float f4;
typedef __attribute__((ext_vector_type(4))) ushort u16x4;
typedef __attribute__((ext_vector_type(8))) ushort u16x8;
typedef __attribute__((ext_vector_type(4))) uint u32x4;
typedef __attribute__((ext_vector_type(8))) short s16x8;

__device__ __forceinline__ ushort f2b(float f) {
    uint u = __float_as_uint(f);
    u = (u + 0x7FFFu + ((u >> 16) & 1u)) >> 16;   // RNE f32->bf16
    return (ushort)u;
}
__device__ __forceinline__ float b2f(ushort s) { return __uint_as_float(((uint)s) << 16); }
__device__ __forceinline__ float sgm(float x) { return 1.f / (1.f + __expf(-x)); }

// ---------- weight prep ----------
__global__ void conv_msgT(const float* __restrict__ Wm, ushort* __restrict__ WT) {
    // WT[k][o][d] <- Wmsg[k][d][o]
    int idx = blockIdx.x * 256 + threadIdx.x;
    if (idx >= KT * 512 * 512) return;
    int k = idx >> 18, rem = idx & 262143;
    int o = rem >> 9, d = rem & 511;
    WT[idx] = f2b(Wm[(k << 18) + (d << 9) + o]);
}
__global__ void conv_copy(const float* __restrict__ x, ushort* __restrict__ y, int n) {
    int i = blockIdx.x * 256 + threadIdx.x;
    if (i < n) y[i] = f2b(x[i]);
}
// Wrz[o2][k2]: o2<512 -> r-gate rows, o2>=512 -> z-gate; k2<512 from w_ih, else w_hh
__global__ void build_wrz(const float* __restrict__ wih, const float* __restrict__ whh,
                          ushort* __restrict__ W) {
    int idx = blockIdx.x * 256 + threadIdx.x;
    if (idx >= 1024 * 1024) return;
    int o2 = idx >> 10, k2 = idx & 1023;
    int gate = o2 >> 9, o = o2 & 511;
    float v = (k2 < 512) ? wih[(gate * 512 + o) * 512 + k2]
                         : whh[(gate * 512 + o) * 512 + (k2 - 512)];
    W[idx] = f2b(v);
}

// ---------- CSR build (etype-major, dst-minor) ----------
__global__ void count_edges(const int* __restrict__ etype, const int* __restrict__ dst,
                            int* __restrict__ cnt) {
    int e = blockIdx.x * 256 + threadIdx.x;
    if (e >= EE) return;
    atomicAdd(&cnt[etype[e] * NP + dst[e]], 1);
}
__global__ __launch_bounds__(1024) void scan_kernel(const int* __restrict__ cnt,
                                                    int* __restrict__ offs,
                                                    float* __restrict__ cntf) {
    __shared__ int part[1024];
    int t = threadIdx.x;
    const int chunk = (TOTKV + 1023) / 1024;
    int b = t * chunk, e = b + chunk; if (e > TOTKV) e = TOTKV; if (b > TOTKV) b = TOTKV;
    int s = 0;
    for (int i = b; i < e; i++) s += cnt[i];
    part[t] = s; __syncthreads();
    for (int off = 1; off < 1024; off <<= 1) {
        int v = part[t];
        int add = (t >= off) ? part[t - off] : 0;
        __syncthreads();
        part[t] = v + add;
        __syncthreads();
    }
    int run = part[t] - s;  // exclusive prefix
    for (int i = b; i < e; i++) { offs[i] = run; cntf[i] = (float)cnt[i]; run += cnt[i]; }
    if (t == 1023) offs[TOTKV] = part[1023];
}
__global__ void fill_edges(const int* __restrict__ etype, const int* __restrict__ dst,
                           const int* __restrict__ src, int* __restrict__ cursor,
                           int* __restrict__ srcs_s, int* __restrict__ dsts_s) {
    int e = blockIdx.x * 256 + threadIdx.x;
    if (e >= EE) return;
    int pos = atomicAdd(&cursor[etype[e] * NP + dst[e]], 1);
    srcs_s[pos] = src[e];
    dsts_s[pos] = dst[e];
}

// ---------- pad input -> bf16 h (zeros for d>=256 and rows>=NN) ----------
__global__ void pad2(const float* __restrict__ in_feat, ushort* __restrict__ h) {
    int idx = blockIdx.x * 256 + threadIdx.x;   // one per 8 elems
    if (idx >= NP * 64) return;
    int n = idx >> 6, o = (idx & 63) * 8;
    u16x8 ov = {0,0,0,0,0,0,0,0};
    if (n < NN && o < IN_F) {
        f4 a = *(const f4*)(in_feat + (size_t)n * IN_F + o);
        f4 b = *(const f4*)(in_feat + (size_t)n * IN_F + o + 4);
        ov = (u16x8){ f2b(a[0]), f2b(a[1]), f2b(a[2]), f2b(a[3]),
                      f2b(b[0]), f2b(b[1]), f2b(b[2]), f2b(b[3]) };
    }
    *(u16x8*)(h + (size_t)n * 512 + o) = ov;
}

// ---------- gather for k-pair: S2[kl][v][:] = sum of hbf[src] over in-edges of etype kp*2+kl ----------
__global__ void gather2(const int* __restrict__ offs, const int* __restrict__ srcs,
                        const ushort* __restrict__ hin, ushort* __restrict__ S2, int kp) {
    int wv = threadIdx.x >> 6, lane = threadIdx.x & 63;
    int r = blockIdx.x * 4 + wv;                 // [0, 2*NP)
    int kl = (r >= NP) ? 1 : 0;
    int v = r - kl * NP;
    int k = kp * 2 + kl;
    int beg = offs[k * NP + v], end = offs[k * NP + v + 1];
    float acc[8] = {0,0,0,0,0,0,0,0};
    for (int e = beg; e < end; e++) {
        int s = srcs[e];
        u16x8 hv = *(const u16x8*)(hin + (size_t)s * 512 + lane * 8);
#pragma unroll
        for (int j = 0; j < 8; j++) acc[j] += b2f(hv[j]);
    }
    u16x8 ov;
#pragma unroll
    for (int j = 0; j < 8; j++) ov[j] = f2b(acc[j]);
    *(u16x8*)(S2 + ((size_t)kl * NP + v) * 512 + lane * 8) = ov;
}

// ---------- generic MFMA GEMM, 128x128 tile, bf16 out ----------
// C[node][o] = sum_k B[node][k] * W[o][k], K split at 512 between (Wa,Ba) and (Wb,Bb).
// flags: 1 = accumulate into existing bf16 C; 2 = add sum_k cntf[k*NP+node]*bmsg[k*512+o]
__global__ __launch_bounds__(256) void gemm2(
    const ushort* __restrict__ Wa, const ushort* __restrict__ Wb, int swA,
    const ushort* __restrict__ Ba, const ushort* __restrict__ Bb, int Kt,
    ushort* __restrict__ C, int ldC, int flags,
    const float* __restrict__ cntf, const float* __restrict__ bmsg) {
    __shared__ ushort As[128][72];
    __shared__ ushort Bs[128][72];
    int t = threadIdx.x;
    int n0 = blockIdx.x * 128, o0 = blockIdx.y * 128;
    int wave = t >> 6, lane = t & 63;
    int wm = wave & 1, wn = wave >> 1;
    int l16 = lane & 15, quad = lane >> 4;
    f4 acc[4][4];
#pragma unroll
    for (int i = 0; i < 4; i++)
#pragma unroll
        for (int j = 0; j < 4; j++) acc[i][j] = (f4){0,0,0,0};
    for (int kk = 0; kk < Kt; kk += 64) {
        const ushort* Wsrc = (kk < 512) ? Wa : Wb;
        const ushort* Bsrc = (kk < 512) ? Ba : Bb;
        int ko = (kk < 512) ? kk : kk - 512;
        for (int i = t; i < 1024; i += 256) {
            int row = i >> 3, c8 = (i & 7) << 3;
            *(u32x4*)&As[row][c8] = *(const u32x4*)(Wsrc + (size_t)(o0 + row) * swA + ko + c8);
            *(u32x4*)&Bs[row][c8] = *(const u32x4*)(Bsrc + (size_t)(n0 + row) * 512 + ko + c8);
        }
        __syncthreads();
#pragma unroll
        for (int ks = 0; ks < 64; ks += 32) {
            s16x8 af[4], bf[4];
#pragma unroll
            for (int mi = 0; mi < 4; mi++) af[mi] = *(const s16x8*)&As[wm*64 + mi*16 + l16][ks + quad*8];
#pragma unroll
            for (int ni = 0; ni < 4; ni++) bf[ni] = *(const s16x8*)&Bs[wn*64 + ni*16 + l16][ks + quad*8];
#pragma unroll
            for (int mi = 0; mi < 4; mi++)
#pragma unroll
                for (int ni = 0; ni < 4; ni++)
                    acc[mi][ni] = __builtin_amdgcn_mfma_f32_16x16x32_bf16(af[mi], bf[ni], acc[mi][ni], 0, 0, 0);
        }
        __syncthreads();
    }
#pragma unroll
    for (int ni = 0; ni < 4; ni++) {
        int node = n0 + wn*64 + ni*16 + l16;
#pragma unroll
        for (int mi = 0; mi < 4; mi++) {
            int o = o0 + wm*64 + mi*16 + quad*4;
            f4 v = acc[mi][ni];
            if (flags & 2) {
#pragma unroll
                for (int k = 0; k < KT; k++) {
                    float ck = cntf[k * NP + node];
                    f4 bm = *(const f4*)(bmsg + k * 512 + o);
                    v += ck * bm;
                }
            }
            ushort* cp = C + (size_t)node * ldC + o;
            if (flags & 1) {
                u16x4 old = *(const u16x4*)cp;
                v += (f4){ b2f(old[0]), b2f(old[1]), b2f(old[2]), b2f(old[3]) };
            }
            u16x4 ov = { f2b(v[0]), f2b(v[1]), f2b(v[2]), f2b(v[3]) };
            *(u16x4*)cp = ov;
        }
    }
}

// ---------- GRU elementwise: h_out = (1-z)*tanh(in + bin + r*(hn + bhn)) + z*h_old ----------
// io holds i_n on entry, receives h_out (same addresses, thread-local)
__global__ void gru_ew(const ushort* __restrict__ rz, const ushort* __restrict__ hnb,
                       const ushort* __restrict__ hin, ushort* __restrict__ io,
                       const float* __restrict__ b_ih, const float* __restrict__ b_hh) {
    int idx = blockIdx.x * 256 + threadIdx.x;   // one per 8 elems
    int n = idx >> 6, o = (idx & 63) * 8;
    u16x8 rz1 = *(const u16x8*)(rz + (size_t)n * 1024 + o);
    u16x8 rz2 = *(const u16x8*)(rz + (size_t)n * 1024 + 512 + o);
    u16x8 inn = *(const u16x8*)(io + (size_t)n * 512 + o);
    u16x8 hnn = *(const u16x8*)(hnb + (size_t)n * 512 + o);
    u16x8 hol = *(const u16x8*)(hin + (size_t)n * 512 + o);
    u16x8 ov;
#pragma unroll
    for (int j = 0; j < 8; j++) {
        float r = sgm(b2f(rz1[j]) + b_ih[o + j] + b_hh[o + j]);
        float z = sgm(b2f(rz2[j]) + b_ih[512 + o + j] + b_hh[512 + o + j]);
        float nv = tanhf(b2f(inn[j]) + b_ih[1024 + o + j] + r * (b2f(hnn[j]) + b_hh[1024 + o + j]));
        ov[j] = f2b((1.f - z) * nv + z * b2f(hol[j]));
    }
    *(u16x8*)(io + (size_t)n * 512 + o) = ov;
}

// ---------- L2 normalize + sigmoid (bf16 in/out), one wave per node ----------
__global__ void norm_sig(ushort* __restrict__ h) {
    int n = blockIdx.x, lane = threadIdx.x;   // 64 threads
    u16x8 v = *(const u16x8*)(h + (size_t)n * 512 + lane * 8);
    float f[8], ss = 0.f;
#pragma unroll
    for (int j = 0; j < 8; j++) { f[j] = b2f(v[j]); ss += f[j] * f[j]; }
    for (int off = 32; off > 0; off >>= 1) ss += __shfl_xor(ss, off);
    float inv = 1.f / fmaxf(sqrtf(ss), 1e-12f);
    u16x8 ov;
#pragma unroll
    for (int j = 0; j < 8; j++) ov[j] = f2b(sgm(f[j] * inv));
    *(u16x8*)(h + (size_t)n * 512 + lane * 8) = ov;
}

// ---------- el/er from bf16 feat, one wave per node ----------
__global__ void el_er2(const ushort* __restrict__ feat, const float* __restrict__ attn_l,
                       const float* __restrict__ attn_r, float* __restrict__ el,
                       float* __restrict__ er) {
    int n = blockIdx.x, lane = threadIdx.x;   // 64
    int head = lane >> 5;
    int ld = (lane * 8) & 255;
    u16x8 v = *(const u16x8*)(feat + (size_t)n * 512 + lane * 8);
    float sl = 0.f, sr = 0.f;
#pragma unroll
    for (int j = 0; j < 8; j++) {
        float f = b2f(v[j]);
        sl += f * attn_l[head * 256 + ld + j];
        sr += f * attn_r[head * 256 + ld + j];
    }
    for (int off = 16; off > 0; off >>= 1) { sl += __shfl_xor(sl, off); sr += __shfl_xor(sr, off); }
    if ((lane & 31) == 0) { el[n * 2 + head] = sl; er[n * 2 + head] = sr; }
}

// ---------- per-CSR-slot edge scores (leaky relu), both heads ----------
__global__ void edge_scores(const int* __restrict__ srcs, const int* __restrict__ dsts,
                            const float* __restrict__ el, const float* __restrict__ er,
                            float* __restrict__ esc) {
    int e = blockIdx.x * 256 + threadIdx.x;
    if (e >= EE) return;
    int s = srcs[e], d = dsts[e];
    f2 elv = *(const f2*)(el + (size_t)s * 2);
    f2 erv = *(const f2*)(er + (size_t)d * 2);
    float s0 = elv[0] + erv[0]; s0 = s0 < 0.f ? 0.2f * s0 : s0;
    float s1 = elv[1] + erv[1]; s1 = s1 < 0.f ? 0.2f * s1 : s1;
    *(f2*)(esc + (size_t)e * 2) = (f2){ s0, s1 };
}

// ---------- fused GAT: softmax over in-edges + aggregation + bias/relu, rst f32 out (no atomics) ----------
__global__ void gat3(const int* __restrict__ offs, const int* __restrict__ srcs,
                     const float* __restrict__ esc, const ushort* __restrict__ feat,
                     const float* __restrict__ gat_bias, float* __restrict__ rst) {
    int wave = threadIdx.x >> 6, lane = threadIdx.x & 63;
    int v = blockIdx.x * 4 + wave;
    int beg[KT], end[KT];
#pragma unroll
    for (int k = 0; k < KT; k++) { beg[k] = offs[k * NP + v]; end[k] = offs[k * NP + v + 1]; }
    float m0 = -1e30f, m1 = -1e30f;
#pragma unroll
    for (int k = 0; k < KT; k++)
        for (int base = beg[k]; base < end[k]; base += 64) {
            int e = base + lane;
            if (e < end[k]) {
                f2 s = *(const f2*)(esc + (size_t)e * 2);
                m0 = fmaxf(m0, s[0]); m1 = fmaxf(m1, s[1]);
            }
        }
    for (int off = 32; off > 0; off >>= 1) {
        m0 = fmaxf(m0, __shfl_xor(m0, off));
        m1 = fmaxf(m1, __shfl_xor(m1, off));
    }
    float d0 = 0.f, d1 = 0.f;
#pragma unroll
    for (int k = 0; k < KT; k++)
        for (int base = beg[k]; base < end[k]; base += 64) {
            int e = base + lane;
            if (e < end[k]) {
                f2 s = *(const f2*)(esc + (size_t)e * 2);
                d0 += __expf(s[0] - m0); d1 += __expf(s[1] - m1);
            }
        }
    for (int off = 32; off > 0; off >>= 1) { d0 += __shfl_xor(d0, off); d1 += __shfl_xor(d1, off); }
    int head = lane >> 5;
    float mm = head ? m1 : m0;
    float iv = head ? (d1 > 0.f ? 1.f / d1 : 0.f) : (d0 > 0.f ? 1.f / d0 : 0.f);
    float acc[8] = {0,0,0,0,0,0,0,0};
#pragma unroll
    for (int k = 0; k < KT; k++)
        for (int e = beg[k]; e < end[k]; e++) {
            float sc = esc[(size_t)e * 2 + head];
            float al = __expf(sc - mm) * iv;
            u16x8 fv = *(const u16x8*)(feat + (size_t)srcs[e] * 512 + lane * 8);
#pragma unroll
            for (int j = 0; j < 8; j++) acc[j] += al * b2f(fv[j]);
        }
    int di = lane * 8;
    f4 o0, o1;
#pragma unroll
    for (int j = 0; j < 4; j++) {
        o0[j] = fmaxf(acc[j] + gat_bias[di + j], 0.f);
        o1[j] = fmaxf(acc[4 + j] + gat_bias[di + 4 + j], 0.f);
    }
    *(f4*)(rst + (size_t)v * 512 + di) = o0;
    *(f4*)(rst + (size_t)v * 512 + di + 4) = o1;
}

// ---------- graph boundaries via binary search on sorted graph_ids ----------
__global__ void graph_bounds(const int* __restrict__ gids, int* __restrict__ goff) {
    int g = threadIdx.x;   // 128 threads, need 0..64
    if (g > GG) return;
    int lo = 0, hi = NN;
    while (lo < hi) { int mid = (lo + hi) >> 1; if (gids[mid] < g) lo = mid + 1; else hi = mid; }
    goff[g] = lo;
}

// ---------- per-graph mean of rst -> hgm ----------
__global__ void graph_mean(const float* __restrict__ rst, const int* __restrict__ goff,
                           float* __restrict__ hgm) {
    int g = blockIdx.x;
    int c = blockIdx.y * 256 + threadIdx.x;
    int beg = goff[g], end = goff[g + 1];
    float s = 0.f;
    for (int n = beg; n < end; n++) s += rst[(size_t)n * 512 + c];
    float inv = (end > beg) ? 1.f / (float)(end - beg) : 0.f;
    hgm[g * 512 + c] = s * inv;
}

// ---------- classify ----------
__global__ void classify(const float* __restrict__ hgm, const float* __restrict__ cw,
                         const float* __restrict__ cb, float* __restrict__ out) {
    __shared__ float hl[512];
    int g = blockIdx.x, t = threadIdx.x;  // 64 threads
    for (int d = t; d < 512; d += 64) hl[d] = hgm[g * 512 + d];
    __syncthreads();
    if (t < 32) {
        int hd = t >> 4, c = t & 15;
        float acc = 0.f;
        for (int d = 0; d < 256; d++) acc += hl[hd * 256 + d] * cw[c * 256 + d];
        out[(g * 2 + hd) * NC + c] = acc + cb[c];
    }
}

static inline int cdiv(int a, int b) { return (a + b - 1) / b; }
static inline size_t alup(size_t x) { return (x + 255) & ~(size_t)255; }

extern "C" void kernel_launch(void* const* d_in, const int* in_sizes, int n_in,
                              void* d_out, int out_size, void* d_ws, size_t ws_size,
                              hipStream_t stream) {
    const float* in_feat   = (const float*)d_in[0];
    const int*   src       = (const int*)d_in[1];
    const int*   dst       = (const int*)d_in[2];
    const int*   etype     = (const int*)d_in[3];
    const int*   graph_ids = (const int*)d_in[4];
    const float* Wmsg      = (const float*)d_in[5];
    const float* bmsg      = (const float*)d_in[6];
    const float* w_ih      = (const float*)d_in[7];
    const float* w_hh      = (const float*)d_in[8];
    const float* b_ih      = (const float*)d_in[9];
    const float* b_hh      = (const float*)d_in[10];
    const float* fc_w      = (const float*)d_in[11];
    const float* attn_l    = (const float*)d_in[12];
    const float* attn_r    = (const float*)d_in[13];
    const float* gat_bias  = (const float*)d_in[14];
    const float* cw        = (const float*)d_in[15];
    const float* cb        = (const float*)d_in[16];
    float* out = (float*)d_out;

    char* p = (char*)d_ws;
    ushort* hbfA  = (ushort*)p; p += alup((size_t)NP * 512 * 2);
    ushort* hbfB  = (ushort*)p; p += alup((size_t)NP * 512 * 2);
    ushort* abf   = (ushort*)p; p += alup((size_t)NP * 512 * 2);
    ushort* S2    = (ushort*)p; p += alup((size_t)2 * NP * 512 * 2);  // rz (NP x 1024); later rst f32 (NP x 512)
    ushort* wmsgT = (ushort*)p; p += alup((size_t)KT * 512 * 512 * 2);
    ushort* wihb  = (ushort*)p; p += alup((size_t)1536 * 512 * 2);
    ushort* whhb  = (ushort*)p; p += alup((size_t)1536 * 512 * 2);
    ushort* wrz   = (ushort*)p; p += alup((size_t)1024 * 1024 * 2);
    ushort* fcb   = (ushort*)p; p += alup((size_t)512 * 512 * 2);
    int*    cnt   = (int*)p;    p += alup((size_t)TOTKV * 4);
    int*    offs  = (int*)p;    p += alup(((size_t)TOTKV + 1) * 4);
    int*    cursor= (int*)p;    p += alup(((size_t)TOTKV + 1) * 4);
    float*  cntf  = (float*)p;  p += alup((size_t)TOTKV * 4);
    int*    srcs_s= (int*)p;    p += alup((size_t)EE * 4);
    int*    dsts_s= (int*)p;    p += alup((size_t)EE * 4);
    float*  esc   = (float*)p;  p += alup((size_t)EE * 2 * 4);
    float*  el    = (float*)p;  p += alup((size_t)NN * 2 * 4);
    float*  er    = (float*)p;  p += alup((size_t)NN * 2 * 4);
    int*    goff  = (int*)p;    p += alup((size_t)(GG + 1) * 4);
    float*  hgm   = (float*)p;  p += alup((size_t)GG * 512 * 4);
    ushort* featbf = abf;          // alias: abf free after last gru_ew
    float*  rst    = (float*)S2;   // alias: rz region free after last gru_ew (same byte size)

    // ---- weight prep ----
    conv_msgT<<<cdiv(KT * 512 * 512, 256), 256, 0, stream>>>(Wmsg, wmsgT);
    conv_copy<<<cdiv(1536 * 512, 256), 256, 0, stream>>>(w_ih, wihb, 1536 * 512);
    conv_copy<<<cdiv(1536 * 512, 256), 256, 0, stream>>>(w_hh, whhb, 1536 * 512);
    build_wrz<<<cdiv(1024 * 1024, 256), 256, 0, stream>>>(w_ih, w_hh, wrz);
    conv_copy<<<cdiv(512 * 512, 256), 256, 0, stream>>>(fc_w, fcb, 512 * 512);

    // ---- CSR build ----
    hipMemsetAsync(cnt, 0, (size_t)TOTKV * 4, stream);
    count_edges<<<cdiv(EE, 256), 256, 0, stream>>>(etype, dst, cnt);
    scan_kernel<<<1, 1024, 0, stream>>>(cnt, offs, cntf);
    hipMemcpyAsync(cursor, offs, (size_t)TOTKV * 4, hipMemcpyDeviceToDevice, stream);
    fill_edges<<<cdiv(EE, 256), 256, 0, stream>>>(etype, dst, src, cursor, srcs_s, dsts_s);
    graph_bounds<<<1, 128, 0, stream>>>(graph_ids, goff);

    pad2<<<cdiv(NP * 64, 256), 256, 0, stream>>>(in_feat, hbfA);

    const ushort* win = wihb + (size_t)1024 * 512;   // n-gate rows of w_ih
    const ushort* whn = whhb + (size_t)1024 * 512;   // n-gate rows of w_hh

    ushort* hin = hbfA;
    ushort* hout = hbfB;
    for (int step = 0; step < NSTEPS; step++) {
        // message passing: abf = sum_k S_k @ Wmsg_k^T + sum_k cnt_k*bmsg_k   (bf16)
        gather2<<<2 * NP / 4, 256, 0, stream>>>(offs, srcs_s, hin, S2, 0);
        gemm2<<<dim3(NP / 128, 4), 256, 0, stream>>>(
            wmsgT, wmsgT + (size_t)1 * 262144, 512, S2, S2 + (size_t)NP * 512, 1024,
            abf, 512, 0, nullptr, nullptr);
        gather2<<<2 * NP / 4, 256, 0, stream>>>(offs, srcs_s, hin, S2, 1);
        gemm2<<<dim3(NP / 128, 4), 256, 0, stream>>>(
            wmsgT + (size_t)2 * 262144, wmsgT + (size_t)3 * 262144, 512, S2, S2 + (size_t)NP * 512, 1024,
            abf, 512, 3, cntf, bmsg);
        // GRU: rz = [abf|hin] @ Wrz^T  (K=1024, M=1024) -> S2 region
        gemm2<<<dim3(NP / 128, 8), 256, 0, stream>>>(
            wrz, wrz + 512, 1024, abf, hin, 1024, S2, 1024, 0, nullptr, nullptr);
        // i_n = abf @ win^T -> hout region
        gemm2<<<dim3(NP / 128, 4), 256, 0, stream>>>(
            win, win, 512, abf, abf, 512, hout, 512, 0, nullptr, nullptr);
        // h_n = hin @ whn^T -> abf region (abf no longer needed)
        gemm2<<<dim3(NP / 128, 4), 256, 0, stream>>>(
            whn, whn, 512, hin, hin, 512, abf, 512, 0, nullptr, nullptr);
        // elementwise GRU combine -> hout (in place over i_n)
        gru_ew<<<NP * 64 / 256, 256, 0, stream>>>(S2, abf, hin, hout, b_ih, b_hh);
        ushort* tmp = hin; hin = hout; hout = tmp;
    }
    // hin now holds final h (hbfA after 4 steps)

    norm_sig<<<NN, 64, 0, stream>>>(hin);
    // feat = h @ fc_w^T  (bf16) -> featbf (abf region)
    gemm2<<<dim3(NP / 128, 4), 256, 0, stream>>>(
        fcb, fcb, 512, hin, hin, 512, featbf, 512, 0, nullptr, nullptr);
    el_er2<<<NN, 64, 0, stream>>>(featbf, attn_l, attn_r, el, er);
    edge_scores<<<cdiv(EE, 256), 256, 0, stream>>>(srcs_s, dsts_s, el, er, esc);

    gat3<<<NN / 4, 256, 0, stream>>>(offs, srcs_s, esc, featbf, gat_bias, rst);
    graph_mean<<<dim3(GG, 2), 256, 0, stream>>>(rst, goff, hgm);
    classify<<<GG, 64, 0, stream>>>(hgm, cw, cb, out);
}

// Round 6
// 2107.484 us; speedup vs baseline: 6.5843x; 1.0288x over previous
//
#include <hip/hip_runtime.h>
#include <math.h>

#define NN 20000
#define NP 20096           // NN padded to 128 (157 tiles)
#define EE 320000
#define GG 64
#define IN_F 256
#define NC 16
#define NSTEPS 4
#define KT 4
#define TOTKV (KT*NP)      // 80384 = 157 * 512
#define NBLK 157

typedef unsigned int uint;
typedef unsigned short ushort;
typedef __attribute__((ext_vector_type(2))) float f2;
typedef __attribute__((ext_vector_type(4))) float f4;
typedef __attribute__((ext_vector_type(4))) ushort u16x4;
typedef __attribute__((ext_vector_type(8))) ushort u16x8;
typedef __attribute__((ext_vector_type(8))) short s16x8;

#define GLD_LDS(gp, lp) __builtin_amdgcn_global_load_lds( \
    (const __attribute__((address_space(1))) void*)(gp),  \
    (__attribute__((address_space(3))) void*)(lp), 16, 0, 0)

__device__ __forceinline__ ushort f2b(float f) {
    uint u = __float_as_uint(f);
    u = (u + 0x7FFFu + ((u >> 16) & 1u)) >> 16;   // RNE f32->bf16
    return (ushort)u;
}
__device__ __forceinline__ float b2f(ushort s) { return __uint_as_float(((uint)s) << 16); }
__device__ __forceinline__ float sgm(float x) { return 1.f / (1.f + __expf(-x)); }

// ---------- weight prep ----------
__global__ void conv_msgT(const float* __restrict__ Wm, ushort* __restrict__ WT) {
    // WT[k][o][d] <- Wmsg[k][d][o]
    int idx = blockIdx.x * 256 + threadIdx.x;
    if (idx >= KT * 512 * 512) return;
    int k = idx >> 18, rem = idx & 262143;
    int o = rem >> 9, d = rem & 511;
    WT[idx] = f2b(Wm[(k << 18) + (d << 9) + o]);
}
__global__ void conv_copy(const float* __restrict__ x, ushort* __restrict__ y, int n) {
    int i = blockIdx.x * 256 + threadIdx.x;
    if (i < n) y[i] = f2b(x[i]);
}
// Wrz[o2][k2]: o2<512 -> r-gate rows, o2>=512 -> z-gate; k2<512 from w_ih, else w_hh
__global__ void build_wrz(const float* __restrict__ wih, const float* __restrict__ whh,
                          ushort* __restrict__ W) {
    int idx = blockIdx.x * 256 + threadIdx.x;
    if (idx >= 1024 * 1024) return;
    int o2 = idx >> 10, k2 = idx & 1023;
    int gate = o2 >> 9, o = o2 & 511;
    float v = (k2 < 512) ? wih[(gate * 512 + o) * 512 + k2]
                         : whh[(gate * 512 + o) * 512 + (k2 - 512)];
    W[idx] = f2b(v);
}

// ---------- CSR build (etype-major, dst-minor) ----------
__global__ void count_edges(const int* __restrict__ etype, const int* __restrict__ dst,
                            int* __restrict__ cnt) {
    int e = blockIdx.x * 256 + threadIdx.x;
    if (e >= EE) return;
    atomicAdd(&cnt[etype[e] * NP + dst[e]], 1);
}
// phase 1: per-block (512 elems) exclusive scan + block sum
__global__ __launch_bounds__(512) void scan_blk(const int* __restrict__ cnt,
                                                int* __restrict__ offs,
                                                float* __restrict__ cntf,
                                                int* __restrict__ bsum) {
    __shared__ int sh[512];
    int t = threadIdx.x, b = blockIdx.x;
    int i = b * 512 + t;
    int v = cnt[i];
    sh[t] = v; __syncthreads();
    for (int off = 1; off < 512; off <<= 1) {
        int add = (t >= off) ? sh[t - off] : 0;
        __syncthreads();
        sh[t] += add;
        __syncthreads();
    }
    offs[i] = sh[t] - v;         // local exclusive
    cntf[i] = (float)v;
    if (t == 511) bsum[b] = sh[511];
}
// phase 2: scan the 157 block sums
__global__ void scan_top(const int* __restrict__ bsum, int* __restrict__ boff,
                         int* __restrict__ offs) {
    if (threadIdx.x == 0) {
        int run = 0;
        for (int i = 0; i < NBLK; i++) { boff[i] = run; run += bsum[i]; }
        offs[TOTKV] = run;
    }
}
// phase 3: add block offsets
__global__ __launch_bounds__(512) void scan_add(int* __restrict__ offs,
                                                const int* __restrict__ boff) {
    int i = blockIdx.x * 512 + threadIdx.x;
    offs[i] += boff[blockIdx.x];
}
__global__ void fill_edges(const int* __restrict__ etype, const int* __restrict__ dst,
                           const int* __restrict__ src, int* __restrict__ cursor,
                           int* __restrict__ srcs_s, int* __restrict__ dsts_s) {
    int e = blockIdx.x * 256 + threadIdx.x;
    if (e >= EE) return;
    int pos = atomicAdd(&cursor[etype[e] * NP + dst[e]], 1);
    srcs_s[pos] = src[e];
    dsts_s[pos] = dst[e];
}

// ---------- pad input -> bf16 h (zeros for d>=256 and rows>=NN) ----------
__global__ void pad2(const float* __restrict__ in_feat, ushort* __restrict__ h) {
    int idx = blockIdx.x * 256 + threadIdx.x;   // one per 8 elems
    if (idx >= NP * 64) return;
    int n = idx >> 6, o = (idx & 63) * 8;
    u16x8 ov = {0,0,0,0,0,0,0,0};
    if (n < NN && o < IN_F) {
        f4 a = *(const f4*)(in_feat + (size_t)n * IN_F + o);
        f4 b = *(const f4*)(in_feat + (size_t)n * IN_F + o + 4);
        ov = (u16x8){ f2b(a[0]), f2b(a[1]), f2b(a[2]), f2b(a[3]),
                      f2b(b[0]), f2b(b[1]), f2b(b[2]), f2b(b[3]) };
    }
    *(u16x8*)(h + (size_t)n * 512 + o) = ov;
}

// ---------- gather for k-pair: S2[kl][v][:] = sum of hbf[src] over in-edges of etype kp*2+kl ----------
__global__ void gather2(const int* __restrict__ offs, const int* __restrict__ srcs,
                        const ushort* __restrict__ hin, ushort* __restrict__ S2, int kp) {
    int wv = threadIdx.x >> 6, lane = threadIdx.x & 63;
    int r = blockIdx.x * 4 + wv;                 // [0, 2*NP)
    int kl = (r >= NP) ? 1 : 0;
    int v = r - kl * NP;
    int k = kp * 2 + kl;
    int beg = offs[k * NP + v], end = offs[k * NP + v + 1];
    float acc[8] = {0,0,0,0,0,0,0,0};
    for (int e = beg; e < end; e++) {
        int s = srcs[e];
        u16x8 hv = *(const u16x8*)(hin + (size_t)s * 512 + lane * 8);
#pragma unroll
        for (int j = 0; j < 8; j++) acc[j] += b2f(hv[j]);
    }
    u16x8 ov;
#pragma unroll
    for (int j = 0; j < 8; j++) ov[j] = f2b(acc[j]);
    *(u16x8*)(S2 + ((size_t)kl * NP + v) * 512 + lane * 8) = ov;
}

// ---------- generic MFMA GEMM, 128x128 tile, bf16 out, global_load_lds staging ----------
// C[node][o] = sum_k B[node][k] * W[o][k], K split at 512 between (Wa,Ba) and (Wb,Bb).
// flags: 1 = accumulate into existing bf16 C; 2 = add sum_k cntf[k*NP+node]*bmsg[k*512+o]
__global__ __launch_bounds__(256) void gemm2(
    const ushort* __restrict__ Wa, const ushort* __restrict__ Wb, int swA,
    const ushort* __restrict__ Ba, const ushort* __restrict__ Bb, int Kt,
    ushort* __restrict__ C, int ldC, int flags,
    const float* __restrict__ cntf, const float* __restrict__ bmsg) {
    __shared__ ushort As[128 * 64];
    __shared__ ushort Bs[128 * 64];
    int t = threadIdx.x;
    int n0 = blockIdx.x * 128, o0 = blockIdx.y * 128;
    int wave = t >> 6, lane = t & 63;
    int wm = wave & 1, wn = wave >> 1;
    int l16 = lane & 15, quad = lane >> 4;
    f4 acc[4][4];
#pragma unroll
    for (int i = 0; i < 4; i++)
#pragma unroll
        for (int j = 0; j < 4; j++) acc[i][j] = (f4){0,0,0,0};
    for (int kk = 0; kk < Kt; kk += 64) {
        const ushort* Wsrc = (kk < 512) ? Wa : Wb;
        const ushort* Bsrc = (kk < 512) ? Ba : Bb;
        int ko = kk & 511;
#pragma unroll
        for (int i = 0; i < 4; i++) {
            int c = i * 256 + t;                  // 16B chunk id, 0..1023
            int row = c >> 3, col = (c & 7) << 3; // col in ushorts
            int ldsoff = (i * 256 + wave * 64) * 8;   // wave-uniform, lane*16B added by HW
            GLD_LDS(Wsrc + (size_t)(o0 + row) * swA + ko + col, As + ldsoff);
            GLD_LDS(Bsrc + (size_t)(n0 + row) * 512 + ko + col, Bs + ldsoff);
        }
        __syncthreads();
#pragma unroll
        for (int ks = 0; ks < 64; ks += 32) {
            s16x8 af[4], bf[4];
#pragma unroll
            for (int mi = 0; mi < 4; mi++)
                af[mi] = *(const s16x8*)&As[(wm*64 + mi*16 + l16) * 64 + ks + quad*8];
#pragma unroll
            for (int ni = 0; ni < 4; ni++)
                bf[ni] = *(const s16x8*)&Bs[(wn*64 + ni*16 + l16) * 64 + ks + quad*8];
#pragma unroll
            for (int mi = 0; mi < 4; mi++)
#pragma unroll
                for (int ni = 0; ni < 4; ni++)
                    acc[mi][ni] = __builtin_amdgcn_mfma_f32_16x16x32_bf16(af[mi], bf[ni], acc[mi][ni], 0, 0, 0);
        }
        __syncthreads();
    }
#pragma unroll
    for (int ni = 0; ni < 4; ni++) {
        int node = n0 + wn*64 + ni*16 + l16;
#pragma unroll
        for (int mi = 0; mi < 4; mi++) {
            int o = o0 + wm*64 + mi*16 + quad*4;
            f4 v = acc[mi][ni];
            if (flags & 2) {
#pragma unroll
                for (int k = 0; k < KT; k++) {
                    float ck = cntf[k * NP + node];
                    f4 bm = *(const f4*)(bmsg + k * 512 + o);
                    v += ck * bm;
                }
            }
            ushort* cp = C + (size_t)node * ldC + o;
            if (flags & 1) {
                u16x4 old = *(const u16x4*)cp;
                v += (f4){ b2f(old[0]), b2f(old[1]), b2f(old[2]), b2f(old[3]) };
            }
            u16x4 ov = { f2b(v[0]), f2b(v[1]), f2b(v[2]), f2b(v[3]) };
            *(u16x4*)cp = ov;
        }
    }
}

// ---------- GRU elementwise: h_out = (1-z)*tanh(in + bin + r*(hn + bhn)) + z*h_old ----------
// io holds i_n on entry, receives h_out (same addresses, thread-local)
__global__ void gru_ew(const ushort* __restrict__ rz, const ushort* __restrict__ hnb,
                       const ushort* __restrict__ hin, ushort* __restrict__ io,
                       const float* __restrict__ b_ih, const float* __restrict__ b_hh) {
    int idx = blockIdx.x * 256 + threadIdx.x;   // one per 8 elems
    int n = idx >> 6, o = (idx & 63) * 8;
    u16x8 rz1 = *(const u16x8*)(rz + (size_t)n * 1024 + o);
    u16x8 rz2 = *(const u16x8*)(rz + (size_t)n * 1024 + 512 + o);
    u16x8 inn = *(const u16x8*)(io + (size_t)n * 512 + o);
    u16x8 hnn = *(const u16x8*)(hnb + (size_t)n * 512 + o);
    u16x8 hol = *(const u16x8*)(hin + (size_t)n * 512 + o);
    u16x8 ov;
#pragma unroll
    for (int j = 0; j < 8; j++) {
        float r = sgm(b2f(rz1[j]) + b_ih[o + j] + b_hh[o + j]);
        float z = sgm(b2f(rz2[j]) + b_ih[512 + o + j] + b_hh[512 + o + j]);
        float nv = tanhf(b2f(inn[j]) + b_ih[1024 + o + j] + r * (b2f(hnn[j]) + b_hh[1024 + o + j]));
        ov[j] = f2b((1.f - z) * nv + z * b2f(hol[j]));
    }
    *(u16x8*)(io + (size_t)n * 512 + o) = ov;
}

// ---------- L2 normalize + sigmoid (bf16 in/out), one wave per node ----------
__global__ void norm_sig(ushort* __restrict__ h) {
    int n = blockIdx.x, lane = threadIdx.x;   // 64 threads
    u16x8 v = *(const u16x8*)(h + (size_t)n * 512 + lane * 8);
    float f[8], ss = 0.f;
#pragma unroll
    for (int j = 0; j < 8; j++) { f[j] = b2f(v[j]); ss += f[j] * f[j]; }
    for (int off = 32; off > 0; off >>= 1) ss += __shfl_xor(ss, off);
    float inv = 1.f / fmaxf(sqrtf(ss), 1e-12f);
    u16x8 ov;
#pragma unroll
    for (int j = 0; j < 8; j++) ov[j] = f2b(sgm(f[j] * inv));
    *(u16x8*)(h + (size_t)n * 512 + lane * 8) = ov;
}

// ---------- el/er from bf16 feat, one wave per node ----------
__global__ void el_er2(const ushort* __restrict__ feat, const float* __restrict__ attn_l,
                       const float* __restrict__ attn_r, float* __restrict__ el,
                       float* __restrict__ er) {
    int n = blockIdx.x, lane = threadIdx.x;   // 64
    int head = lane >> 5;
    int ld = (lane * 8) & 255;
    u16x8 v = *(const u16x8*)(feat + (size_t)n * 512 + lane * 8);
    float sl = 0.f, sr = 0.f;
#pragma unroll
    for (int j = 0; j < 8; j++) {
        float f = b2f(v[j]);
        sl += f * attn_l[head * 256 + ld + j];
        sr += f * attn_r[head * 256 + ld + j];
    }
    for (int off = 16; off > 0; off >>= 1) { sl += __shfl_xor(sl, off); sr += __shfl_xor(sr, off); }
    if ((lane & 31) == 0) { el[n * 2 + head] = sl; er[n * 2 + head] = sr; }
}

// ---------- per-CSR-slot edge scores (leaky relu), both heads ----------
__global__ void edge_scores(const int* __restrict__ srcs, const int* __restrict__ dsts,
                            const float* __restrict__ el, const float* __restrict__ er,
                            float* __restrict__ esc) {
    int e = blockIdx.x * 256 + threadIdx.x;
    if (e >= EE) return;
    int s = srcs[e], d = dsts[e];
    f2 elv = *(const f2*)(el + (size_t)s * 2);
    f2 erv = *(const f2*)(er + (size_t)d * 2);
    float s0 = elv[0] + erv[0]; s0 = s0 < 0.f ? 0.2f * s0 : s0;
    float s1 = elv[1] + erv[1]; s1 = s1 < 0.f ? 0.2f * s1 : s1;
    *(f2*)(esc + (size_t)e * 2) = (f2){ s0, s1 };
}

// ---------- fused GAT: softmax over in-edges + aggregation + bias/relu, rst f32 out (no atomics) ----------
__global__ void gat3(const int* __restrict__ offs, const int* __restrict__ srcs,
                     const float* __restrict__ esc, const ushort* __restrict__ feat,
                     const float* __restrict__ gat_bias, float* __restrict__ rst) {
    int wave = threadIdx.x >> 6, lane = threadIdx.x & 63;
    int v = blockIdx.x * 4 + wave;
    int beg[KT], end[KT];
#pragma unroll
    for (int k = 0; k < KT; k++) { beg[k] = offs[k * NP + v]; end[k] = offs[k * NP + v + 1]; }
    float m0 = -1e30f, m1 = -1e30f;
#pragma unroll
    for (int k = 0; k < KT; k++)
        for (int base = beg[k]; base < end[k]; base += 64) {
            int e = base + lane;
            if (e < end[k]) {
                f2 s = *(const f2*)(esc + (size_t)e * 2);
                m0 = fmaxf(m0, s[0]); m1 = fmaxf(m1, s[1]);
            }
        }
    for (int off = 32; off > 0; off >>= 1) {
        m0 = fmaxf(m0, __shfl_xor(m0, off));
        m1 = fmaxf(m1, __shfl_xor(m1, off));
    }
    float d0 = 0.f, d1 = 0.f;
#pragma unroll
    for (int k = 0; k < KT; k++)
        for (int base = beg[k]; base < end[k]; base += 64) {
            int e = base + lane;
            if (e < end[k]) {
                f2 s = *(const f2*)(esc + (size_t)e * 2);
                d0 += __expf(s[0] - m0); d1 += __expf(s[1] - m1);
            }
        }
    for (int off = 32; off > 0; off >>= 1) { d0 += __shfl_xor(d0, off); d1 += __shfl_xor(d1, off); }
    int head = lane >> 5;
    float mm = head ? m1 : m0;
    float iv = head ? (d1 > 0.f ? 1.f / d1 : 0.f) : (d0 > 0.f ? 1.f / d0 : 0.f);
    float acc[8] = {0,0,0,0,0,0,0,0};
#pragma unroll
    for (int k = 0; k < KT; k++)
        for (int e = beg[k]; e < end[k]; e++) {
            float sc = esc[(size_t)e * 2 + head];
            float al = __expf(sc - mm) * iv;
            u16x8 fv = *(const u16x8*)(feat + (size_t)srcs[e] * 512 + lane * 8);
#pragma unroll
            for (int j = 0; j < 8; j++) acc[j] += al * b2f(fv[j]);
        }
    int di = lane * 8;
    f4 o0, o1;
#pragma unroll
    for (int j = 0; j < 4; j++) {
        o0[j] = fmaxf(acc[j] + gat_bias[di + j], 0.f);
        o1[j] = fmaxf(acc[4 + j] + gat_bias[di + 4 + j], 0.f);
    }
    *(f4*)(rst + (size_t)v * 512 + di) = o0;
    *(f4*)(rst + (size_t)v * 512 + di + 4) = o1;
}

// ---------- graph boundaries via binary search on sorted graph_ids ----------
__global__ void graph_bounds(const int* __restrict__ gids, int* __restrict__ goff) {
    int g = threadIdx.x;   // 128 threads, need 0..64
    if (g > GG) return;
    int lo = 0, hi = NN;
    while (lo < hi) { int mid = (lo + hi) >> 1; if (gids[mid] < g) lo = mid + 1; else hi = mid; }
    goff[g] = lo;
}

// ---------- per-graph mean of rst -> hgm ----------
__global__ void graph_mean(const float* __restrict__ rst, const int* __restrict__ goff,
                           float* __restrict__ hgm) {
    int g = blockIdx.x;
    int c = blockIdx.y * 256 + threadIdx.x;
    int beg = goff[g], end = goff[g + 1];
    float s = 0.f;
    for (int n = beg; n < end; n++) s += rst[(size_t)n * 512 + c];
    float inv = (end > beg) ? 1.f / (float)(end - beg) : 0.f;
    hgm[g * 512 + c] = s * inv;
}

// ---------- classify ----------
__global__ void classify(const float* __restrict__ hgm, const float* __restrict__ cw,
                         const float* __restrict__ cb, float* __restrict__ out) {
    __shared__ float hl[512];
    int g = blockIdx.x, t = threadIdx.x;  // 64 threads
    for (int d = t; d < 512; d += 64) hl[d] = hgm[g * 512 + d];
    __syncthreads();
    if (t < 32) {
        int hd = t >> 4, c = t & 15;
        float acc = 0.f;
        for (int d = 0; d < 256; d++) acc += hl[hd * 256 + d] * cw[c * 256 + d];
        out[(g * 2 + hd) * NC + c] = acc + cb[c];
    }
}

static inline int cdiv(int a, int b) { return (a + b - 1) / b; }
static inline size_t alup(size_t x) { return (x + 255) & ~(size_t)255; }

extern "C" void kernel_launch(void* const* d_in, const int* in_sizes, int n_in,
                              void* d_out, int out_size, void* d_ws, size_t ws_size,
                              hipStream_t stream) {
    const float* in_feat   = (const float*)d_in[0];
    const int*   src       = (const int*)d_in[1];
    const int*   dst       = (const int*)d_in[2];
    const int*   etype     = (const int*)d_in[3];
    const int*   graph_ids = (const int*)d_in[4];
    const float* Wmsg      = (const float*)d_in[5];
    const float* bmsg      = (const float*)d_in[6];
    const float* w_ih      = (const float*)d_in[7];
    const float* w_hh      = (const float*)d_in[8];
    const float* b_ih      = (const float*)d_in[9];
    const float* b_hh      = (const float*)d_in[10];
    const float* fc_w      = (const float*)d_in[11];
    const float* attn_l    = (const float*)d_in[12];
    const float* attn_r    = (const float*)d_in[13];
    const float* gat_bias  = (const float*)d_in[14];
    const float* cw        = (const float*)d_in[15];
    const float* cb        = (const float*)d_in[16];
    float* out = (float*)d_out;

    char* p = (char*)d_ws;
    ushort* hbfA  = (ushort*)p; p += alup((size_t)NP * 512 * 2);
    ushort* hbfB  = (ushort*)p; p += alup((size_t)NP * 512 * 2);
    ushort* abf   = (ushort*)p; p += alup((size_t)NP * 512 * 2);
    ushort* S2    = (ushort*)p; p += alup((size_t)2 * NP * 512 * 2);  // rz (NP x 1024); later rst f32 (NP x 512)
    ushort* wmsgT = (ushort*)p; p += alup((size_t)KT * 512 * 512 * 2);
    ushort* wihb  = (ushort*)p; p += alup((size_t)1536 * 512 * 2);
    ushort* whhb  = (ushort*)p; p += alup((size_t)1536 * 512 * 2);
    ushort* wrz   = (ushort*)p; p += alup((size_t)1024 * 1024 * 2);
    ushort* fcb   = (ushort*)p; p += alup((size_t)512 * 512 * 2);
    int*    cnt   = (int*)p;    p += alup((size_t)TOTKV * 4);
    int*    offs  = (int*)p;    p += alup(((size_t)TOTKV + 1) * 4);
    int*    cursor= (int*)p;    p += alup(((size_t)TOTKV + 1) * 4);
    float*  cntf  = (float*)p;  p += alup((size_t)TOTKV * 4);
    int*    bsum  = (int*)p;    p += alup((size_t)NBLK * 4);
    int*    boff  = (int*)p;    p += alup((size_t)NBLK * 4);
    int*    srcs_s= (int*)p;    p += alup((size_t)EE * 4);
    int*    dsts_s= (int*)p;    p += alup((size_t)EE * 4);
    float*  esc   = (float*)p;  p += alup((size_t)EE * 2 * 4);
    float*  el    = (float*)p;  p += alup((size_t)NN * 2 * 4);
    float*  er    = (float*)p;  p += alup((size_t)NN * 2 * 4);
    int*    goff  = (int*)p;    p += alup((size_t)(GG + 1) * 4);
    float*  hgm   = (float*)p;  p += alup((size_t)GG * 512 * 4);
    ushort* featbf = abf;          // alias: abf free after last gru_ew
    float*  rst    = (float*)S2;   // alias: rz region free after last gru_ew (same byte size)

    // ---- weight prep ----
    conv_msgT<<<cdiv(KT * 512 * 512, 256), 256, 0, stream>>>(Wmsg, wmsgT);
    conv_copy<<<cdiv(1536 * 512, 256), 256, 0, stream>>>(w_ih, wihb, 1536 * 512);
    conv_copy<<<cdiv(1536 * 512, 256), 256, 0, stream>>>(w_hh, whhb, 1536 * 512);
    build_wrz<<<cdiv(1024 * 1024, 256), 256, 0, stream>>>(w_ih, w_hh, wrz);
    conv_copy<<<cdiv(512 * 512, 256), 256, 0, stream>>>(fc_w, fcb, 512 * 512);

    // ---- CSR build ----
    hipMemsetAsync(cnt, 0, (size_t)TOTKV * 4, stream);
    count_edges<<<cdiv(EE, 256), 256, 0, stream>>>(etype, dst, cnt);
    scan_blk<<<NBLK, 512, 0, stream>>>(cnt, offs, cntf, bsum);
    scan_top<<<1, 64, 0, stream>>>(bsum, boff, offs);
    scan_add<<<NBLK, 512, 0, stream>>>(offs, boff);
    hipMemcpyAsync(cursor, offs, (size_t)TOTKV * 4, hipMemcpyDeviceToDevice, stream);
    fill_edges<<<cdiv(EE, 256), 256, 0, stream>>>(etype, dst, src, cursor, srcs_s, dsts_s);
    graph_bounds<<<1, 128, 0, stream>>>(graph_ids, goff);

    pad2<<<cdiv(NP * 64, 256), 256, 0, stream>>>(in_feat, hbfA);

    const ushort* win = wihb + (size_t)1024 * 512;   // n-gate rows of w_ih
    const ushort* whn = whhb + (size_t)1024 * 512;   // n-gate rows of w_hh

    ushort* hin = hbfA;
    ushort* hout = hbfB;
    for (int step = 0; step < NSTEPS; step++) {
        // message passing: abf = sum_k S_k @ Wmsg_k^T + sum_k cnt_k*bmsg_k   (bf16)
        gather2<<<2 * NP / 4, 256, 0, stream>>>(offs, srcs_s, hin, S2, 0);
        gemm2<<<dim3(NP / 128, 4), 256, 0, stream>>>(
            wmsgT, wmsgT + (size_t)1 * 262144, 512, S2, S2 + (size_t)NP * 512, 1024,
            abf, 512, 0, nullptr, nullptr);
        gather2<<<2 * NP / 4, 256, 0, stream>>>(offs, srcs_s, hin, S2, 1);
        gemm2<<<dim3(NP / 128, 4), 256, 0, stream>>>(
            wmsgT + (size_t)2 * 262144, wmsgT + (size_t)3 * 262144, 512, S2, S2 + (size_t)NP * 512, 1024,
            abf, 512, 3, cntf, bmsg);
        // GRU: rz = [abf|hin] @ Wrz^T  (K=1024, M=1024) -> S2 region
        gemm2<<<dim3(NP / 128, 8), 256, 0, stream>>>(
            wrz, wrz + 512, 1024, abf, hin, 1024, S2, 1024, 0, nullptr, nullptr);
        // i_n = abf @ win^T -> hout region
        gemm2<<<dim3(NP / 128, 4), 256, 0, stream>>>(
            win, win, 512, abf, abf, 512, hout, 512, 0, nullptr, nullptr);
        // h_n = hin @ whn^T -> abf region (abf no longer needed)
        gemm2<<<dim3(NP / 128, 4), 256, 0, stream>>>(
            whn, whn, 512, hin, hin, 512, abf, 512, 0, nullptr, nullptr);
        // elementwise GRU combine -> hout (in place over i_n)
        gru_ew<<<NP * 64 / 256, 256, 0, stream>>>(S2, abf, hin, hout, b_ih, b_hh);
        ushort* tmp = hin; hin = hout; hout = tmp;
    }
    // hin now holds final h (hbfA after 4 steps)

    norm_sig<<<NN, 64, 0, stream>>>(hin);
    // feat = h @ fc_w^T  (bf16) -> featbf (abf region)
    gemm2<<<dim3(NP / 128, 4), 256, 0, stream>>>(
        fcb, fcb, 512, hin, hin, 512, featbf, 512, 0, nullptr, nullptr);
    el_er2<<<NN, 64, 0, stream>>>(featbf, attn_l, attn_r, el, er);
    edge_scores<<<cdiv(EE, 256), 256, 0, stream>>>(srcs_s, dsts_s, el, er, esc);

    gat3<<<NN / 4, 256, 0, stream>>>(offs, srcs_s, esc, featbf, gat_bias, rst);
    graph_mean<<<dim3(GG, 2), 256, 0, stream>>>(rst, goff, hgm);
    classify<<<GG, 64, 0, stream>>>(hgm, cw, cb, out);
}

// Round 7
// 1799.125 us; speedup vs baseline: 7.7128x; 1.1714x over previous
//
#include <hip/hip_runtime.h>
#include <math.h>

#define NN 20000
#define NP 20096           // NN padded to 128 (157 tiles)
#define EE 320000
#define GG 64
#define IN_F 256
#define NC 16
#define NSTEPS 4
#define KT 4
#define TOTKV (KT*NP)      // 80384 = 157 * 512
#define NBLK 157

typedef unsigned int uint;
typedef unsigned short ushort;
typedef __attribute__((ext_vector_type(2))) float f2;
typedef __attribute__((ext_vector_type(4))) float f4;
typedef __attribute__((ext_vector_type(4))) ushort u16x4;
typedef __attribute__((ext_vector_type(8))) ushort u16x8;
typedef __attribute__((ext_vector_type(8))) short s16x8;

#define GLD_LDS(gp, lp) __builtin_amdgcn_global_load_lds( \
    (const __attribute__((address_space(1))) void*)(gp),  \
    (__attribute__((address_space(3))) void*)(lp), 16, 0, 0)

__device__ __forceinline__ ushort f2b(float f) {
    uint u = __float_as_uint(f);
    u = (u + 0x7FFFu + ((u >> 16) & 1u)) >> 16;   // RNE f32->bf16
    return (ushort)u;
}
__device__ __forceinline__ float b2f(ushort s) { return __uint_as_float(((uint)s) << 16); }
__device__ __forceinline__ float sgm(float x) { return 1.f / (1.f + __expf(-x)); }
__device__ __forceinline__ float ftanh(float x) { return 2.f / (1.f + __expf(-2.f * x)) - 1.f; }

// ---------- weight prep ----------
__global__ void conv_msgT(const float* __restrict__ Wm, ushort* __restrict__ WT) {
    // WT[k][o][d] <- Wmsg[k][d][o]
    int idx = blockIdx.x * 256 + threadIdx.x;
    if (idx >= KT * 512 * 512) return;
    int k = idx >> 18, rem = idx & 262143;
    int o = rem >> 9, d = rem & 511;
    WT[idx] = f2b(Wm[(k << 18) + (d << 9) + o]);
}
__global__ void conv_copy(const float* __restrict__ x, ushort* __restrict__ y, int n) {
    int i = blockIdx.x * 256 + threadIdx.x;
    if (i < n) y[i] = f2b(x[i]);
}
// Wrz[o2][k2]: o2<512 -> r-gate rows, o2>=512 -> z-gate; k2<512 from w_ih, else w_hh
__global__ void build_wrz(const float* __restrict__ wih, const float* __restrict__ whh,
                          ushort* __restrict__ W) {
    int idx = blockIdx.x * 256 + threadIdx.x;
    if (idx >= 1024 * 1024) return;
    int o2 = idx >> 10, k2 = idx & 1023;
    int gate = o2 >> 9, o = o2 & 511;
    float v = (k2 < 512) ? wih[(gate * 512 + o) * 512 + k2]
                         : whh[(gate * 512 + o) * 512 + (k2 - 512)];
    W[idx] = f2b(v);
}

// ---------- CSR build (etype-major, dst-minor) ----------
__global__ void count_edges(const int* __restrict__ etype, const int* __restrict__ dst,
                            int* __restrict__ cnt) {
    int e = blockIdx.x * 256 + threadIdx.x;
    if (e >= EE) return;
    atomicAdd(&cnt[etype[e] * NP + dst[e]], 1);
}
// phase 1: per-block (512 elems) exclusive scan + block sum
__global__ __launch_bounds__(512) void scan_blk(const int* __restrict__ cnt,
                                                int* __restrict__ offs,
                                                float* __restrict__ cntf,
                                                int* __restrict__ bsum) {
    __shared__ int sh[512];
    int t = threadIdx.x, b = blockIdx.x;
    int i = b * 512 + t;
    int v = cnt[i];
    sh[t] = v; __syncthreads();
    for (int off = 1; off < 512; off <<= 1) {
        int add = (t >= off) ? sh[t - off] : 0;
        __syncthreads();
        sh[t] += add;
        __syncthreads();
    }
    offs[i] = sh[t] - v;         // local exclusive
    cntf[i] = (float)v;
    if (t == 511) bsum[b] = sh[511];
}
// phase 2: scan the 157 block sums
__global__ void scan_top(const int* __restrict__ bsum, int* __restrict__ boff,
                         int* __restrict__ offs) {
    if (threadIdx.x == 0) {
        int run = 0;
        for (int i = 0; i < NBLK; i++) { boff[i] = run; run += bsum[i]; }
        offs[TOTKV] = run;
    }
}
// phase 3: add block offsets
__global__ __launch_bounds__(512) void scan_add(int* __restrict__ offs,
                                                const int* __restrict__ boff) {
    int i = blockIdx.x * 512 + threadIdx.x;
    offs[i] += boff[blockIdx.x];
}
__global__ void fill_edges(const int* __restrict__ etype, const int* __restrict__ dst,
                           const int* __restrict__ src, int* __restrict__ cursor,
                           int* __restrict__ srcs_s, int* __restrict__ dsts_s) {
    int e = blockIdx.x * 256 + threadIdx.x;
    if (e >= EE) return;
    int pos = atomicAdd(&cursor[etype[e] * NP + dst[e]], 1);
    srcs_s[pos] = src[e];
    dsts_s[pos] = dst[e];
}

// ---------- pad input -> bf16 h (zeros for d>=256 and rows>=NN) ----------
__global__ void pad2(const float* __restrict__ in_feat, ushort* __restrict__ h) {
    int idx = blockIdx.x * 256 + threadIdx.x;   // one per 8 elems
    if (idx >= NP * 64) return;
    int n = idx >> 6, o = (idx & 63) * 8;
    u16x8 ov = {0,0,0,0,0,0,0,0};
    if (n < NN && o < IN_F) {
        f4 a = *(const f4*)(in_feat + (size_t)n * IN_F + o);
        f4 b = *(const f4*)(in_feat + (size_t)n * IN_F + o + 4);
        ov = (u16x8){ f2b(a[0]), f2b(a[1]), f2b(a[2]), f2b(a[3]),
                      f2b(b[0]), f2b(b[1]), f2b(b[2]), f2b(b[3]) };
    }
    *(u16x8*)(h + (size_t)n * 512 + o) = ov;
}

// ---------- gather for k-pair: S2[kl][v][:] = sum of hbf[src] over in-edges of etype kp*2+kl ----------
__global__ void gather2(const int* __restrict__ offs, const int* __restrict__ srcs,
                        const ushort* __restrict__ hin, ushort* __restrict__ S2, int kp) {
    int wv = threadIdx.x >> 6, lane = threadIdx.x & 63;
    int r = blockIdx.x * 4 + wv;                 // [0, 2*NP)
    int kl = (r >= NP) ? 1 : 0;
    int v = r - kl * NP;
    int k = kp * 2 + kl;
    int beg = offs[k * NP + v], end = offs[k * NP + v + 1];
    float acc[8] = {0,0,0,0,0,0,0,0};
    for (int e = beg; e < end; e++) {
        int s = srcs[e];
        u16x8 hv = *(const u16x8*)(hin + (size_t)s * 512 + lane * 8);
#pragma unroll
        for (int j = 0; j < 8; j++) acc[j] += b2f(hv[j]);
    }
    u16x8 ov;
#pragma unroll
    for (int j = 0; j < 8; j++) ov[j] = f2b(acc[j]);
    *(u16x8*)(S2 + ((size_t)kl * NP + v) * 512 + lane * 8) = ov;
}

// ---------- generic MFMA GEMM, 128x128 tile, bf16 out, global_load_lds staging ----------
// C[node][o] = sum_k B[node][k] * W[o][k], K split at 512 between (Wa,Ba) and (Wb,Bb).
// flags: 1 = accumulate into existing bf16 C; 2 = add sum_k cntf[k*NP+node]*bmsg[k*512+o]
__global__ __launch_bounds__(256) void gemm2(
    const ushort* __restrict__ Wa, const ushort* __restrict__ Wb, int swA,
    const ushort* __restrict__ Ba, const ushort* __restrict__ Bb, int Kt,
    ushort* __restrict__ C, int ldC, int flags,
    const float* __restrict__ cntf, const float* __restrict__ bmsg) {
    __shared__ ushort As[128 * 64];
    __shared__ ushort Bs[128 * 64];
    int t = threadIdx.x;
    int n0 = blockIdx.x * 128, o0 = blockIdx.y * 128;
    int wave = t >> 6, lane = t & 63;
    int wm = wave & 1, wn = wave >> 1;
    int l16 = lane & 15, quad = lane >> 4;
    f4 acc[4][4];
#pragma unroll
    for (int i = 0; i < 4; i++)
#pragma unroll
        for (int j = 0; j < 4; j++) acc[i][j] = (f4){0,0,0,0};
    for (int kk = 0; kk < Kt; kk += 64) {
        const ushort* Wsrc = (kk < 512) ? Wa : Wb;
        const ushort* Bsrc = (kk < 512) ? Ba : Bb;
        int ko = kk & 511;
#pragma unroll
        for (int i = 0; i < 4; i++) {
            int c = i * 256 + t;                  // 16B chunk id, 0..1023
            int row = c >> 3, col = (c & 7) << 3; // col in ushorts
            int ldsoff = (i * 256 + wave * 64) * 8;   // wave-uniform, lane*16B added by HW
            GLD_LDS(Wsrc + (size_t)(o0 + row) * swA + ko + col, As + ldsoff);
            GLD_LDS(Bsrc + (size_t)(n0 + row) * 512 + ko + col, Bs + ldsoff);
        }
        __syncthreads();
#pragma unroll
        for (int ks = 0; ks < 64; ks += 32) {
            s16x8 af[4], bf[4];
#pragma unroll
            for (int mi = 0; mi < 4; mi++)
                af[mi] = *(const s16x8*)&As[(wm*64 + mi*16 + l16) * 64 + ks + quad*8];
#pragma unroll
            for (int ni = 0; ni < 4; ni++)
                bf[ni] = *(const s16x8*)&Bs[(wn*64 + ni*16 + l16) * 64 + ks + quad*8];
#pragma unroll
            for (int mi = 0; mi < 4; mi++)
#pragma unroll
                for (int ni = 0; ni < 4; ni++)
                    acc[mi][ni] = __builtin_amdgcn_mfma_f32_16x16x32_bf16(af[mi], bf[ni], acc[mi][ni], 0, 0, 0);
        }
        __syncthreads();
    }
#pragma unroll
    for (int ni = 0; ni < 4; ni++) {
        int node = n0 + wn*64 + ni*16 + l16;
#pragma unroll
        for (int mi = 0; mi < 4; mi++) {
            int o = o0 + wm*64 + mi*16 + quad*4;
            f4 v = acc[mi][ni];
            if (flags & 2) {
#pragma unroll
                for (int k = 0; k < KT; k++) {
                    float ck = cntf[k * NP + node];
                    f4 bm = *(const f4*)(bmsg + k * 512 + o);
                    v += ck * bm;
                }
            }
            ushort* cp = C + (size_t)node * ldC + o;
            if (flags & 1) {
                u16x4 old = *(const u16x4*)cp;
                v += (f4){ b2f(old[0]), b2f(old[1]), b2f(old[2]), b2f(old[3]) };
            }
            u16x4 ov = { f2b(v[0]), f2b(v[1]), f2b(v[2]), f2b(v[3]) };
            *(u16x4*)cp = ov;
        }
    }
}

// ---------- i_n GEMM with fused GRU epilogue ----------
// acc = abf @ win^T (i_n pre-bias). Epilogue: r/z from rz buf, hn from hnb, h_old from hin;
// writes h_new bf16 into hnb (same tile coords it reads -> no races).
__global__ __launch_bounds__(256) void gemm_gru(
    const ushort* __restrict__ W, const ushort* __restrict__ Bm,
    const ushort* __restrict__ rz, const ushort* __restrict__ hin,
    const float* __restrict__ b_ih, const float* __restrict__ b_hh,
    ushort* __restrict__ hnb) {
    __shared__ ushort As[128 * 64];
    __shared__ ushort Bs[128 * 64];
    int t = threadIdx.x;
    int n0 = blockIdx.x * 128, o0 = blockIdx.y * 128;
    int wave = t >> 6, lane = t & 63;
    int wm = wave & 1, wn = wave >> 1;
    int l16 = lane & 15, quad = lane >> 4;
    f4 acc[4][4];
#pragma unroll
    for (int i = 0; i < 4; i++)
#pragma unroll
        for (int j = 0; j < 4; j++) acc[i][j] = (f4){0,0,0,0};
    for (int kk = 0; kk < 512; kk += 64) {
#pragma unroll
        for (int i = 0; i < 4; i++) {
            int c = i * 256 + t;
            int row = c >> 3, col = (c & 7) << 3;
            int ldsoff = (i * 256 + wave * 64) * 8;
            GLD_LDS(W + (size_t)(o0 + row) * 512 + kk + col, As + ldsoff);
            GLD_LDS(Bm + (size_t)(n0 + row) * 512 + kk + col, Bs + ldsoff);
        }
        __syncthreads();
#pragma unroll
        for (int ks = 0; ks < 64; ks += 32) {
            s16x8 af[4], bf[4];
#pragma unroll
            for (int mi = 0; mi < 4; mi++)
                af[mi] = *(const s16x8*)&As[(wm*64 + mi*16 + l16) * 64 + ks + quad*8];
#pragma unroll
            for (int ni = 0; ni < 4; ni++)
                bf[ni] = *(const s16x8*)&Bs[(wn*64 + ni*16 + l16) * 64 + ks + quad*8];
#pragma unroll
            for (int mi = 0; mi < 4; mi++)
#pragma unroll
                for (int ni = 0; ni < 4; ni++)
                    acc[mi][ni] = __builtin_amdgcn_mfma_f32_16x16x32_bf16(af[mi], bf[ni], acc[mi][ni], 0, 0, 0);
        }
        __syncthreads();
    }
#pragma unroll
    for (int ni = 0; ni < 4; ni++) {
        int node = n0 + wn*64 + ni*16 + l16;
#pragma unroll
        for (int mi = 0; mi < 4; mi++) {
            int o = o0 + wm*64 + mi*16 + quad*4;
            u16x4 rz1 = *(const u16x4*)(rz + (size_t)node * 1024 + o);
            u16x4 rz2 = *(const u16x4*)(rz + (size_t)node * 1024 + 512 + o);
            u16x4 hnv = *(const u16x4*)(hnb + (size_t)node * 512 + o);
            u16x4 hol = *(const u16x4*)(hin + (size_t)node * 512 + o);
            f4 bi0 = *(const f4*)(b_ih + o);
            f4 bi1 = *(const f4*)(b_ih + 512 + o);
            f4 bi2 = *(const f4*)(b_ih + 1024 + o);
            f4 bh0 = *(const f4*)(b_hh + o);
            f4 bh1 = *(const f4*)(b_hh + 512 + o);
            f4 bh2 = *(const f4*)(b_hh + 1024 + o);
            u16x4 ov;
#pragma unroll
            for (int r = 0; r < 4; r++) {
                float rg = sgm(b2f(rz1[r]) + bi0[r] + bh0[r]);
                float zg = sgm(b2f(rz2[r]) + bi1[r] + bh1[r]);
                float nv = ftanh(acc[mi][ni][r] + bi2[r] + rg * (b2f(hnv[r]) + bh2[r]));
                ov[r] = f2b((1.f - zg) * nv + zg * b2f(hol[r]));
            }
            *(u16x4*)(hnb + (size_t)node * 512 + o) = ov;
        }
    }
}

// ---------- L2 normalize + sigmoid (bf16 in/out), one wave per node ----------
__global__ void norm_sig(ushort* __restrict__ h) {
    int n = blockIdx.x, lane = threadIdx.x;   // 64 threads
    u16x8 v = *(const u16x8*)(h + (size_t)n * 512 + lane * 8);
    float f[8], ss = 0.f;
#pragma unroll
    for (int j = 0; j < 8; j++) { f[j] = b2f(v[j]); ss += f[j] * f[j]; }
    for (int off = 32; off > 0; off >>= 1) ss += __shfl_xor(ss, off);
    float inv = 1.f / fmaxf(sqrtf(ss), 1e-12f);
    u16x8 ov;
#pragma unroll
    for (int j = 0; j < 8; j++) ov[j] = f2b(sgm(f[j] * inv));
    *(u16x8*)(h + (size_t)n * 512 + lane * 8) = ov;
}

// ---------- el/er from bf16 feat, one wave per node ----------
__global__ void el_er2(const ushort* __restrict__ feat, const float* __restrict__ attn_l,
                       const float* __restrict__ attn_r, float* __restrict__ el,
                       float* __restrict__ er) {
    int n = blockIdx.x, lane = threadIdx.x;   // 64
    int head = lane >> 5;
    int ld = (lane * 8) & 255;
    u16x8 v = *(const u16x8*)(feat + (size_t)n * 512 + lane * 8);
    float sl = 0.f, sr = 0.f;
#pragma unroll
    for (int j = 0; j < 8; j++) {
        float f = b2f(v[j]);
        sl += f * attn_l[head * 256 + ld + j];
        sr += f * attn_r[head * 256 + ld + j];
    }
    for (int off = 16; off > 0; off >>= 1) { sl += __shfl_xor(sl, off); sr += __shfl_xor(sr, off); }
    if ((lane & 31) == 0) { el[n * 2 + head] = sl; er[n * 2 + head] = sr; }
}

// ---------- per-CSR-slot edge scores (leaky relu), both heads ----------
__global__ void edge_scores(const int* __restrict__ srcs, const int* __restrict__ dsts,
                            const float* __restrict__ el, const float* __restrict__ er,
                            float* __restrict__ esc) {
    int e = blockIdx.x * 256 + threadIdx.x;
    if (e >= EE) return;
    int s = srcs[e], d = dsts[e];
    f2 elv = *(const f2*)(el + (size_t)s * 2);
    f2 erv = *(const f2*)(er + (size_t)d * 2);
    float s0 = elv[0] + erv[0]; s0 = s0 < 0.f ? 0.2f * s0 : s0;
    float s1 = elv[1] + erv[1]; s1 = s1 < 0.f ? 0.2f * s1 : s1;
    *(f2*)(esc + (size_t)e * 2) = (f2){ s0, s1 };
}

// ---------- fused GAT: softmax over in-edges + aggregation + bias/relu, rst f32 out (no atomics) ----------
__global__ void gat3(const int* __restrict__ offs, const int* __restrict__ srcs,
                     const float* __restrict__ esc, const ushort* __restrict__ feat,
                     const float* __restrict__ gat_bias, float* __restrict__ rst) {
    int wave = threadIdx.x >> 6, lane = threadIdx.x & 63;
    int v = blockIdx.x * 4 + wave;
    int beg[KT], end[KT];
#pragma unroll
    for (int k = 0; k < KT; k++) { beg[k] = offs[k * NP + v]; end[k] = offs[k * NP + v + 1]; }
    float m0 = -1e30f, m1 = -1e30f;
#pragma unroll
    for (int k = 0; k < KT; k++)
        for (int base = beg[k]; base < end[k]; base += 64) {
            int e = base + lane;
            if (e < end[k]) {
                f2 s = *(const f2*)(esc + (size_t)e * 2);
                m0 = fmaxf(m0, s[0]); m1 = fmaxf(m1, s[1]);
            }
        }
    for (int off = 32; off > 0; off >>= 1) {
        m0 = fmaxf(m0, __shfl_xor(m0, off));
        m1 = fmaxf(m1, __shfl_xor(m1, off));
    }
    float d0 = 0.f, d1 = 0.f;
#pragma unroll
    for (int k = 0; k < KT; k++)
        for (int base = beg[k]; base < end[k]; base += 64) {
            int e = base + lane;
            if (e < end[k]) {
                f2 s = *(const f2*)(esc + (size_t)e * 2);
                d0 += __expf(s[0] - m0); d1 += __expf(s[1] - m1);
            }
        }
    for (int off = 32; off > 0; off >>= 1) { d0 += __shfl_xor(d0, off); d1 += __shfl_xor(d1, off); }
    int head = lane >> 5;
    float mm = head ? m1 : m0;
    float iv = head ? (d1 > 0.f ? 1.f / d1 : 0.f) : (d0 > 0.f ? 1.f / d0 : 0.f);
    float acc[8] = {0,0,0,0,0,0,0,0};
#pragma unroll
    for (int k = 0; k < KT; k++)
        for (int e = beg[k]; e < end[k]; e++) {
            float sc = esc[(size_t)e * 2 + head];
            float al = __expf(sc - mm) * iv;
            u16x8 fv = *(const u16x8*)(feat + (size_t)srcs[e] * 512 + lane * 8);
#pragma unroll
            for (int j = 0; j < 8; j++) acc[j] += al * b2f(fv[j]);
        }
    int di = lane * 8;
    f4 o0, o1;
#pragma unroll
    for (int j = 0; j < 4; j++) {
        o0[j] = fmaxf(acc[j] + gat_bias[di + j], 0.f);
        o1[j] = fmaxf(acc[4 + j] + gat_bias[di + 4 + j], 0.f);
    }
    *(f4*)(rst + (size_t)v * 512 + di) = o0;
    *(f4*)(rst + (size_t)v * 512 + di + 4) = o1;
}

// ---------- graph boundaries via binary search on sorted graph_ids ----------
__global__ void graph_bounds(const int* __restrict__ gids, int* __restrict__ goff) {
    int g = threadIdx.x;   // 128 threads, need 0..64
    if (g > GG) return;
    int lo = 0, hi = NN;
    while (lo < hi) { int mid = (lo + hi) >> 1; if (gids[mid] < g) lo = mid + 1; else hi = mid; }
    goff[g] = lo;
}

// ---------- per-graph mean of rst -> hgm ----------
__global__ void graph_mean(const float* __restrict__ rst, const int* __restrict__ goff,
                           float* __restrict__ hgm) {
    int g = blockIdx.x;
    int c = blockIdx.y * 256 + threadIdx.x;
    int beg = goff[g], end = goff[g + 1];
    float s = 0.f;
    for (int n = beg; n < end; n++) s += rst[(size_t)n * 512 + c];
    float inv = (end > beg) ? 1.f / (float)(end - beg) : 0.f;
    hgm[g * 512 + c] = s * inv;
}

// ---------- classify ----------
__global__ void classify(const float* __restrict__ hgm, const float* __restrict__ cw,
                         const float* __restrict__ cb, float* __restrict__ out) {
    __shared__ float hl[512];
    int g = blockIdx.x, t = threadIdx.x;  // 64 threads
    for (int d = t; d < 512; d += 64) hl[d] = hgm[g * 512 + d];
    __syncthreads();
    if (t < 32) {
        int hd = t >> 4, c = t & 15;
        float acc = 0.f;
        for (int d = 0; d < 256; d++) acc += hl[hd * 256 + d] * cw[c * 256 + d];
        out[(g * 2 + hd) * NC + c] = acc + cb[c];
    }
}

static inline int cdiv(int a, int b) { return (a + b - 1) / b; }
static inline size_t alup(size_t x) { return (x + 255) & ~(size_t)255; }

extern "C" void kernel_launch(void* const* d_in, const int* in_sizes, int n_in,
                              void* d_out, int out_size, void* d_ws, size_t ws_size,
                              hipStream_t stream) {
    const float* in_feat   = (const float*)d_in[0];
    const int*   src       = (const int*)d_in[1];
    const int*   dst       = (const int*)d_in[2];
    const int*   etype     = (const int*)d_in[3];
    const int*   graph_ids = (const int*)d_in[4];
    const float* Wmsg      = (const float*)d_in[5];
    const float* bmsg      = (const float*)d_in[6];
    const float* w_ih      = (const float*)d_in[7];
    const float* w_hh      = (const float*)d_in[8];
    const float* b_ih      = (const float*)d_in[9];
    const float* b_hh      = (const float*)d_in[10];
    const float* fc_w      = (const float*)d_in[11];
    const float* attn_l    = (const float*)d_in[12];
    const float* attn_r    = (const float*)d_in[13];
    const float* gat_bias  = (const float*)d_in[14];
    const float* cw        = (const float*)d_in[15];
    const float* cb        = (const float*)d_in[16];
    float* out = (float*)d_out;

    char* p = (char*)d_ws;
    ushort* hbfA  = (ushort*)p; p += alup((size_t)NP * 512 * 2);
    ushort* hbfB  = (ushort*)p; p += alup((size_t)NP * 512 * 2);
    ushort* abf   = (ushort*)p; p += alup((size_t)NP * 512 * 2);
    ushort* S2    = (ushort*)p; p += alup((size_t)2 * NP * 512 * 2);  // gathered S pair / rz (NP x 1024) / rst f32
    ushort* wmsgT = (ushort*)p; p += alup((size_t)KT * 512 * 512 * 2);
    ushort* wihb  = (ushort*)p; p += alup((size_t)1536 * 512 * 2);
    ushort* whhb  = (ushort*)p; p += alup((size_t)1536 * 512 * 2);
    ushort* wrz   = (ushort*)p; p += alup((size_t)1024 * 1024 * 2);
    ushort* fcb   = (ushort*)p; p += alup((size_t)512 * 512 * 2);
    int*    cnt   = (int*)p;    p += alup((size_t)TOTKV * 4);
    int*    offs  = (int*)p;    p += alup(((size_t)TOTKV + 1) * 4);
    int*    cursor= (int*)p;    p += alup(((size_t)TOTKV + 1) * 4);
    float*  cntf  = (float*)p;  p += alup((size_t)TOTKV * 4);
    int*    bsum  = (int*)p;    p += alup((size_t)NBLK * 4);
    int*    boff  = (int*)p;    p += alup((size_t)NBLK * 4);
    int*    srcs_s= (int*)p;    p += alup((size_t)EE * 4);
    int*    dsts_s= (int*)p;    p += alup((size_t)EE * 4);
    float*  esc   = (float*)p;  p += alup((size_t)EE * 2 * 4);
    float*  el    = (float*)p;  p += alup((size_t)NN * 2 * 4);
    float*  er    = (float*)p;  p += alup((size_t)NN * 2 * 4);
    int*    goff  = (int*)p;    p += alup((size_t)(GG + 1) * 4);
    float*  hgm   = (float*)p;  p += alup((size_t)GG * 512 * 4);
    ushort* featbf = abf;          // alias: abf free after last gemm_gru
    float*  rst    = (float*)S2;   // alias: rz region free after last gemm_gru (same byte size)

    // ---- weight prep ----
    conv_msgT<<<cdiv(KT * 512 * 512, 256), 256, 0, stream>>>(Wmsg, wmsgT);
    conv_copy<<<cdiv(1536 * 512, 256), 256, 0, stream>>>(w_ih, wihb, 1536 * 512);
    conv_copy<<<cdiv(1536 * 512, 256), 256, 0, stream>>>(w_hh, whhb, 1536 * 512);
    build_wrz<<<cdiv(1024 * 1024, 256), 256, 0, stream>>>(w_ih, w_hh, wrz);
    conv_copy<<<cdiv(512 * 512, 256), 256, 0, stream>>>(fc_w, fcb, 512 * 512);

    // ---- CSR build ----
    hipMemsetAsync(cnt, 0, (size_t)TOTKV * 4, stream);
    count_edges<<<cdiv(EE, 256), 256, 0, stream>>>(etype, dst, cnt);
    scan_blk<<<NBLK, 512, 0, stream>>>(cnt, offs, cntf, bsum);
    scan_top<<<1, 64, 0, stream>>>(bsum, boff, offs);
    scan_add<<<NBLK, 512, 0, stream>>>(offs, boff);
    hipMemcpyAsync(cursor, offs, (size_t)TOTKV * 4, hipMemcpyDeviceToDevice, stream);
    fill_edges<<<cdiv(EE, 256), 256, 0, stream>>>(etype, dst, src, cursor, srcs_s, dsts_s);
    graph_bounds<<<1, 128, 0, stream>>>(graph_ids, goff);

    pad2<<<cdiv(NP * 64, 256), 256, 0, stream>>>(in_feat, hbfA);

    const ushort* win = wihb + (size_t)1024 * 512;   // n-gate rows of w_ih
    const ushort* whn = whhb + (size_t)1024 * 512;   // n-gate rows of w_hh

    ushort* hin = hbfA;
    ushort* hout = hbfB;
    for (int step = 0; step < NSTEPS; step++) {
        // message passing: abf = sum_k S_k @ Wmsg_k^T + sum_k cnt_k*bmsg_k   (bf16)
        gather2<<<2 * NP / 4, 256, 0, stream>>>(offs, srcs_s, hin, S2, 0);
        gemm2<<<dim3(NP / 128, 4), 256, 0, stream>>>(
            wmsgT, wmsgT + (size_t)1 * 262144, 512, S2, S2 + (size_t)NP * 512, 1024,
            abf, 512, 0, nullptr, nullptr);
        gather2<<<2 * NP / 4, 256, 0, stream>>>(offs, srcs_s, hin, S2, 1);
        gemm2<<<dim3(NP / 128, 4), 256, 0, stream>>>(
            wmsgT + (size_t)2 * 262144, wmsgT + (size_t)3 * 262144, 512, S2, S2 + (size_t)NP * 512, 1024,
            abf, 512, 3, cntf, bmsg);
        // GRU: rz = [abf|hin] @ Wrz^T  (K=1024, M=1024) -> S2 region
        gemm2<<<dim3(NP / 128, 8), 256, 0, stream>>>(
            wrz, wrz + 512, 1024, abf, hin, 1024, S2, 1024, 0, nullptr, nullptr);
        // h_n = hin @ whn^T -> hout region (pre-bias)
        gemm2<<<dim3(NP / 128, 4), 256, 0, stream>>>(
            whn, whn, 512, hin, hin, 512, hout, 512, 0, nullptr, nullptr);
        // i_n GEMM + fused GRU epilogue -> hout = h_new
        gemm_gru<<<dim3(NP / 128, 4), 256, 0, stream>>>(
            win, abf, S2, hin, b_ih, b_hh, hout);
        ushort* tmp = hin; hin = hout; hout = tmp;
    }
    // hin now holds final h (hbfA after 4 steps)

    norm_sig<<<NN, 64, 0, stream>>>(hin);
    // feat = h @ fc_w^T  (bf16) -> featbf (abf region)
    gemm2<<<dim3(NP / 128, 4), 256, 0, stream>>>(
        fcb, fcb, 512, hin, hin, 512, featbf, 512, 0, nullptr, nullptr);
    el_er2<<<NN, 64, 0, stream>>>(featbf, attn_l, attn_r, el, er);
    edge_scores<<<cdiv(EE, 256), 256, 0, stream>>>(srcs_s, dsts_s, el, er, esc);

    gat3<<<NN / 4, 256, 0, stream>>>(offs, srcs_s, esc, featbf, gat_bias, rst);
    graph_mean<<<dim3(GG, 2), 256, 0, stream>>>(rst, goff, hgm);
    classify<<<GG, 64, 0, stream>>>(hgm, cw, cb, out);
}

// Round 8
// 1669.998 us; speedup vs baseline: 8.3091x; 1.0773x over previous
//
#include <hip/hip_runtime.h>
#include <math.h>

#define NN 20000
#define NP 20096           // NN padded to 128 (157 tiles)
#define EE 320000
#define GG 64
#define IN_F 256
#define NC 16
#define NSTEPS 4
#define KT 4
#define TOTKV (KT*NP)      // 80384 = 157 * 512
#define NBLK 157

typedef unsigned int uint;
typedef unsigned short ushort;
typedef __attribute__((ext_vector_type(2))) float f2;
typedef __attribute__((ext_vector_type(4))) float f4;
typedef __attribute__((ext_vector_type(4))) ushort u16x4;
typedef __attribute__((ext_vector_type(8))) ushort u16x8;
typedef __attribute__((ext_vector_type(8))) short s16x8;

#define GLD_LDS(gp, lp) __builtin_amdgcn_global_load_lds( \
    (const __attribute__((address_space(1))) void*)(gp),  \
    (__attribute__((address_space(3))) void*)(lp), 16, 0, 0)

__device__ __forceinline__ ushort f2b(float f) {
    uint u = __float_as_uint(f);
    u = (u + 0x7FFFu + ((u >> 16) & 1u)) >> 16;   // RNE f32->bf16
    return (ushort)u;
}
__device__ __forceinline__ float b2f(ushort s) { return __uint_as_float(((uint)s) << 16); }
__device__ __forceinline__ float sgm(float x) { return 1.f / (1.f + __expf(-x)); }
__device__ __forceinline__ float ftanh(float x) { return 2.f / (1.f + __expf(-2.f * x)) - 1.f; }

// ---------- weight prep ----------
__global__ void conv_msgT(const float* __restrict__ Wm, ushort* __restrict__ WT) {
    // WT[k][o][d] <- Wmsg[k][d][o]
    int idx = blockIdx.x * 256 + threadIdx.x;
    if (idx >= KT * 512 * 512) return;
    int k = idx >> 18, rem = idx & 262143;
    int o = rem >> 9, d = rem & 511;
    WT[idx] = f2b(Wm[(k << 18) + (d << 9) + o]);
}
__global__ void conv_copy(const float* __restrict__ x, ushort* __restrict__ y, int n) {
    int i = blockIdx.x * 256 + threadIdx.x;
    if (i < n) y[i] = f2b(x[i]);
}
// Wrz[o2][k2]: o2<512 -> r-gate rows, o2>=512 -> z-gate; k2<512 from w_ih, else w_hh
__global__ void build_wrz(const float* __restrict__ wih, const float* __restrict__ whh,
                          ushort* __restrict__ W) {
    int idx = blockIdx.x * 256 + threadIdx.x;
    if (idx >= 1024 * 1024) return;
    int o2 = idx >> 10, k2 = idx & 1023;
    int gate = o2 >> 9, o = o2 & 511;
    float v = (k2 < 512) ? wih[(gate * 512 + o) * 512 + k2]
                         : whh[(gate * 512 + o) * 512 + (k2 - 512)];
    W[idx] = f2b(v);
}

// ---------- CSR build (etype-major, dst-minor) ----------
__global__ void count_edges(const int* __restrict__ etype, const int* __restrict__ dst,
                            int* __restrict__ cnt) {
    int e = blockIdx.x * 256 + threadIdx.x;
    if (e >= EE) return;
    atomicAdd(&cnt[etype[e] * NP + dst[e]], 1);
}
// phase 1: per-block (512 elems) exclusive scan + block sum
__global__ __launch_bounds__(512) void scan_blk(const int* __restrict__ cnt,
                                                int* __restrict__ offs,
                                                float* __restrict__ cntf,
                                                int* __restrict__ bsum) {
    __shared__ int sh[512];
    int t = threadIdx.x, b = blockIdx.x;
    int i = b * 512 + t;
    int v = cnt[i];
    sh[t] = v; __syncthreads();
    for (int off = 1; off < 512; off <<= 1) {
        int add = (t >= off) ? sh[t - off] : 0;
        __syncthreads();
        sh[t] += add;
        __syncthreads();
    }
    offs[i] = sh[t] - v;         // local exclusive
    cntf[i] = (float)v;
    if (t == 511) bsum[b] = sh[511];
}
// phase 2: scan the 157 block sums
__global__ void scan_top(const int* __restrict__ bsum, int* __restrict__ boff,
                         int* __restrict__ offs) {
    if (threadIdx.x == 0) {
        int run = 0;
        for (int i = 0; i < NBLK; i++) { boff[i] = run; run += bsum[i]; }
        offs[TOTKV] = run;
    }
}
// phase 3: add block offsets
__global__ __launch_bounds__(512) void scan_add(int* __restrict__ offs,
                                                const int* __restrict__ boff) {
    int i = blockIdx.x * 512 + threadIdx.x;
    offs[i] += boff[blockIdx.x];
}
__global__ void fill_edges(const int* __restrict__ etype, const int* __restrict__ dst,
                           const int* __restrict__ src, int* __restrict__ cursor,
                           int* __restrict__ srcs_s, int* __restrict__ dsts_s) {
    int e = blockIdx.x * 256 + threadIdx.x;
    if (e >= EE) return;
    int pos = atomicAdd(&cursor[etype[e] * NP + dst[e]], 1);
    srcs_s[pos] = src[e];
    dsts_s[pos] = dst[e];
}

// ---------- pad input -> bf16 h (zeros for d>=256 and rows>=NN) ----------
__global__ void pad2(const float* __restrict__ in_feat, ushort* __restrict__ h) {
    int idx = blockIdx.x * 256 + threadIdx.x;   // one per 8 elems
    if (idx >= NP * 64) return;
    int n = idx >> 6, o = (idx & 63) * 8;
    u16x8 ov = {0,0,0,0,0,0,0,0};
    if (n < NN && o < IN_F) {
        f4 a = *(const f4*)(in_feat + (size_t)n * IN_F + o);
        f4 b = *(const f4*)(in_feat + (size_t)n * IN_F + o + 4);
        ov = (u16x8){ f2b(a[0]), f2b(a[1]), f2b(a[2]), f2b(a[3]),
                      f2b(b[0]), f2b(b[1]), f2b(b[2]), f2b(b[3]) };
    }
    *(u16x8*)(h + (size_t)n * 512 + o) = ov;
}

// ---------- gather for k-pair: S2[kl][v][:] = sum of hbf[src] over in-edges of etype kp*2+kl ----------
__global__ void gather2(const int* __restrict__ offs, const int* __restrict__ srcs,
                        const ushort* __restrict__ hin, ushort* __restrict__ S2, int kp) {
    int wv = threadIdx.x >> 6, lane = threadIdx.x & 63;
    int r = blockIdx.x * 4 + wv;                 // [0, 2*NP)
    int kl = (r >= NP) ? 1 : 0;
    int v = r - kl * NP;
    int k = kp * 2 + kl;
    int beg = offs[k * NP + v], end = offs[k * NP + v + 1];
    float acc[8] = {0,0,0,0,0,0,0,0};
    for (int e = beg; e < end; e++) {
        int s = srcs[e];
        u16x8 hv = *(const u16x8*)(hin + (size_t)s * 512 + lane * 8);
#pragma unroll
        for (int j = 0; j < 8; j++) acc[j] += b2f(hv[j]);
    }
    u16x8 ov;
#pragma unroll
    for (int j = 0; j < 8; j++) ov[j] = f2b(acc[j]);
    *(u16x8*)(S2 + ((size_t)kl * NP + v) * 512 + lane * 8) = ov;
}

// ---------- generic MFMA GEMM, 128x128 tile, bf16 out, global_load_lds + XOR swizzle ----------
// grid: x = output chunk (M/128), y = node tile (157)
// C[node][o] = sum_k B[node][k] * W[o][k], K split at 512 between (Wa,Ba) and (Wb,Bb).
// flags: 1 = accumulate into existing bf16 C; 2 = add sum_k cntf[k*NP+node]*bmsg[k*512+o]
__global__ __launch_bounds__(256) void gemm2(
    const ushort* __restrict__ Wa, const ushort* __restrict__ Wb, int swA,
    const ushort* __restrict__ Ba, const ushort* __restrict__ Bb, int Kt,
    ushort* __restrict__ C, int ldC, int flags,
    const float* __restrict__ cntf, const float* __restrict__ bmsg) {
    __shared__ ushort As[128 * 64];
    __shared__ ushort Bs[128 * 64];
    int t = threadIdx.x;
    int o0 = blockIdx.x * 128, n0 = blockIdx.y * 128;
    int wave = t >> 6, lane = t & 63;
    int wm = wave & 1, wn = wave >> 1;
    int l16 = lane & 15, quad = lane >> 4;
    f4 acc[4][4];
#pragma unroll
    for (int i = 0; i < 4; i++)
#pragma unroll
        for (int j = 0; j < 4; j++) acc[i][j] = (f4){0,0,0,0};
    for (int kk = 0; kk < Kt; kk += 64) {
        const ushort* Wsrc = (kk < 512) ? Wa : Wb;
        const ushort* Bsrc = (kk < 512) ? Ba : Bb;
        int ko = kk & 511;
#pragma unroll
        for (int i = 0; i < 4; i++) {
            int c = i * 256 + t;                  // LDS 16B slot id, 0..1023
            int row = c >> 3, pc = c & 7;         // physical chunk pc
            int gcol = ((pc ^ (row & 7)) << 3);   // XOR swizzle: source logical chunk
            int ldsoff = (i * 256 + wave * 64) * 8;   // wave-uniform, lane*16B added by HW
            GLD_LDS(Wsrc + (size_t)(o0 + row) * swA + ko + gcol, As + ldsoff);
            GLD_LDS(Bsrc + (size_t)(n0 + row) * 512 + ko + gcol, Bs + ldsoff);
        }
        __syncthreads();
#pragma unroll
        for (int ks = 0; ks < 64; ks += 32) {
            s16x8 af[4], bf[4];
            int j = (ks >> 3) + quad;             // logical chunk
#pragma unroll
            for (int mi = 0; mi < 4; mi++) {
                int R = wm*64 + mi*16 + l16;
                af[mi] = *(const s16x8*)&As[R * 64 + ((j ^ (R & 7)) << 3)];
            }
#pragma unroll
            for (int ni = 0; ni < 4; ni++) {
                int R = wn*64 + ni*16 + l16;
                bf[ni] = *(const s16x8*)&Bs[R * 64 + ((j ^ (R & 7)) << 3)];
            }
#pragma unroll
            for (int mi = 0; mi < 4; mi++)
#pragma unroll
                for (int ni = 0; ni < 4; ni++)
                    acc[mi][ni] = __builtin_amdgcn_mfma_f32_16x16x32_bf16(af[mi], bf[ni], acc[mi][ni], 0, 0, 0);
        }
        __syncthreads();
    }
#pragma unroll
    for (int ni = 0; ni < 4; ni++) {
        int node = n0 + wn*64 + ni*16 + l16;
#pragma unroll
        for (int mi = 0; mi < 4; mi++) {
            int o = o0 + wm*64 + mi*16 + quad*4;
            f4 v = acc[mi][ni];
            if (flags & 2) {
#pragma unroll
                for (int k = 0; k < KT; k++) {
                    float ck = cntf[k * NP + node];
                    f4 bm = *(const f4*)(bmsg + k * 512 + o);
                    v += ck * bm;
                }
            }
            ushort* cp = C + (size_t)node * ldC + o;
            if (flags & 1) {
                u16x4 old = *(const u16x4*)cp;
                v += (f4){ b2f(old[0]), b2f(old[1]), b2f(old[2]), b2f(old[3]) };
            }
            u16x4 ov = { f2b(v[0]), f2b(v[1]), f2b(v[2]), f2b(v[3]) };
            *(u16x4*)cp = ov;
        }
    }
}

// ---------- i_n GEMM with fused GRU epilogue (same swizzle/grid layout) ----------
__global__ __launch_bounds__(256) void gemm_gru(
    const ushort* __restrict__ W, const ushort* __restrict__ Bm,
    const ushort* __restrict__ rz, const ushort* __restrict__ hin,
    const float* __restrict__ b_ih, const float* __restrict__ b_hh,
    ushort* __restrict__ hnb) {
    __shared__ ushort As[128 * 64];
    __shared__ ushort Bs[128 * 64];
    int t = threadIdx.x;
    int o0 = blockIdx.x * 128, n0 = blockIdx.y * 128;
    int wave = t >> 6, lane = t & 63;
    int wm = wave & 1, wn = wave >> 1;
    int l16 = lane & 15, quad = lane >> 4;
    f4 acc[4][4];
#pragma unroll
    for (int i = 0; i < 4; i++)
#pragma unroll
        for (int j = 0; j < 4; j++) acc[i][j] = (f4){0,0,0,0};
    for (int kk = 0; kk < 512; kk += 64) {
#pragma unroll
        for (int i = 0; i < 4; i++) {
            int c = i * 256 + t;
            int row = c >> 3, pc = c & 7;
            int gcol = ((pc ^ (row & 7)) << 3);
            int ldsoff = (i * 256 + wave * 64) * 8;
            GLD_LDS(W + (size_t)(o0 + row) * 512 + kk + gcol, As + ldsoff);
            GLD_LDS(Bm + (size_t)(n0 + row) * 512 + kk + gcol, Bs + ldsoff);
        }
        __syncthreads();
#pragma unroll
        for (int ks = 0; ks < 64; ks += 32) {
            s16x8 af[4], bf[4];
            int j = (ks >> 3) + quad;
#pragma unroll
            for (int mi = 0; mi < 4; mi++) {
                int R = wm*64 + mi*16 + l16;
                af[mi] = *(const s16x8*)&As[R * 64 + ((j ^ (R & 7)) << 3)];
            }
#pragma unroll
            for (int ni = 0; ni < 4; ni++) {
                int R = wn*64 + ni*16 + l16;
                bf[ni] = *(const s16x8*)&Bs[R * 64 + ((j ^ (R & 7)) << 3)];
            }
#pragma unroll
            for (int mi = 0; mi < 4; mi++)
#pragma unroll
                for (int ni = 0; ni < 4; ni++)
                    acc[mi][ni] = __builtin_amdgcn_mfma_f32_16x16x32_bf16(af[mi], bf[ni], acc[mi][ni], 0, 0, 0);
        }
        __syncthreads();
    }
#pragma unroll
    for (int ni = 0; ni < 4; ni++) {
        int node = n0 + wn*64 + ni*16 + l16;
#pragma unroll
        for (int mi = 0; mi < 4; mi++) {
            int o = o0 + wm*64 + mi*16 + quad*4;
            u16x4 rz1 = *(const u16x4*)(rz + (size_t)node * 1024 + o);
            u16x4 rz2 = *(const u16x4*)(rz + (size_t)node * 1024 + 512 + o);
            u16x4 hnv = *(const u16x4*)(hnb + (size_t)node * 512 + o);
            u16x4 hol = *(const u16x4*)(hin + (size_t)node * 512 + o);
            f4 bi0 = *(const f4*)(b_ih + o);
            f4 bi1 = *(const f4*)(b_ih + 512 + o);
            f4 bi2 = *(const f4*)(b_ih + 1024 + o);
            f4 bh0 = *(const f4*)(b_hh + o);
            f4 bh1 = *(const f4*)(b_hh + 512 + o);
            f4 bh2 = *(const f4*)(b_hh + 1024 + o);
            u16x4 ov;
#pragma unroll
            for (int r = 0; r < 4; r++) {
                float rg = sgm(b2f(rz1[r]) + bi0[r] + bh0[r]);
                float zg = sgm(b2f(rz2[r]) + bi1[r] + bh1[r]);
                float nv = ftanh(acc[mi][ni][r] + bi2[r] + rg * (b2f(hnv[r]) + bh2[r]));
                ov[r] = f2b((1.f - zg) * nv + zg * b2f(hol[r]));
            }
            *(u16x4*)(hnb + (size_t)node * 512 + o) = ov;
        }
    }
}

// ---------- L2 normalize + sigmoid (bf16 in/out), one wave per node ----------
__global__ void norm_sig(ushort* __restrict__ h) {
    int n = blockIdx.x, lane = threadIdx.x;   // 64 threads
    u16x8 v = *(const u16x8*)(h + (size_t)n * 512 + lane * 8);
    float f[8], ss = 0.f;
#pragma unroll
    for (int j = 0; j < 8; j++) { f[j] = b2f(v[j]); ss += f[j] * f[j]; }
    for (int off = 32; off > 0; off >>= 1) ss += __shfl_xor(ss, off);
    float inv = 1.f / fmaxf(sqrtf(ss), 1e-12f);
    u16x8 ov;
#pragma unroll
    for (int j = 0; j < 8; j++) ov[j] = f2b(sgm(f[j] * inv));
    *(u16x8*)(h + (size_t)n * 512 + lane * 8) = ov;
}

// ---------- el/er from bf16 feat, one wave per node ----------
__global__ void el_er2(const ushort* __restrict__ feat, const float* __restrict__ attn_l,
                       const float* __restrict__ attn_r, float* __restrict__ el,
                       float* __restrict__ er) {
    int n = blockIdx.x, lane = threadIdx.x;   // 64
    int head = lane >> 5;
    int ld = (lane * 8) & 255;
    u16x8 v = *(const u16x8*)(feat + (size_t)n * 512 + lane * 8);
    float sl = 0.f, sr = 0.f;
#pragma unroll
    for (int j = 0; j < 8; j++) {
        float f = b2f(v[j]);
        sl += f * attn_l[head * 256 + ld + j];
        sr += f * attn_r[head * 256 + ld + j];
    }
    for (int off = 16; off > 0; off >>= 1) { sl += __shfl_xor(sl, off); sr += __shfl_xor(sr, off); }
    if ((lane & 31) == 0) { el[n * 2 + head] = sl; er[n * 2 + head] = sr; }
}

// ---------- per-CSR-slot edge scores (leaky relu), both heads ----------
__global__ void edge_scores(const int* __restrict__ srcs, const int* __restrict__ dsts,
                            const float* __restrict__ el, const float* __restrict__ er,
                            float* __restrict__ esc) {
    int e = blockIdx.x * 256 + threadIdx.x;
    if (e >= EE) return;
    int s = srcs[e], d = dsts[e];
    f2 elv = *(const f2*)(el + (size_t)s * 2);
    f2 erv = *(const f2*)(er + (size_t)d * 2);
    float s0 = elv[0] + erv[0]; s0 = s0 < 0.f ? 0.2f * s0 : s0;
    float s1 = elv[1] + erv[1]; s1 = s1 < 0.f ? 0.2f * s1 : s1;
    *(f2*)(esc + (size_t)e * 2) = (f2){ s0, s1 };
}

// ---------- fused GAT: softmax over in-edges + aggregation + bias/relu, rst f32 out (no atomics) ----------
__global__ void gat3(const int* __restrict__ offs, const int* __restrict__ srcs,
                     const float* __restrict__ esc, const ushort* __restrict__ feat,
                     const float* __restrict__ gat_bias, float* __restrict__ rst) {
    int wave = threadIdx.x >> 6, lane = threadIdx.x & 63;
    int v = blockIdx.x * 4 + wave;
    int beg[KT], end[KT];
#pragma unroll
    for (int k = 0; k < KT; k++) { beg[k] = offs[k * NP + v]; end[k] = offs[k * NP + v + 1]; }
    float m0 = -1e30f, m1 = -1e30f;
#pragma unroll
    for (int k = 0; k < KT; k++)
        for (int base = beg[k]; base < end[k]; base += 64) {
            int e = base + lane;
            if (e < end[k]) {
                f2 s = *(const f2*)(esc + (size_t)e * 2);
                m0 = fmaxf(m0, s[0]); m1 = fmaxf(m1, s[1]);
            }
        }
    for (int off = 32; off > 0; off >>= 1) {
        m0 = fmaxf(m0, __shfl_xor(m0, off));
        m1 = fmaxf(m1, __shfl_xor(m1, off));
    }
    float d0 = 0.f, d1 = 0.f;
#pragma unroll
    for (int k = 0; k < KT; k++)
        for (int base = beg[k]; base < end[k]; base += 64) {
            int e = base + lane;
            if (e < end[k]) {
                f2 s = *(const f2*)(esc + (size_t)e * 2);
                d0 += __expf(s[0] - m0); d1 += __expf(s[1] - m1);
            }
        }
    for (int off = 32; off > 0; off >>= 1) { d0 += __shfl_xor(d0, off); d1 += __shfl_xor(d1, off); }
    int head = lane >> 5;
    float mm = head ? m1 : m0;
    float iv = head ? (d1 > 0.f ? 1.f / d1 : 0.f) : (d0 > 0.f ? 1.f / d0 : 0.f);
    float acc[8] = {0,0,0,0,0,0,0,0};
#pragma unroll
    for (int k = 0; k < KT; k++)
        for (int e = beg[k]; e < end[k]; e++) {
            float sc = esc[(size_t)e * 2 + head];
            float al = __expf(sc - mm) * iv;
            u16x8 fv = *(const u16x8*)(feat + (size_t)srcs[e] * 512 + lane * 8);
#pragma unroll
            for (int j = 0; j < 8; j++) acc[j] += al * b2f(fv[j]);
        }
    int di = lane * 8;
    f4 o0, o1;
#pragma unroll
    for (int j = 0; j < 4; j++) {
        o0[j] = fmaxf(acc[j] + gat_bias[di + j], 0.f);
        o1[j] = fmaxf(acc[4 + j] + gat_bias[di + 4 + j], 0.f);
    }
    *(f4*)(rst + (size_t)v * 512 + di) = o0;
    *(f4*)(rst + (size_t)v * 512 + di + 4) = o1;
}

// ---------- graph boundaries via binary search on sorted graph_ids ----------
__global__ void graph_bounds(const int* __restrict__ gids, int* __restrict__ goff) {
    int g = threadIdx.x;   // 128 threads, need 0..64
    if (g > GG) return;
    int lo = 0, hi = NN;
    while (lo < hi) { int mid = (lo + hi) >> 1; if (gids[mid] < g) lo = mid + 1; else hi = mid; }
    goff[g] = lo;
}

// ---------- per-graph mean of rst -> hgm ----------
__global__ void graph_mean(const float* __restrict__ rst, const int* __restrict__ goff,
                           float* __restrict__ hgm) {
    int g = blockIdx.x;
    int c = blockIdx.y * 256 + threadIdx.x;
    int beg = goff[g], end = goff[g + 1];
    float s = 0.f;
    for (int n = beg; n < end; n++) s += rst[(size_t)n * 512 + c];
    float inv = (end > beg) ? 1.f / (float)(end - beg) : 0.f;
    hgm[g * 512 + c] = s * inv;
}

// ---------- classify ----------
__global__ void classify(const float* __restrict__ hgm, const float* __restrict__ cw,
                         const float* __restrict__ cb, float* __restrict__ out) {
    __shared__ float hl[512];
    int g = blockIdx.x, t = threadIdx.x;  // 64 threads
    for (int d = t; d < 512; d += 64) hl[d] = hgm[g * 512 + d];
    __syncthreads();
    if (t < 32) {
        int hd = t >> 4, c = t & 15;
        float acc = 0.f;
        for (int d = 0; d < 256; d++) acc += hl[hd * 256 + d] * cw[c * 256 + d];
        out[(g * 2 + hd) * NC + c] = acc + cb[c];
    }
}

static inline int cdiv(int a, int b) { return (a + b - 1) / b; }
static inline size_t alup(size_t x) { return (x + 255) & ~(size_t)255; }

extern "C" void kernel_launch(void* const* d_in, const int* in_sizes, int n_in,
                              void* d_out, int out_size, void* d_ws, size_t ws_size,
                              hipStream_t stream) {
    const float* in_feat   = (const float*)d_in[0];
    const int*   src       = (const int*)d_in[1];
    const int*   dst       = (const int*)d_in[2];
    const int*   etype     = (const int*)d_in[3];
    const int*   graph_ids = (const int*)d_in[4];
    const float* Wmsg      = (const float*)d_in[5];
    const float* bmsg      = (const float*)d_in[6];
    const float* w_ih      = (const float*)d_in[7];
    const float* w_hh      = (const float*)d_in[8];
    const float* b_ih      = (const float*)d_in[9];
    const float* b_hh      = (const float*)d_in[10];
    const float* fc_w      = (const float*)d_in[11];
    const float* attn_l    = (const float*)d_in[12];
    const float* attn_r    = (const float*)d_in[13];
    const float* gat_bias  = (const float*)d_in[14];
    const float* cw        = (const float*)d_in[15];
    const float* cb        = (const float*)d_in[16];
    float* out = (float*)d_out;

    char* p = (char*)d_ws;
    ushort* hbfA  = (ushort*)p; p += alup((size_t)NP * 512 * 2);
    ushort* hbfB  = (ushort*)p; p += alup((size_t)NP * 512 * 2);
    ushort* abf   = (ushort*)p; p += alup((size_t)NP * 512 * 2);
    ushort* S2    = (ushort*)p; p += alup((size_t)2 * NP * 512 * 2);  // gathered S pair / rz (NP x 1024) / rst f32
    ushort* wmsgT = (ushort*)p; p += alup((size_t)KT * 512 * 512 * 2);
    ushort* wihb  = (ushort*)p; p += alup((size_t)1536 * 512 * 2);
    ushort* whhb  = (ushort*)p; p += alup((size_t)1536 * 512 * 2);
    ushort* wrz   = (ushort*)p; p += alup((size_t)1024 * 1024 * 2);
    ushort* fcb   = (ushort*)p; p += alup((size_t)512 * 512 * 2);
    int*    cnt   = (int*)p;    p += alup((size_t)TOTKV * 4);
    int*    offs  = (int*)p;    p += alup(((size_t)TOTKV + 1) * 4);
    int*    cursor= (int*)p;    p += alup(((size_t)TOTKV + 1) * 4);
    float*  cntf  = (float*)p;  p += alup((size_t)TOTKV * 4);
    int*    bsum  = (int*)p;    p += alup((size_t)NBLK * 4);
    int*    boff  = (int*)p;    p += alup((size_t)NBLK * 4);
    int*    srcs_s= (int*)p;    p += alup((size_t)EE * 4);
    int*    dsts_s= (int*)p;    p += alup((size_t)EE * 4);
    float*  esc   = (float*)p;  p += alup((size_t)EE * 2 * 4);
    float*  el    = (float*)p;  p += alup((size_t)NN * 2 * 4);
    float*  er    = (float*)p;  p += alup((size_t)NN * 2 * 4);
    int*    goff  = (int*)p;    p += alup((size_t)(GG + 1) * 4);
    float*  hgm   = (float*)p;  p += alup((size_t)GG * 512 * 4);
    ushort* featbf = abf;          // alias: abf free after last gemm_gru
    float*  rst    = (float*)S2;   // alias: rz region free after last gemm_gru (same byte size)

    // ---- weight prep ----
    conv_msgT<<<cdiv(KT * 512 * 512, 256), 256, 0, stream>>>(Wmsg, wmsgT);
    conv_copy<<<cdiv(1536 * 512, 256), 256, 0, stream>>>(w_ih, wihb, 1536 * 512);
    conv_copy<<<cdiv(1536 * 512, 256), 256, 0, stream>>>(w_hh, whhb, 1536 * 512);
    build_wrz<<<cdiv(1024 * 1024, 256), 256, 0, stream>>>(w_ih, w_hh, wrz);
    conv_copy<<<cdiv(512 * 512, 256), 256, 0, stream>>>(fc_w, fcb, 512 * 512);

    // ---- CSR build ----
    hipMemsetAsync(cnt, 0, (size_t)TOTKV * 4, stream);
    count_edges<<<cdiv(EE, 256), 256, 0, stream>>>(etype, dst, cnt);
    scan_blk<<<NBLK, 512, 0, stream>>>(cnt, offs, cntf, bsum);
    scan_top<<<1, 64, 0, stream>>>(bsum, boff, offs);
    scan_add<<<NBLK, 512, 0, stream>>>(offs, boff);
    hipMemcpyAsync(cursor, offs, (size_t)TOTKV * 4, hipMemcpyDeviceToDevice, stream);
    fill_edges<<<cdiv(EE, 256), 256, 0, stream>>>(etype, dst, src, cursor, srcs_s, dsts_s);
    graph_bounds<<<1, 128, 0, stream>>>(graph_ids, goff);

    pad2<<<cdiv(NP * 64, 256), 256, 0, stream>>>(in_feat, hbfA);

    const ushort* win = wihb + (size_t)1024 * 512;   // n-gate rows of w_ih
    const ushort* whn = whhb + (size_t)1024 * 512;   // n-gate rows of w_hh

    ushort* hin = hbfA;
    ushort* hout = hbfB;
    for (int step = 0; step < NSTEPS; step++) {
        // message passing: abf = sum_k S_k @ Wmsg_k^T + sum_k cnt_k*bmsg_k   (bf16)
        gather2<<<2 * NP / 4, 256, 0, stream>>>(offs, srcs_s, hin, S2, 0);
        gemm2<<<dim3(4, NP / 128), 256, 0, stream>>>(
            wmsgT, wmsgT + (size_t)1 * 262144, 512, S2, S2 + (size_t)NP * 512, 1024,
            abf, 512, 0, nullptr, nullptr);
        gather2<<<2 * NP / 4, 256, 0, stream>>>(offs, srcs_s, hin, S2, 1);
        gemm2<<<dim3(4, NP / 128), 256, 0, stream>>>(
            wmsgT + (size_t)2 * 262144, wmsgT + (size_t)3 * 262144, 512, S2, S2 + (size_t)NP * 512, 1024,
            abf, 512, 3, cntf, bmsg);
        // GRU: rz = [abf|hin] @ Wrz^T  (K=1024, M=1024) -> S2 region
        gemm2<<<dim3(8, NP / 128), 256, 0, stream>>>(
            wrz, wrz + 512, 1024, abf, hin, 1024, S2, 1024, 0, nullptr, nullptr);
        // h_n = hin @ whn^T -> hout region (pre-bias)
        gemm2<<<dim3(4, NP / 128), 256, 0, stream>>>(
            whn, whn, 512, hin, hin, 512, hout, 512, 0, nullptr, nullptr);
        // i_n GEMM + fused GRU epilogue -> hout = h_new
        gemm_gru<<<dim3(4, NP / 128), 256, 0, stream>>>(
            win, abf, S2, hin, b_ih, b_hh, hout);
        ushort* tmp = hin; hin = hout; hout = tmp;
    }
    // hin now holds final h (hbfA after 4 steps)

    norm_sig<<<NN, 64, 0, stream>>>(hin);
    // feat = h @ fc_w^T  (bf16) -> featbf (abf region)
    gemm2<<<dim3(4, NP / 128), 256, 0, stream>>>(
        fcb, fcb, 512, hin, hin, 512, featbf, 512, 0, nullptr, nullptr);
    el_er2<<<NN, 64, 0, stream>>>(featbf, attn_l, attn_r, el, er);
    edge_scores<<<cdiv(EE, 256), 256, 0, stream>>>(srcs_s, dsts_s, el, er, esc);

    gat3<<<NN / 4, 256, 0, stream>>>(offs, srcs_s, esc, featbf, gat_bias, rst);
    graph_mean<<<dim3(GG, 2), 256, 0, stream>>>(rst, goff, hgm);
    classify<<<GG, 64, 0, stream>>>(hgm, cw, cb, out);
}

// Round 9
// 1500.313 us; speedup vs baseline: 9.2489x; 1.1131x over previous
//
#include <hip/hip_runtime.h>
#include <math.h>

#define NN 20000
#define NP 20096           // NN padded to 128 (157 tiles)
#define EE 320000
#define GG 64
#define IN_F 256
#define NC 16
#define NSTEPS 4
#define KT 4
#define TOTKV (KT*NP)      // 80384 = 157 * 512
#define NBLK 157

typedef unsigned int uint;
typedef unsigned short ushort;
typedef __attribute__((ext_vector_type(2))) float f2;
typedef __attribute__((ext_vector_type(4))) float f4;
typedef __attribute__((ext_vector_type(4))) ushort u16x4;
typedef __attribute__((ext_vector_type(8))) ushort u16x8;
typedef __attribute__((ext_vector_type(8))) short s16x8;

#define GLD_LDS(gp, lp) __builtin_amdgcn_global_load_lds( \
    (const __attribute__((address_space(1))) void*)(gp),  \
    (__attribute__((address_space(3))) void*)(lp), 16, 0, 0)

__device__ __forceinline__ ushort f2b(float f) {
    uint u = __float_as_uint(f);
    u = (u + 0x7FFFu + ((u >> 16) & 1u)) >> 16;   // RNE f32->bf16
    return (ushort)u;
}
__device__ __forceinline__ float b2f(ushort s) { return __uint_as_float(((uint)s) << 16); }
__device__ __forceinline__ float sgm(float x) { return 1.f / (1.f + __expf(-x)); }
__device__ __forceinline__ float ftanh(float x) { return 2.f / (1.f + __expf(-2.f * x)) - 1.f; }

// ---------- weight prep ----------
// WT[k][o][d] <- Wmsg[k][d][o], LDS-tiled 32x32 so both sides coalesce
__global__ void conv_msgT(const float* __restrict__ Wm, ushort* __restrict__ WT) {
    __shared__ ushort sh[32][33];
    int k = blockIdx.z;
    int d0 = blockIdx.x * 32, o0 = blockIdx.y * 32;
    int tx = threadIdx.x & 31, ty = threadIdx.x >> 5;   // ty 0..7
#pragma unroll
    for (int i = 0; i < 4; i++) {
        int d = d0 + ty + i * 8;
        sh[ty + i * 8][tx] = f2b(Wm[((size_t)k << 18) + (size_t)d * 512 + o0 + tx]);
    }
    __syncthreads();
#pragma unroll
    for (int i = 0; i < 4; i++) {
        int o = o0 + ty + i * 8;
        WT[((size_t)k << 18) + (size_t)o * 512 + d0 + tx] = sh[tx][ty + i * 8];
    }
}
__global__ void conv_copy(const float* __restrict__ x, ushort* __restrict__ y, int n) {
    int i = blockIdx.x * 256 + threadIdx.x;
    if (i < n) y[i] = f2b(x[i]);
}
// Wrz[o2][k2]: o2<512 -> r-gate rows, o2>=512 -> z-gate; k2<512 from w_ih, else w_hh
__global__ void build_wrz(const float* __restrict__ wih, const float* __restrict__ whh,
                          ushort* __restrict__ W) {
    int idx = blockIdx.x * 256 + threadIdx.x;
    if (idx >= 1024 * 1024) return;
    int o2 = idx >> 10, k2 = idx & 1023;
    int gate = o2 >> 9, o = o2 & 511;
    float v = (k2 < 512) ? wih[(gate * 512 + o) * 512 + k2]
                         : whh[(gate * 512 + o) * 512 + (k2 - 512)];
    W[idx] = f2b(v);
}

// ---------- CSR build (etype-major, dst-minor) ----------
__global__ void count_edges(const int* __restrict__ etype, const int* __restrict__ dst,
                            int* __restrict__ cnt) {
    int e = blockIdx.x * 256 + threadIdx.x;
    if (e >= EE) return;
    atomicAdd(&cnt[etype[e] * NP + dst[e]], 1);
}
__global__ __launch_bounds__(512) void scan_blk(const int* __restrict__ cnt,
                                                int* __restrict__ offs,
                                                float* __restrict__ cntf,
                                                int* __restrict__ bsum) {
    __shared__ int sh[512];
    int t = threadIdx.x, b = blockIdx.x;
    int i = b * 512 + t;
    int v = cnt[i];
    sh[t] = v; __syncthreads();
    for (int off = 1; off < 512; off <<= 1) {
        int add = (t >= off) ? sh[t - off] : 0;
        __syncthreads();
        sh[t] += add;
        __syncthreads();
    }
    offs[i] = sh[t] - v;         // local exclusive
    cntf[i] = (float)v;
    if (t == 511) bsum[b] = sh[511];
}
__global__ void scan_top(const int* __restrict__ bsum, int* __restrict__ boff,
                         int* __restrict__ offs) {
    if (threadIdx.x == 0) {
        int run = 0;
        for (int i = 0; i < NBLK; i++) { boff[i] = run; run += bsum[i]; }
        offs[TOTKV] = run;
    }
}
__global__ __launch_bounds__(512) void scan_add(int* __restrict__ offs,
                                                const int* __restrict__ boff) {
    int i = blockIdx.x * 512 + threadIdx.x;
    offs[i] += boff[blockIdx.x];
}
__global__ void fill_edges(const int* __restrict__ etype, const int* __restrict__ dst,
                           const int* __restrict__ src, int* __restrict__ cursor,
                           int* __restrict__ srcs_s, int* __restrict__ dsts_s) {
    int e = blockIdx.x * 256 + threadIdx.x;
    if (e >= EE) return;
    int pos = atomicAdd(&cursor[etype[e] * NP + dst[e]], 1);
    srcs_s[pos] = src[e];
    dsts_s[pos] = dst[e];
}

// ---------- pad input -> bf16 h (zeros for d>=256 and rows>=NN) ----------
__global__ void pad2(const float* __restrict__ in_feat, ushort* __restrict__ h) {
    int idx = blockIdx.x * 256 + threadIdx.x;   // one per 8 elems
    if (idx >= NP * 64) return;
    int n = idx >> 6, o = (idx & 63) * 8;
    u16x8 ov = {0,0,0,0,0,0,0,0};
    if (n < NN && o < IN_F) {
        f4 a = *(const f4*)(in_feat + (size_t)n * IN_F + o);
        f4 b = *(const f4*)(in_feat + (size_t)n * IN_F + o + 4);
        ov = (u16x8){ f2b(a[0]), f2b(a[1]), f2b(a[2]), f2b(a[3]),
                      f2b(b[0]), f2b(b[1]), f2b(b[2]), f2b(b[3]) };
    }
    *(u16x8*)(h + (size_t)n * 512 + o) = ov;
}

// ---------- gather for k-pair: S2[kl][v][:] = sum of hbf[src] over in-edges of etype kp*2+kl ----------
__global__ void gather2(const int* __restrict__ offs, const int* __restrict__ srcs,
                        const ushort* __restrict__ hin, ushort* __restrict__ S2, int kp) {
    int wv = threadIdx.x >> 6, lane = threadIdx.x & 63;
    int r = blockIdx.x * 4 + wv;                 // [0, 2*NP)
    int kl = (r >= NP) ? 1 : 0;
    int v = r - kl * NP;
    int k = kp * 2 + kl;
    int beg = offs[k * NP + v], end = offs[k * NP + v + 1];
    float acc[8] = {0,0,0,0,0,0,0,0};
    for (int e = beg; e < end; e++) {
        int s = srcs[e];
        u16x8 hv = *(const u16x8*)(hin + (size_t)s * 512 + lane * 8);
#pragma unroll
        for (int j = 0; j < 8; j++) acc[j] += b2f(hv[j]);
    }
    u16x8 ov;
#pragma unroll
    for (int j = 0; j < 8; j++) ov[j] = f2b(acc[j]);
    *(u16x8*)(S2 + ((size_t)kl * NP + v) * 512 + lane * 8) = ov;
}

// ---------- shared MFMA GEMM body: 128x128 tile, global_load_lds + XOR swizzle ----------
// C[node][o] = sum_k B[node][k] * W[o][k], K split at KtA between (Wa,Ba) and (Wb,Bb).
// B matrices stride 512. flags: 1 = accumulate bf16 C; 2 = add sum_k cntf*bmsg
__device__ __forceinline__ void gemm_body(
    ushort* As, ushort* Bs,
    const ushort* __restrict__ Wa, const ushort* __restrict__ Wb, int swA,
    const ushort* __restrict__ Ba, const ushort* __restrict__ Bb,
    int KtA, int Kt, ushort* __restrict__ C, int ldC, int o0, int n0, int flags,
    const float* __restrict__ cntf, const float* __restrict__ bmsg) {
    int t = threadIdx.x;
    int wave = t >> 6, lane = t & 63;
    int wm = wave & 1, wn = wave >> 1;
    int l16 = lane & 15, quad = lane >> 4;
    f4 acc[4][4];
#pragma unroll
    for (int i = 0; i < 4; i++)
#pragma unroll
        for (int j = 0; j < 4; j++) acc[i][j] = (f4){0,0,0,0};
    for (int kk = 0; kk < Kt; kk += 64) {
        const ushort* Wsrc = (kk < KtA) ? Wa : Wb;
        const ushort* Bsrc = (kk < KtA) ? Ba : Bb;
        int ko = (kk < KtA) ? kk : kk - KtA;
#pragma unroll
        for (int i = 0; i < 4; i++) {
            int c = i * 256 + t;                  // LDS 16B slot id, 0..1023
            int row = c >> 3, pc = c & 7;         // physical chunk pc
            int gcol = ((pc ^ (row & 7)) << 3);   // XOR swizzle: source logical chunk
            int ldsoff = (i * 256 + wave * 64) * 8;   // wave-uniform, lane*16B added by HW
            GLD_LDS(Wsrc + (size_t)(o0 + row) * swA + ko + gcol, As + ldsoff);
            GLD_LDS(Bsrc + (size_t)(n0 + row) * 512 + ko + gcol, Bs + ldsoff);
        }
        __syncthreads();
#pragma unroll
        for (int ks = 0; ks < 64; ks += 32) {
            s16x8 af[4], bf[4];
            int j = (ks >> 3) + quad;             // logical chunk
#pragma unroll
            for (int mi = 0; mi < 4; mi++) {
                int R = wm*64 + mi*16 + l16;
                af[mi] = *(const s16x8*)&As[R * 64 + ((j ^ (R & 7)) << 3)];
            }
#pragma unroll
            for (int ni = 0; ni < 4; ni++) {
                int R = wn*64 + ni*16 + l16;
                bf[ni] = *(const s16x8*)&Bs[R * 64 + ((j ^ (R & 7)) << 3)];
            }
#pragma unroll
            for (int mi = 0; mi < 4; mi++)
#pragma unroll
                for (int ni = 0; ni < 4; ni++)
                    acc[mi][ni] = __builtin_amdgcn_mfma_f32_16x16x32_bf16(af[mi], bf[ni], acc[mi][ni], 0, 0, 0);
        }
        __syncthreads();
    }
#pragma unroll
    for (int ni = 0; ni < 4; ni++) {
        int node = n0 + wn*64 + ni*16 + l16;
#pragma unroll
        for (int mi = 0; mi < 4; mi++) {
            int o = o0 + wm*64 + mi*16 + quad*4;
            f4 v = acc[mi][ni];
            if (flags & 2) {
#pragma unroll
                for (int k = 0; k < KT; k++) {
                    float ck = cntf[k * NP + node];
                    f4 bm = *(const f4*)(bmsg + k * 512 + o);
                    v += ck * bm;
                }
            }
            ushort* cp = C + (size_t)node * ldC + o;
            if (flags & 1) {
                u16x4 old = *(const u16x4*)cp;
                v += (f4){ b2f(old[0]), b2f(old[1]), b2f(old[2]), b2f(old[3]) };
            }
            u16x4 ov = { f2b(v[0]), f2b(v[1]), f2b(v[2]), f2b(v[3]) };
            *(u16x4*)cp = ov;
        }
    }
}

// grid: x = output chunk, y = node tile
__global__ __launch_bounds__(256) void gemm2(
    const ushort* Wa, const ushort* Wb, int swA,
    const ushort* Ba, const ushort* Bb, int KtA, int Kt,
    ushort* C, int ldC, int flags,
    const float* cntf, const float* bmsg) {
    __shared__ ushort As[128 * 64];
    __shared__ ushort Bs[128 * 64];
    gemm_body(As, Bs, Wa, Wb, swA, Ba, Bb, KtA, Kt, C, ldC,
              blockIdx.x * 128, blockIdx.y * 128, flags, cntf, bmsg);
}

// merged rz + hn dispatch: x<8 -> rz (M=1024), x>=8 -> hn (M=512)
__global__ __launch_bounds__(256) void gemm_rzhn(
    const ushort* wrz, const ushort* whn,
    const ushort* abf, const ushort* hin,
    ushort* rzout, ushort* hnout, int ktRZ, int ktHN) {
    __shared__ ushort As[128 * 64];
    __shared__ ushort Bs[128 * 64];
    if (blockIdx.x < 8) {
        gemm_body(As, Bs, wrz, wrz + 512, 1024, abf, hin, 512, ktRZ,
                  rzout, 1024, blockIdx.x * 128, blockIdx.y * 128, 0, nullptr, nullptr);
    } else {
        gemm_body(As, Bs, whn, whn, 512, hin, hin, 512, ktHN,
                  hnout, 512, (blockIdx.x - 8) * 128, blockIdx.y * 128, 0, nullptr, nullptr);
    }
}

// ---------- i_n GEMM with fused GRU epilogue ----------
__global__ __launch_bounds__(256) void gemm_gru(
    const ushort* __restrict__ W, const ushort* __restrict__ Bm,
    const ushort* __restrict__ rz, const ushort* __restrict__ hin,
    const float* __restrict__ b_ih, const float* __restrict__ b_hh,
    ushort* __restrict__ hnb) {
    __shared__ ushort As[128 * 64];
    __shared__ ushort Bs[128 * 64];
    int t = threadIdx.x;
    int o0 = blockIdx.x * 128, n0 = blockIdx.y * 128;
    int wave = t >> 6, lane = t & 63;
    int wm = wave & 1, wn = wave >> 1;
    int l16 = lane & 15, quad = lane >> 4;
    f4 acc[4][4];
#pragma unroll
    for (int i = 0; i < 4; i++)
#pragma unroll
        for (int j = 0; j < 4; j++) acc[i][j] = (f4){0,0,0,0};
    for (int kk = 0; kk < 512; kk += 64) {
#pragma unroll
        for (int i = 0; i < 4; i++) {
            int c = i * 256 + t;
            int row = c >> 3, pc = c & 7;
            int gcol = ((pc ^ (row & 7)) << 3);
            int ldsoff = (i * 256 + wave * 64) * 8;
            GLD_LDS(W + (size_t)(o0 + row) * 512 + kk + gcol, As + ldsoff);
            GLD_LDS(Bm + (size_t)(n0 + row) * 512 + kk + gcol, Bs + ldsoff);
        }
        __syncthreads();
#pragma unroll
        for (int ks = 0; ks < 64; ks += 32) {
            s16x8 af[4], bf[4];
            int j = (ks >> 3) + quad;
#pragma unroll
            for (int mi = 0; mi < 4; mi++) {
                int R = wm*64 + mi*16 + l16;
                af[mi] = *(const s16x8*)&As[R * 64 + ((j ^ (R & 7)) << 3)];
            }
#pragma unroll
            for (int ni = 0; ni < 4; ni++) {
                int R = wn*64 + ni*16 + l16;
                bf[ni] = *(const s16x8*)&Bs[R * 64 + ((j ^ (R & 7)) << 3)];
            }
#pragma unroll
            for (int mi = 0; mi < 4; mi++)
#pragma unroll
                for (int ni = 0; ni < 4; ni++)
                    acc[mi][ni] = __builtin_amdgcn_mfma_f32_16x16x32_bf16(af[mi], bf[ni], acc[mi][ni], 0, 0, 0);
        }
        __syncthreads();
    }
#pragma unroll
    for (int ni = 0; ni < 4; ni++) {
        int node = n0 + wn*64 + ni*16 + l16;
#pragma unroll
        for (int mi = 0; mi < 4; mi++) {
            int o = o0 + wm*64 + mi*16 + quad*4;
            u16x4 rz1 = *(const u16x4*)(rz + (size_t)node * 1024 + o);
            u16x4 rz2 = *(const u16x4*)(rz + (size_t)node * 1024 + 512 + o);
            u16x4 hnv = *(const u16x4*)(hnb + (size_t)node * 512 + o);
            u16x4 hol = *(const u16x4*)(hin + (size_t)node * 512 + o);
            f4 bi0 = *(const f4*)(b_ih + o);
            f4 bi1 = *(const f4*)(b_ih + 512 + o);
            f4 bi2 = *(const f4*)(b_ih + 1024 + o);
            f4 bh0 = *(const f4*)(b_hh + o);
            f4 bh1 = *(const f4*)(b_hh + 512 + o);
            f4 bh2 = *(const f4*)(b_hh + 1024 + o);
            u16x4 ov;
#pragma unroll
            for (int r = 0; r < 4; r++) {
                float rg = sgm(b2f(rz1[r]) + bi0[r] + bh0[r]);
                float zg = sgm(b2f(rz2[r]) + bi1[r] + bh1[r]);
                float nv = ftanh(acc[mi][ni][r] + bi2[r] + rg * (b2f(hnv[r]) + bh2[r]));
                ov[r] = f2b((1.f - zg) * nv + zg * b2f(hol[r]));
            }
            *(u16x4*)(hnb + (size_t)node * 512 + o) = ov;
        }
    }
}

// ---------- L2 normalize + sigmoid (bf16 in/out), one wave per node ----------
__global__ void norm_sig(ushort* __restrict__ h) {
    int n = blockIdx.x, lane = threadIdx.x;   // 64 threads
    u16x8 v = *(const u16x8*)(h + (size_t)n * 512 + lane * 8);
    float f[8], ss = 0.f;
#pragma unroll
    for (int j = 0; j < 8; j++) { f[j] = b2f(v[j]); ss += f[j] * f[j]; }
    for (int off = 32; off > 0; off >>= 1) ss += __shfl_xor(ss, off);
    float inv = 1.f / fmaxf(sqrtf(ss), 1e-12f);
    u16x8 ov;
#pragma unroll
    for (int j = 0; j < 8; j++) ov[j] = f2b(sgm(f[j] * inv));
    *(u16x8*)(h + (size_t)n * 512 + lane * 8) = ov;
}

// ---------- el/er from bf16 feat, one wave per node ----------
__global__ void el_er2(const ushort* __restrict__ feat, const float* __restrict__ attn_l,
                       const float* __restrict__ attn_r, float* __restrict__ el,
                       float* __restrict__ er) {
    int n = blockIdx.x, lane = threadIdx.x;   // 64
    int head = lane >> 5;
    int ld = (lane * 8) & 255;
    u16x8 v = *(const u16x8*)(feat + (size_t)n * 512 + lane * 8);
    float sl = 0.f, sr = 0.f;
#pragma unroll
    for (int j = 0; j < 8; j++) {
        float f = b2f(v[j]);
        sl += f * attn_l[head * 256 + ld + j];
        sr += f * attn_r[head * 256 + ld + j];
    }
    for (int off = 16; off > 0; off >>= 1) { sl += __shfl_xor(sl, off); sr += __shfl_xor(sr, off); }
    if ((lane & 31) == 0) { el[n * 2 + head] = sl; er[n * 2 + head] = sr; }
}

// ---------- per-CSR-slot edge scores (leaky relu), both heads ----------
__global__ void edge_scores(const int* __restrict__ srcs, const int* __restrict__ dsts,
                            const float* __restrict__ el, const float* __restrict__ er,
                            float* __restrict__ esc) {
    int e = blockIdx.x * 256 + threadIdx.x;
    if (e >= EE) return;
    int s = srcs[e], d = dsts[e];
    f2 elv = *(const f2*)(el + (size_t)s * 2);
    f2 erv = *(const f2*)(er + (size_t)d * 2);
    float s0 = elv[0] + erv[0]; s0 = s0 < 0.f ? 0.2f * s0 : s0;
    float s1 = elv[1] + erv[1]; s1 = s1 < 0.f ? 0.2f * s1 : s1;
    *(f2*)(esc + (size_t)e * 2) = (f2){ s0, s1 };
}

// ---------- fused GAT: softmax over in-edges + aggregation + bias/relu, rst f32 out (no atomics) ----------
__global__ void gat3(const int* __restrict__ offs, const int* __restrict__ srcs,
                     const float* __restrict__ esc, const ushort* __restrict__ feat,
                     const float* __restrict__ gat_bias, float* __restrict__ rst) {
    int wave = threadIdx.x >> 6, lane = threadIdx.x & 63;
    int v = blockIdx.x * 4 + wave;
    int beg[KT], end[KT];
#pragma unroll
    for (int k = 0; k < KT; k++) { beg[k] = offs[k * NP + v]; end[k] = offs[k * NP + v + 1]; }
    float m0 = -1e30f, m1 = -1e30f;
#pragma unroll
    for (int k = 0; k < KT; k++)
        for (int base = beg[k]; base < end[k]; base += 64) {
            int e = base + lane;
            if (e < end[k]) {
                f2 s = *(const f2*)(esc + (size_t)e * 2);
                m0 = fmaxf(m0, s[0]); m1 = fmaxf(m1, s[1]);
            }
        }
    for (int off = 32; off > 0; off >>= 1) {
        m0 = fmaxf(m0, __shfl_xor(m0, off));
        m1 = fmaxf(m1, __shfl_xor(m1, off));
    }
    float d0 = 0.f, d1 = 0.f;
#pragma unroll
    for (int k = 0; k < KT; k++)
        for (int base = beg[k]; base < end[k]; base += 64) {
            int e = base + lane;
            if (e < end[k]) {
                f2 s = *(const f2*)(esc + (size_t)e * 2);
                d0 += __expf(s[0] - m0); d1 += __expf(s[1] - m1);
            }
        }
    for (int off = 32; off > 0; off >>= 1) { d0 += __shfl_xor(d0, off); d1 += __shfl_xor(d1, off); }
    int head = lane >> 5;
    float mm = head ? m1 : m0;
    float iv = head ? (d1 > 0.f ? 1.f / d1 : 0.f) : (d0 > 0.f ? 1.f / d0 : 0.f);
    float acc[8] = {0,0,0,0,0,0,0,0};
#pragma unroll
    for (int k = 0; k < KT; k++)
        for (int e = beg[k]; e < end[k]; e++) {
            float sc = esc[(size_t)e * 2 + head];
            float al = __expf(sc - mm) * iv;
            u16x8 fv = *(const u16x8*)(feat + (size_t)srcs[e] * 512 + lane * 8);
#pragma unroll
            for (int j = 0; j < 8; j++) acc[j] += al * b2f(fv[j]);
        }
    int di = lane * 8;
    f4 o0, o1;
#pragma unroll
    for (int j = 0; j < 4; j++) {
        o0[j] = fmaxf(acc[j] + gat_bias[di + j], 0.f);
        o1[j] = fmaxf(acc[4 + j] + gat_bias[di + 4 + j], 0.f);
    }
    *(f4*)(rst + (size_t)v * 512 + di) = o0;
    *(f4*)(rst + (size_t)v * 512 + di + 4) = o1;
}

// ---------- graph boundaries via binary search on sorted graph_ids ----------
__global__ void graph_bounds(const int* __restrict__ gids, int* __restrict__ goff) {
    int g = threadIdx.x;   // 128 threads, need 0..64
    if (g > GG) return;
    int lo = 0, hi = NN;
    while (lo < hi) { int mid = (lo + hi) >> 1; if (gids[mid] < g) lo = mid + 1; else hi = mid; }
    goff[g] = lo;
}

// ---------- per-graph partial sums of rst -> hgm (atomic, 8 chunks/graph) ----------
__global__ void graph_mean2(const float* __restrict__ rst, const int* __restrict__ goff,
                            float* __restrict__ hgm) {
    int g = blockIdx.x, yc = blockIdx.y, t = threadIdx.x;
    int beg = goff[g], end = goff[g + 1];
    float s0 = 0.f, s1 = 0.f;
    for (int n = beg + yc; n < end; n += 8) {
        s0 += rst[(size_t)n * 512 + t];
        s1 += rst[(size_t)n * 512 + 256 + t];
    }
    atomicAdd(&hgm[g * 512 + t], s0);
    atomicAdd(&hgm[g * 512 + 256 + t], s1);
}

// ---------- classify (divides by graph size) ----------
__global__ void classify(const float* __restrict__ hgm, const int* __restrict__ goff,
                         const float* __restrict__ cw, const float* __restrict__ cb,
                         float* __restrict__ out) {
    __shared__ float hl[512];
    int g = blockIdx.x, t = threadIdx.x;  // 64 threads
    int cntn = goff[g + 1] - goff[g];
    float inv = (cntn > 0) ? 1.f / (float)cntn : 0.f;
    for (int d = t; d < 512; d += 64) hl[d] = hgm[g * 512 + d] * inv;
    __syncthreads();
    if (t < 32) {
        int hd = t >> 4, c = t & 15;
        float acc = 0.f;
        for (int d = 0; d < 256; d++) acc += hl[hd * 256 + d] * cw[c * 256 + d];
        out[(g * 2 + hd) * NC + c] = acc + cb[c];
    }
}

static inline int cdiv(int a, int b) { return (a + b - 1) / b; }
static inline size_t alup(size_t x) { return (x + 255) & ~(size_t)255; }

extern "C" void kernel_launch(void* const* d_in, const int* in_sizes, int n_in,
                              void* d_out, int out_size, void* d_ws, size_t ws_size,
                              hipStream_t stream) {
    const float* in_feat   = (const float*)d_in[0];
    const int*   src       = (const int*)d_in[1];
    const int*   dst       = (const int*)d_in[2];
    const int*   etype     = (const int*)d_in[3];
    const int*   graph_ids = (const int*)d_in[4];
    const float* Wmsg      = (const float*)d_in[5];
    const float* bmsg      = (const float*)d_in[6];
    const float* w_ih      = (const float*)d_in[7];
    const float* w_hh      = (const float*)d_in[8];
    const float* b_ih      = (const float*)d_in[9];
    const float* b_hh      = (const float*)d_in[10];
    const float* fc_w      = (const float*)d_in[11];
    const float* attn_l    = (const float*)d_in[12];
    const float* attn_r    = (const float*)d_in[13];
    const float* gat_bias  = (const float*)d_in[14];
    const float* cw        = (const float*)d_in[15];
    const float* cb        = (const float*)d_in[16];
    float* out = (float*)d_out;

    char* p = (char*)d_ws;
    ushort* hbfA  = (ushort*)p; p += alup((size_t)NP * 512 * 2);
    ushort* hbfB  = (ushort*)p; p += alup((size_t)NP * 512 * 2);
    ushort* abf   = (ushort*)p; p += alup((size_t)NP * 512 * 2);
    ushort* S2    = (ushort*)p; p += alup((size_t)2 * NP * 512 * 2);  // gathered S pair / rz (NP x 1024) / rst f32
    ushort* wmsgT = (ushort*)p; p += alup((size_t)KT * 512 * 512 * 2);
    ushort* wihb  = (ushort*)p; p += alup((size_t)1536 * 512 * 2);
    ushort* whhb  = (ushort*)p; p += alup((size_t)1536 * 512 * 2);
    ushort* wrz   = (ushort*)p; p += alup((size_t)1024 * 1024 * 2);
    ushort* fcb   = (ushort*)p; p += alup((size_t)512 * 512 * 2);
    int*    cnt   = (int*)p;    p += alup((size_t)TOTKV * 4);
    int*    offs  = (int*)p;    p += alup(((size_t)TOTKV + 1) * 4);
    int*    cursor= (int*)p;    p += alup(((size_t)TOTKV + 1) * 4);
    float*  cntf  = (float*)p;  p += alup((size_t)TOTKV * 4);
    int*    bsum  = (int*)p;    p += alup((size_t)NBLK * 4);
    int*    boff  = (int*)p;    p += alup((size_t)NBLK * 4);
    int*    srcs_s= (int*)p;    p += alup((size_t)EE * 4);
    int*    dsts_s= (int*)p;    p += alup((size_t)EE * 4);
    float*  esc   = (float*)p;  p += alup((size_t)EE * 2 * 4);
    float*  el    = (float*)p;  p += alup((size_t)NN * 2 * 4);
    float*  er    = (float*)p;  p += alup((size_t)NN * 2 * 4);
    int*    goff  = (int*)p;    p += alup((size_t)(GG + 1) * 4);
    float*  hgm   = (float*)p;  p += alup((size_t)GG * 512 * 4);
    ushort* featbf = abf;          // alias: abf free after last gemm_gru
    float*  rst    = (float*)S2;   // alias: rz region free after last gemm_gru (same byte size)

    // ---- weight prep ----
    conv_msgT<<<dim3(16, 16, 4), 256, 0, stream>>>(Wmsg, wmsgT);
    conv_copy<<<cdiv(1536 * 512, 256), 256, 0, stream>>>(w_ih, wihb, 1536 * 512);
    conv_copy<<<cdiv(1536 * 512, 256), 256, 0, stream>>>(w_hh, whhb, 1536 * 512);
    build_wrz<<<cdiv(1024 * 1024, 256), 256, 0, stream>>>(w_ih, w_hh, wrz);
    conv_copy<<<cdiv(512 * 512, 256), 256, 0, stream>>>(fc_w, fcb, 512 * 512);

    // ---- CSR build ----
    hipMemsetAsync(cnt, 0, (size_t)TOTKV * 4, stream);
    count_edges<<<cdiv(EE, 256), 256, 0, stream>>>(etype, dst, cnt);
    scan_blk<<<NBLK, 512, 0, stream>>>(cnt, offs, cntf, bsum);
    scan_top<<<1, 64, 0, stream>>>(bsum, boff, offs);
    scan_add<<<NBLK, 512, 0, stream>>>(offs, boff);
    hipMemcpyAsync(cursor, offs, (size_t)TOTKV * 4, hipMemcpyDeviceToDevice, stream);
    fill_edges<<<cdiv(EE, 256), 256, 0, stream>>>(etype, dst, src, cursor, srcs_s, dsts_s);
    graph_bounds<<<1, 128, 0, stream>>>(graph_ids, goff);

    pad2<<<cdiv(NP * 64, 256), 256, 0, stream>>>(in_feat, hbfA);

    const ushort* win = wihb + (size_t)1024 * 512;   // n-gate rows of w_ih
    const ushort* whn = whhb + (size_t)1024 * 512;   // n-gate rows of w_hh

    ushort* hin = hbfA;
    ushort* hout = hbfB;
    for (int step = 0; step < NSTEPS; step++) {
        // step 0: h cols 256..511 are zero -> trim K on every GEMM touching h
        int ktMsgA = (step == 0) ? 256 : 512;     // per-segment K for msg gemms
        int ktMsg  = 2 * ktMsgA;
        int ktRZ   = (step == 0) ? 768 : 1024;    // abf(512) + h(256|512)
        int ktHN   = (step == 0) ? 256 : 512;
        // message passing: abf = sum_k S_k @ Wmsg_k^T + sum_k cnt_k*bmsg_k   (bf16)
        gather2<<<2 * NP / 4, 256, 0, stream>>>(offs, srcs_s, hin, S2, 0);
        gemm2<<<dim3(4, NP / 128), 256, 0, stream>>>(
            wmsgT, wmsgT + (size_t)1 * 262144, 512, S2, S2 + (size_t)NP * 512, ktMsgA, ktMsg,
            abf, 512, 0, nullptr, nullptr);
        gather2<<<2 * NP / 4, 256, 0, stream>>>(offs, srcs_s, hin, S2, 1);
        gemm2<<<dim3(4, NP / 128), 256, 0, stream>>>(
            wmsgT + (size_t)2 * 262144, wmsgT + (size_t)3 * 262144, 512, S2, S2 + (size_t)NP * 512, ktMsgA, ktMsg,
            abf, 512, 3, cntf, bmsg);
        // merged: rz = [abf|hin] @ Wrz^T -> S2 ; h_n = hin @ whn^T -> hout
        gemm_rzhn<<<dim3(12, NP / 128), 256, 0, stream>>>(
            wrz, whn, abf, hin, S2, hout, ktRZ, ktHN);
        // i_n GEMM + fused GRU epilogue -> hout = h_new
        gemm_gru<<<dim3(4, NP / 128), 256, 0, stream>>>(
            win, abf, S2, hin, b_ih, b_hh, hout);
        ushort* tmp = hin; hin = hout; hout = tmp;
    }
    // hin now holds final h (hbfA after 4 steps)

    norm_sig<<<NN, 64, 0, stream>>>(hin);
    // feat = h @ fc_w^T  (bf16) -> featbf (abf region)
    gemm2<<<dim3(4, NP / 128), 256, 0, stream>>>(
        fcb, fcb, 512, hin, hin, 512, 512, featbf, 512, 0, nullptr, nullptr);
    el_er2<<<NN, 64, 0, stream>>>(featbf, attn_l, attn_r, el, er);
    edge_scores<<<cdiv(EE, 256), 256, 0, stream>>>(srcs_s, dsts_s, el, er, esc);

    gat3<<<NN / 4, 256, 0, stream>>>(offs, srcs_s, esc, featbf, gat_bias, rst);
    hipMemsetAsync(hgm, 0, (size_t)GG * 512 * 4, stream);
    graph_mean2<<<dim3(GG, 8), 256, 0, stream>>>(rst, goff, hgm);
    classify<<<GG, 64, 0, stream>>>(hgm, goff, cw, cb, out);
}

// Round 10
// 1209.155 us; speedup vs baseline: 11.4760x; 1.2408x over previous
//
#include <hip/hip_runtime.h>
#include <math.h>

#define NN 20000
#define NP 20096           // NN padded to 128 (157 tiles)
#define EE 320000
#define GG 64
#define IN_F 256
#define NC 16
#define NSTEPS 4
#define KT 4
#define TOTKV (KT*NP)      // 80384 = 157 * 512
#define NBLK 157

typedef unsigned int uint;
typedef unsigned short ushort;
typedef __attribute__((ext_vector_type(2))) float f2;
typedef __attribute__((ext_vector_type(4))) float f4;
typedef __attribute__((ext_vector_type(4))) ushort u16x4;
typedef __attribute__((ext_vector_type(8))) ushort u16x8;
typedef __attribute__((ext_vector_type(8))) short s16x8;

#define GLD_LDS(gp, lp) __builtin_amdgcn_global_load_lds( \
    (const __attribute__((address_space(1))) void*)(gp),  \
    (__attribute__((address_space(3))) void*)(lp), 16, 0, 0)

__device__ __forceinline__ ushort f2b(float f) {
    uint u = __float_as_uint(f);
    u = (u + 0x7FFFu + ((u >> 16) & 1u)) >> 16;   // RNE f32->bf16
    return (ushort)u;
}
__device__ __forceinline__ float b2f(ushort s) { return __uint_as_float(((uint)s) << 16); }
__device__ __forceinline__ float sgm(float x) { return 1.f / (1.f + __expf(-x)); }
__device__ __forceinline__ float ftanh(float x) { return 2.f / (1.f + __expf(-2.f * x)) - 1.f; }

// XCD-aware work swizzle: all GX work-columns of a node-tile y land on one XCD
// (assumes flat-id % 8 round-robin). y rows >=152 (tail of 157) map linearly.
__device__ __forceinline__ void sw_xy(int GX, int& x, int& y) {
    int f = blockIdx.x + GX * blockIdx.y;
    int body = GX * 152;                 // 19 groups of 8 y-rows
    if (f < body) {
        int xcd = f & 7, j = f >> 3;
        x = j % GX;
        y = (j / GX) * 8 + xcd;
    } else {
        int r = f - body;
        x = r % GX;
        y = 152 + r / GX;
    }
}

// ---------- weight prep ----------
// WT[k][o][d] <- Wmsg[k][d][o], LDS-tiled 32x32 so both sides coalesce
__global__ void conv_msgT(const float* __restrict__ Wm, ushort* __restrict__ WT) {
    __shared__ ushort sh[32][33];
    int k = blockIdx.z;
    int d0 = blockIdx.x * 32, o0 = blockIdx.y * 32;
    int tx = threadIdx.x & 31, ty = threadIdx.x >> 5;   // ty 0..7
#pragma unroll
    for (int i = 0; i < 4; i++) {
        int d = d0 + ty + i * 8;
        sh[ty + i * 8][tx] = f2b(Wm[((size_t)k << 18) + (size_t)d * 512 + o0 + tx]);
    }
    __syncthreads();
#pragma unroll
    for (int i = 0; i < 4; i++) {
        int o = o0 + ty + i * 8;
        WT[((size_t)k << 18) + (size_t)o * 512 + d0 + tx] = sh[tx][ty + i * 8];
    }
}
__global__ void conv_copy(const float* __restrict__ x, ushort* __restrict__ y, int n) {
    int i = blockIdx.x * 256 + threadIdx.x;
    if (i < n) y[i] = f2b(x[i]);
}
// Wrz[o2][k2]: o2<512 -> r-gate rows, o2>=512 -> z-gate; k2<512 from w_ih, else w_hh
__global__ void build_wrz(const float* __restrict__ wih, const float* __restrict__ whh,
                          ushort* __restrict__ W) {
    int idx = blockIdx.x * 256 + threadIdx.x;
    if (idx >= 1024 * 1024) return;
    int o2 = idx >> 10, k2 = idx & 1023;
    int gate = o2 >> 9, o = o2 & 511;
    float v = (k2 < 512) ? wih[(gate * 512 + o) * 512 + k2]
                         : whh[(gate * 512 + o) * 512 + (k2 - 512)];
    W[idx] = f2b(v);
}

// ---------- CSR build (etype-major, dst-minor) ----------
__global__ void count_edges(const int* __restrict__ etype, const int* __restrict__ dst,
                            int* __restrict__ cnt) {
    int e = blockIdx.x * 256 + threadIdx.x;
    if (e >= EE) return;
    atomicAdd(&cnt[etype[e] * NP + dst[e]], 1);
}
__global__ __launch_bounds__(512) void scan_blk(const int* __restrict__ cnt,
                                                int* __restrict__ offs,
                                                float* __restrict__ cntf,
                                                int* __restrict__ bsum) {
    __shared__ int sh[512];
    int t = threadIdx.x, b = blockIdx.x;
    int i = b * 512 + t;
    int v = cnt[i];
    sh[t] = v; __syncthreads();
    for (int off = 1; off < 512; off <<= 1) {
        int add = (t >= off) ? sh[t - off] : 0;
        __syncthreads();
        sh[t] += add;
        __syncthreads();
    }
    offs[i] = sh[t] - v;         // local exclusive
    cntf[i] = (float)v;
    if (t == 511) bsum[b] = sh[511];
}
__global__ void scan_top(const int* __restrict__ bsum, int* __restrict__ boff,
                         int* __restrict__ offs) {
    if (threadIdx.x == 0) {
        int run = 0;
        for (int i = 0; i < NBLK; i++) { boff[i] = run; run += bsum[i]; }
        offs[TOTKV] = run;
    }
}
__global__ __launch_bounds__(512) void scan_add(int* __restrict__ offs,
                                                const int* __restrict__ boff) {
    int i = blockIdx.x * 512 + threadIdx.x;
    offs[i] += boff[blockIdx.x];
}
__global__ void fill_edges(const int* __restrict__ etype, const int* __restrict__ dst,
                           const int* __restrict__ src, int* __restrict__ cursor,
                           int* __restrict__ srcs_s, int* __restrict__ dsts_s) {
    int e = blockIdx.x * 256 + threadIdx.x;
    if (e >= EE) return;
    int pos = atomicAdd(&cursor[etype[e] * NP + dst[e]], 1);
    srcs_s[pos] = src[e];
    dsts_s[pos] = dst[e];
}

// ---------- pad input -> bf16 h (zeros for d>=256 and rows>=NN) ----------
__global__ void pad2(const float* __restrict__ in_feat, ushort* __restrict__ h) {
    int idx = blockIdx.x * 256 + threadIdx.x;   // one per 8 elems
    if (idx >= NP * 64) return;
    int n = idx >> 6, o = (idx & 63) * 8;
    u16x8 ov = {0,0,0,0,0,0,0,0};
    if (n < NN && o < IN_F) {
        f4 a = *(const f4*)(in_feat + (size_t)n * IN_F + o);
        f4 b = *(const f4*)(in_feat + (size_t)n * IN_F + o + 4);
        ov = (u16x8){ f2b(a[0]), f2b(a[1]), f2b(a[2]), f2b(a[3]),
                      f2b(b[0]), f2b(b[1]), f2b(b[2]), f2b(b[3]) };
    }
    *(u16x8*)(h + (size_t)n * 512 + o) = ov;
}

// ---------- gather for k-pair: S2[kl][v][:] = sum of hbf[src] over in-edges of etype kp*2+kl ----------
__global__ void gather2(const int* __restrict__ offs, const int* __restrict__ srcs,
                        const ushort* __restrict__ hin, ushort* __restrict__ S2, int kp) {
    int wv = threadIdx.x >> 6, lane = threadIdx.x & 63;
    int r = blockIdx.x * 4 + wv;                 // [0, 2*NP)
    int kl = (r >= NP) ? 1 : 0;
    int v = r - kl * NP;
    int k = kp * 2 + kl;
    int beg = offs[k * NP + v], end = offs[k * NP + v + 1];
    float acc[8] = {0,0,0,0,0,0,0,0};
    for (int e = beg; e < end; e++) {
        int s = srcs[e];
        u16x8 hv = *(const u16x8*)(hin + (size_t)s * 512 + lane * 8);
#pragma unroll
        for (int j = 0; j < 8; j++) acc[j] += b2f(hv[j]);
    }
    u16x8 ov;
#pragma unroll
    for (int j = 0; j < 8; j++) ov[j] = f2b(acc[j]);
    *(u16x8*)(S2 + ((size_t)kl * NP + v) * 512 + lane * 8) = ov;
}

// ---------- shared MFMA GEMM body: 128x128 tile, global_load_lds + XOR swizzle ----------
// C[node][o] = sum_k B[node][k] * W[o][k], K split at KtA between (Wa,Ba) and (Wb,Bb).
// B matrices stride 512. flags: 1 = accumulate bf16 C; 2 = add sum_k cntf*bmsg
__device__ __forceinline__ void gemm_body(
    ushort* As, ushort* Bs,
    const ushort* __restrict__ Wa, const ushort* __restrict__ Wb, int swA,
    const ushort* __restrict__ Ba, const ushort* __restrict__ Bb,
    int KtA, int Kt, ushort* __restrict__ C, int ldC, int o0, int n0, int flags,
    const float* __restrict__ cntf, const float* __restrict__ bmsg) {
    int t = threadIdx.x;
    int wave = t >> 6, lane = t & 63;
    int wm = wave & 1, wn = wave >> 1;
    int l16 = lane & 15, quad = lane >> 4;
    f4 acc[4][4];
#pragma unroll
    for (int i = 0; i < 4; i++)
#pragma unroll
        for (int j = 0; j < 4; j++) acc[i][j] = (f4){0,0,0,0};
    for (int kk = 0; kk < Kt; kk += 64) {
        const ushort* Wsrc = (kk < KtA) ? Wa : Wb;
        const ushort* Bsrc = (kk < KtA) ? Ba : Bb;
        int ko = (kk < KtA) ? kk : kk - KtA;
#pragma unroll
        for (int i = 0; i < 4; i++) {
            int c = i * 256 + t;                  // LDS 16B slot id, 0..1023
            int row = c >> 3, pc = c & 7;         // physical chunk pc
            int gcol = ((pc ^ (row & 7)) << 3);   // XOR swizzle: source logical chunk
            int ldsoff = (i * 256 + wave * 64) * 8;   // wave-uniform, lane*16B added by HW
            GLD_LDS(Wsrc + (size_t)(o0 + row) * swA + ko + gcol, As + ldsoff);
            GLD_LDS(Bsrc + (size_t)(n0 + row) * 512 + ko + gcol, Bs + ldsoff);
        }
        __syncthreads();
#pragma unroll
        for (int ks = 0; ks < 64; ks += 32) {
            s16x8 af[4], bf[4];
            int j = (ks >> 3) + quad;             // logical chunk
#pragma unroll
            for (int mi = 0; mi < 4; mi++) {
                int R = wm*64 + mi*16 + l16;
                af[mi] = *(const s16x8*)&As[R * 64 + ((j ^ (R & 7)) << 3)];
            }
#pragma unroll
            for (int ni = 0; ni < 4; ni++) {
                int R = wn*64 + ni*16 + l16;
                bf[ni] = *(const s16x8*)&Bs[R * 64 + ((j ^ (R & 7)) << 3)];
            }
#pragma unroll
            for (int mi = 0; mi < 4; mi++)
#pragma unroll
                for (int ni = 0; ni < 4; ni++)
                    acc[mi][ni] = __builtin_amdgcn_mfma_f32_16x16x32_bf16(af[mi], bf[ni], acc[mi][ni], 0, 0, 0);
        }
        __syncthreads();
    }
#pragma unroll
    for (int ni = 0; ni < 4; ni++) {
        int node = n0 + wn*64 + ni*16 + l16;
#pragma unroll
        for (int mi = 0; mi < 4; mi++) {
            int o = o0 + wm*64 + mi*16 + quad*4;
            f4 v = acc[mi][ni];
            if (flags & 2) {
#pragma unroll
                for (int k = 0; k < KT; k++) {
                    float ck = cntf[k * NP + node];
                    f4 bm = *(const f4*)(bmsg + k * 512 + o);
                    v += ck * bm;
                }
            }
            ushort* cp = C + (size_t)node * ldC + o;
            if (flags & 1) {
                u16x4 old = *(const u16x4*)cp;
                v += (f4){ b2f(old[0]), b2f(old[1]), b2f(old[2]), b2f(old[3]) };
            }
            u16x4 ov = { f2b(v[0]), f2b(v[1]), f2b(v[2]), f2b(v[3]) };
            *(u16x4*)cp = ov;
        }
    }
}

// grid: x = output chunk, y = node tile (XCD-swizzled)
__global__ __launch_bounds__(256, 3) void gemm2(
    const ushort* Wa, const ushort* Wb, int swA,
    const ushort* Ba, const ushort* Bb, int KtA, int Kt,
    ushort* C, int ldC, int flags,
    const float* cntf, const float* bmsg) {
    __shared__ ushort As[128 * 64];
    __shared__ ushort Bs[128 * 64];
    int x, y; sw_xy(gridDim.x, x, y);
    gemm_body(As, Bs, Wa, Wb, swA, Ba, Bb, KtA, Kt, C, ldC,
              x * 128, y * 128, flags, cntf, bmsg);
}

// merged rz + hn dispatch: x<8 -> rz (M=1024), x>=8 -> hn (M=512)
__global__ __launch_bounds__(256, 3) void gemm_rzhn(
    const ushort* wrz, const ushort* whn,
    const ushort* abf, const ushort* hin,
    ushort* rzout, ushort* hnout, int ktRZ, int ktHN) {
    __shared__ ushort As[128 * 64];
    __shared__ ushort Bs[128 * 64];
    int x, y; sw_xy(gridDim.x, x, y);
    if (x < 8) {
        gemm_body(As, Bs, wrz, wrz + 512, 1024, abf, hin, 512, ktRZ,
                  rzout, 1024, x * 128, y * 128, 0, nullptr, nullptr);
    } else {
        gemm_body(As, Bs, whn, whn, 512, hin, hin, 512, ktHN,
                  hnout, 512, (x - 8) * 128, y * 128, 0, nullptr, nullptr);
    }
}

// ---------- i_n GEMM with fused GRU epilogue ----------
__global__ __launch_bounds__(256, 3) void gemm_gru(
    const ushort* __restrict__ W, const ushort* __restrict__ Bm,
    const ushort* __restrict__ rz, const ushort* __restrict__ hin,
    const float* __restrict__ b_ih, const float* __restrict__ b_hh,
    ushort* __restrict__ hnb) {
    __shared__ ushort As[128 * 64];
    __shared__ ushort Bs[128 * 64];
    int t = threadIdx.x;
    int x, y; sw_xy(gridDim.x, x, y);
    int o0 = x * 128, n0 = y * 128;
    int wave = t >> 6, lane = t & 63;
    int wm = wave & 1, wn = wave >> 1;
    int l16 = lane & 15, quad = lane >> 4;
    f4 acc[4][4];
#pragma unroll
    for (int i = 0; i < 4; i++)
#pragma unroll
        for (int j = 0; j < 4; j++) acc[i][j] = (f4){0,0,0,0};
    for (int kk = 0; kk < 512; kk += 64) {
#pragma unroll
        for (int i = 0; i < 4; i++) {
            int c = i * 256 + t;
            int row = c >> 3, pc = c & 7;
            int gcol = ((pc ^ (row & 7)) << 3);
            int ldsoff = (i * 256 + wave * 64) * 8;
            GLD_LDS(W + (size_t)(o0 + row) * 512 + kk + gcol, As + ldsoff);
            GLD_LDS(Bm + (size_t)(n0 + row) * 512 + kk + gcol, Bs + ldsoff);
        }
        __syncthreads();
#pragma unroll
        for (int ks = 0; ks < 64; ks += 32) {
            s16x8 af[4], bf[4];
            int j = (ks >> 3) + quad;
#pragma unroll
            for (int mi = 0; mi < 4; mi++) {
                int R = wm*64 + mi*16 + l16;
                af[mi] = *(const s16x8*)&As[R * 64 + ((j ^ (R & 7)) << 3)];
            }
#pragma unroll
            for (int ni = 0; ni < 4; ni++) {
                int R = wn*64 + ni*16 + l16;
                bf[ni] = *(const s16x8*)&Bs[R * 64 + ((j ^ (R & 7)) << 3)];
            }
#pragma unroll
            for (int mi = 0; mi < 4; mi++)
#pragma unroll
                for (int ni = 0; ni < 4; ni++)
                    acc[mi][ni] = __builtin_amdgcn_mfma_f32_16x16x32_bf16(af[mi], bf[ni], acc[mi][ni], 0, 0, 0);
        }
        __syncthreads();
    }
#pragma unroll
    for (int ni = 0; ni < 4; ni++) {
        int node = n0 + wn*64 + ni*16 + l16;
#pragma unroll
        for (int mi = 0; mi < 4; mi++) {
            int o = o0 + wm*64 + mi*16 + quad*4;
            u16x4 rz1 = *(const u16x4*)(rz + (size_t)node * 1024 + o);
            u16x4 rz2 = *(const u16x4*)(rz + (size_t)node * 1024 + 512 + o);
            u16x4 hnv = *(const u16x4*)(hnb + (size_t)node * 512 + o);
            u16x4 hol = *(const u16x4*)(hin + (size_t)node * 512 + o);
            f4 bi0 = *(const f4*)(b_ih + o);
            f4 bi1 = *(const f4*)(b_ih + 512 + o);
            f4 bi2 = *(const f4*)(b_ih + 1024 + o);
            f4 bh0 = *(const f4*)(b_hh + o);
            f4 bh1 = *(const f4*)(b_hh + 512 + o);
            f4 bh2 = *(const f4*)(b_hh + 1024 + o);
            u16x4 ov;
#pragma unroll
            for (int r = 0; r < 4; r++) {
                float rg = sgm(b2f(rz1[r]) + bi0[r] + bh0[r]);
                float zg = sgm(b2f(rz2[r]) + bi1[r] + bh1[r]);
                float nv = ftanh(acc[mi][ni][r] + bi2[r] + rg * (b2f(hnv[r]) + bh2[r]));
                ov[r] = f2b((1.f - zg) * nv + zg * b2f(hol[r]));
            }
            *(u16x4*)(hnb + (size_t)node * 512 + o) = ov;
        }
    }
}

// ---------- L2 normalize + sigmoid (bf16 in/out), one wave per node ----------
__global__ void norm_sig(ushort* __restrict__ h) {
    int n = blockIdx.x, lane = threadIdx.x;   // 64 threads
    u16x8 v = *(const u16x8*)(h + (size_t)n * 512 + lane * 8);
    float f[8], ss = 0.f;
#pragma unroll
    for (int j = 0; j < 8; j++) { f[j] = b2f(v[j]); ss += f[j] * f[j]; }
    for (int off = 32; off > 0; off >>= 1) ss += __shfl_xor(ss, off);
    float inv = 1.f / fmaxf(sqrtf(ss), 1e-12f);
    u16x8 ov;
#pragma unroll
    for (int j = 0; j < 8; j++) ov[j] = f2b(sgm(f[j] * inv));
    *(u16x8*)(h + (size_t)n * 512 + lane * 8) = ov;
}

// ---------- el/er from bf16 feat, one wave per node ----------
__global__ void el_er2(const ushort* __restrict__ feat, const float* __restrict__ attn_l,
                       const float* __restrict__ attn_r, float* __restrict__ el,
                       float* __restrict__ er) {
    int n = blockIdx.x, lane = threadIdx.x;   // 64
    int head = lane >> 5;
    int ld = (lane * 8) & 255;
    u16x8 v = *(const u16x8*)(feat + (size_t)n * 512 + lane * 8);
    float sl = 0.f, sr = 0.f;
#pragma unroll
    for (int j = 0; j < 8; j++) {
        float f = b2f(v[j]);
        sl += f * attn_l[head * 256 + ld + j];
        sr += f * attn_r[head * 256 + ld + j];
    }
    for (int off = 16; off > 0; off >>= 1) { sl += __shfl_xor(sl, off); sr += __shfl_xor(sr, off); }
    if ((lane & 31) == 0) { el[n * 2 + head] = sl; er[n * 2 + head] = sr; }
}

// ---------- per-CSR-slot edge scores (leaky relu), both heads ----------
__global__ void edge_scores(const int* __restrict__ srcs, const int* __restrict__ dsts,
                            const float* __restrict__ el, const float* __restrict__ er,
                            float* __restrict__ esc) {
    int e = blockIdx.x * 256 + threadIdx.x;
    if (e >= EE) return;
    int s = srcs[e], d = dsts[e];
    f2 elv = *(const f2*)(el + (size_t)s * 2);
    f2 erv = *(const f2*)(er + (size_t)d * 2);
    float s0 = elv[0] + erv[0]; s0 = s0 < 0.f ? 0.2f * s0 : s0;
    float s1 = elv[1] + erv[1]; s1 = s1 < 0.f ? 0.2f * s1 : s1;
    *(f2*)(esc + (size_t)e * 2) = (f2){ s0, s1 };
}

// ---------- fused GAT: softmax over in-edges + aggregation + bias/relu, rst f32 out (no atomics) ----------
__global__ void gat3(const int* __restrict__ offs, const int* __restrict__ srcs,
                     const float* __restrict__ esc, const ushort* __restrict__ feat,
                     const float* __restrict__ gat_bias, float* __restrict__ rst) {
    int wave = threadIdx.x >> 6, lane = threadIdx.x & 63;
    int v = blockIdx.x * 4 + wave;
    int beg[KT], end[KT];
#pragma unroll
    for (int k = 0; k < KT; k++) { beg[k] = offs[k * NP + v]; end[k] = offs[k * NP + v + 1]; }
    float m0 = -1e30f, m1 = -1e30f;
#pragma unroll
    for (int k = 0; k < KT; k++)
        for (int base = beg[k]; base < end[k]; base += 64) {
            int e = base + lane;
            if (e < end[k]) {
                f2 s = *(const f2*)(esc + (size_t)e * 2);
                m0 = fmaxf(m0, s[0]); m1 = fmaxf(m1, s[1]);
            }
        }
    for (int off = 32; off > 0; off >>= 1) {
        m0 = fmaxf(m0, __shfl_xor(m0, off));
        m1 = fmaxf(m1, __shfl_xor(m1, off));
    }
    float d0 = 0.f, d1 = 0.f;
#pragma unroll
    for (int k = 0; k < KT; k++)
        for (int base = beg[k]; base < end[k]; base += 64) {
            int e = base + lane;
            if (e < end[k]) {
                f2 s = *(const f2*)(esc + (size_t)e * 2);
                d0 += __expf(s[0] - m0); d1 += __expf(s[1] - m1);
            }
        }
    for (int off = 32; off > 0; off >>= 1) { d0 += __shfl_xor(d0, off); d1 += __shfl_xor(d1, off); }
    int head = lane >> 5;
    float mm = head ? m1 : m0;
    float iv = head ? (d1 > 0.f ? 1.f / d1 : 0.f) : (d0 > 0.f ? 1.f / d0 : 0.f);
    float acc[8] = {0,0,0,0,0,0,0,0};
#pragma unroll
    for (int k = 0; k < KT; k++)
        for (int e = beg[k]; e < end[k]; e++) {
            float sc = esc[(size_t)e * 2 + head];
            float al = __expf(sc - mm) * iv;
            u16x8 fv = *(const u16x8*)(feat + (size_t)srcs[e] * 512 + lane * 8);
#pragma unroll
            for (int j = 0; j < 8; j++) acc[j] += al * b2f(fv[j]);
        }
    int di = lane * 8;
    f4 o0, o1;
#pragma unroll
    for (int j = 0; j < 4; j++) {
        o0[j] = fmaxf(acc[j] + gat_bias[di + j], 0.f);
        o1[j] = fmaxf(acc[4 + j] + gat_bias[di + 4 + j], 0.f);
    }
    *(f4*)(rst + (size_t)v * 512 + di) = o0;
    *(f4*)(rst + (size_t)v * 512 + di + 4) = o1;
}

// ---------- graph boundaries via binary search on sorted graph_ids ----------
__global__ void graph_bounds(const int* __restrict__ gids, int* __restrict__ goff) {
    int g = threadIdx.x;   // 128 threads, need 0..64
    if (g > GG) return;
    int lo = 0, hi = NN;
    while (lo < hi) { int mid = (lo + hi) >> 1; if (gids[mid] < g) lo = mid + 1; else hi = mid; }
    goff[g] = lo;
}

// ---------- per-graph partial sums of rst -> hgm (atomic, 8 chunks/graph) ----------
__global__ void graph_mean2(const float* __restrict__ rst, const int* __restrict__ goff,
                            float* __restrict__ hgm) {
    int g = blockIdx.x, yc = blockIdx.y, t = threadIdx.x;
    int beg = goff[g], end = goff[g + 1];
    float s0 = 0.f, s1 = 0.f;
    for (int n = beg + yc; n < end; n += 8) {
        s0 += rst[(size_t)n * 512 + t];
        s1 += rst[(size_t)n * 512 + 256 + t];
    }
    atomicAdd(&hgm[g * 512 + t], s0);
    atomicAdd(&hgm[g * 512 + 256 + t], s1);
}

// ---------- classify (divides by graph size) ----------
__global__ void classify(const float* __restrict__ hgm, const int* __restrict__ goff,
                         const float* __restrict__ cw, const float* __restrict__ cb,
                         float* __restrict__ out) {
    __shared__ float hl[512];
    int g = blockIdx.x, t = threadIdx.x;  // 64 threads
    int cntn = goff[g + 1] - goff[g];
    float inv = (cntn > 0) ? 1.f / (float)cntn : 0.f;
    for (int d = t; d < 512; d += 64) hl[d] = hgm[g * 512 + d] * inv;
    __syncthreads();
    if (t < 32) {
        int hd = t >> 4, c = t & 15;
        float acc = 0.f;
        for (int d = 0; d < 256; d++) acc += hl[hd * 256 + d] * cw[c * 256 + d];
        out[(g * 2 + hd) * NC + c] = acc + cb[c];
    }
}

static inline int cdiv(int a, int b) { return (a + b - 1) / b; }
static inline size_t alup(size_t x) { return (x + 255) & ~(size_t)255; }

extern "C" void kernel_launch(void* const* d_in, const int* in_sizes, int n_in,
                              void* d_out, int out_size, void* d_ws, size_t ws_size,
                              hipStream_t stream) {
    const float* in_feat   = (const float*)d_in[0];
    const int*   src       = (const int*)d_in[1];
    const int*   dst       = (const int*)d_in[2];
    const int*   etype     = (const int*)d_in[3];
    const int*   graph_ids = (const int*)d_in[4];
    const float* Wmsg      = (const float*)d_in[5];
    const float* bmsg      = (const float*)d_in[6];
    const float* w_ih      = (const float*)d_in[7];
    const float* w_hh      = (const float*)d_in[8];
    const float* b_ih      = (const float*)d_in[9];
    const float* b_hh      = (const float*)d_in[10];
    const float* fc_w      = (const float*)d_in[11];
    const float* attn_l    = (const float*)d_in[12];
    const float* attn_r    = (const float*)d_in[13];
    const float* gat_bias  = (const float*)d_in[14];
    const float* cw        = (const float*)d_in[15];
    const float* cb        = (const float*)d_in[16];
    float* out = (float*)d_out;

    char* p = (char*)d_ws;
    ushort* hbfA  = (ushort*)p; p += alup((size_t)NP * 512 * 2);
    ushort* hbfB  = (ushort*)p; p += alup((size_t)NP * 512 * 2);
    ushort* abf   = (ushort*)p; p += alup((size_t)NP * 512 * 2);
    ushort* S2    = (ushort*)p; p += alup((size_t)2 * NP * 512 * 2);  // gathered S pair / rz (NP x 1024) / rst f32
    ushort* wmsgT = (ushort*)p; p += alup((size_t)KT * 512 * 512 * 2);
    ushort* wihb  = (ushort*)p; p += alup((size_t)1536 * 512 * 2);
    ushort* whhb  = (ushort*)p; p += alup((size_t)1536 * 512 * 2);
    ushort* wrz   = (ushort*)p; p += alup((size_t)1024 * 1024 * 2);
    ushort* fcb   = (ushort*)p; p += alup((size_t)512 * 512 * 2);
    int*    cnt   = (int*)p;    p += alup((size_t)TOTKV * 4);
    int*    offs  = (int*)p;    p += alup(((size_t)TOTKV + 1) * 4);
    int*    cursor= (int*)p;    p += alup(((size_t)TOTKV + 1) * 4);
    float*  cntf  = (float*)p;  p += alup((size_t)TOTKV * 4);
    int*    bsum  = (int*)p;    p += alup((size_t)NBLK * 4);
    int*    boff  = (int*)p;    p += alup((size_t)NBLK * 4);
    int*    srcs_s= (int*)p;    p += alup((size_t)EE * 4);
    int*    dsts_s= (int*)p;    p += alup((size_t)EE * 4);
    float*  esc   = (float*)p;  p += alup((size_t)EE * 2 * 4);
    float*  el    = (float*)p;  p += alup((size_t)NN * 2 * 4);
    float*  er    = (float*)p;  p += alup((size_t)NN * 2 * 4);
    int*    goff  = (int*)p;    p += alup((size_t)(GG + 1) * 4);
    float*  hgm   = (float*)p;  p += alup((size_t)GG * 512 * 4);
    ushort* featbf = abf;          // alias: abf free after last gemm_gru
    float*  rst    = (float*)S2;   // alias: rz region free after last gemm_gru (same byte size)

    // ---- weight prep ----
    conv_msgT<<<dim3(16, 16, 4), 256, 0, stream>>>(Wmsg, wmsgT);
    conv_copy<<<cdiv(1536 * 512, 256), 256, 0, stream>>>(w_ih, wihb, 1536 * 512);
    conv_copy<<<cdiv(1536 * 512, 256), 256, 0, stream>>>(w_hh, whhb, 1536 * 512);
    build_wrz<<<cdiv(1024 * 1024, 256), 256, 0, stream>>>(w_ih, w_hh, wrz);
    conv_copy<<<cdiv(512 * 512, 256), 256, 0, stream>>>(fc_w, fcb, 512 * 512);

    // ---- CSR build ----
    hipMemsetAsync(cnt, 0, (size_t)TOTKV * 4, stream);
    count_edges<<<cdiv(EE, 256), 256, 0, stream>>>(etype, dst, cnt);
    scan_blk<<<NBLK, 512, 0, stream>>>(cnt, offs, cntf, bsum);
    scan_top<<<1, 64, 0, stream>>>(bsum, boff, offs);
    scan_add<<<NBLK, 512, 0, stream>>>(offs, boff);
    hipMemcpyAsync(cursor, offs, (size_t)TOTKV * 4, hipMemcpyDeviceToDevice, stream);
    fill_edges<<<cdiv(EE, 256), 256, 0, stream>>>(etype, dst, src, cursor, srcs_s, dsts_s);
    graph_bounds<<<1, 128, 0, stream>>>(graph_ids, goff);

    pad2<<<cdiv(NP * 64, 256), 256, 0, stream>>>(in_feat, hbfA);

    const ushort* win = wihb + (size_t)1024 * 512;   // n-gate rows of w_ih
    const ushort* whn = whhb + (size_t)1024 * 512;   // n-gate rows of w_hh

    ushort* hin = hbfA;
    ushort* hout = hbfB;
    for (int step = 0; step < NSTEPS; step++) {
        // step 0: h cols 256..511 are zero -> trim K on every GEMM touching h
        int ktMsgA = (step == 0) ? 256 : 512;     // per-segment K for msg gemms
        int ktMsg  = 2 * ktMsgA;
        int ktRZ   = (step == 0) ? 768 : 1024;    // abf(512) + h(256|512)
        int ktHN   = (step == 0) ? 256 : 512;
        // message passing: abf = sum_k S_k @ Wmsg_k^T + sum_k cnt_k*bmsg_k   (bf16)
        gather2<<<2 * NP / 4, 256, 0, stream>>>(offs, srcs_s, hin, S2, 0);
        gemm2<<<dim3(4, NP / 128), 256, 0, stream>>>(
            wmsgT, wmsgT + (size_t)1 * 262144, 512, S2, S2 + (size_t)NP * 512, ktMsgA, ktMsg,
            abf, 512, 0, nullptr, nullptr);
        gather2<<<2 * NP / 4, 256, 0, stream>>>(offs, srcs_s, hin, S2, 1);
        gemm2<<<dim3(4, NP / 128), 256, 0, stream>>>(
            wmsgT + (size_t)2 * 262144, wmsgT + (size_t)3 * 262144, 512, S2, S2 + (size_t)NP * 512, ktMsgA, ktMsg,
            abf, 512, 3, cntf, bmsg);
        // merged: rz = [abf|hin] @ Wrz^T -> S2 ; h_n = hin @ whn^T -> hout
        gemm_rzhn<<<dim3(12, NP / 128), 256, 0, stream>>>(
            wrz, whn, abf, hin, S2, hout, ktRZ, ktHN);
        // i_n GEMM + fused GRU epilogue -> hout = h_new
        gemm_gru<<<dim3(4, NP / 128), 256, 0, stream>>>(
            win, abf, S2, hin, b_ih, b_hh, hout);
        ushort* tmp = hin; hin = hout; hout = tmp;
    }
    // hin now holds final h (hbfA after 4 steps)

    norm_sig<<<NN, 64, 0, stream>>>(hin);
    // feat = h @ fc_w^T  (bf16) -> featbf (abf region)
    gemm2<<<dim3(4, NP / 128), 256, 0, stream>>>(
        fcb, fcb, 512, hin, hin, 512, 512, featbf, 512, 0, nullptr, nullptr);
    el_er2<<<NN, 64, 0, stream>>>(featbf, attn_l, attn_r, el, er);
    edge_scores<<<cdiv(EE, 256), 256, 0, stream>>>(srcs_s, dsts_s, el, er, esc);

    gat3<<<NN / 4, 256, 0, stream>>>(offs, srcs_s, esc, featbf, gat_bias, rst);
    hipMemsetAsync(hgm, 0, (size_t)GG * 512 * 4, stream);
    graph_mean2<<<dim3(GG, 8), 256, 0, stream>>>(rst, goff, hgm);
    classify<<<GG, 64, 0, stream>>>(hgm, goff, cw, cb, out);
}